// Round 6
// baseline (387.985 us; speedup 1.0000x reference)
//
#include <hip/hip_runtime.h>
#include <math.h>

#define NB 16      // B
#define NN 1024    // N
#define NF 32      // F
#define NT 12      // T
#define NFC 64
#define NFT 64

typedef __attribute__((ext_vector_type(8))) short bf16x8;
typedef __attribute__((ext_vector_type(4))) float f32x4;

__device__ inline unsigned short cvt_bf(float f) {
    unsigned int u = __float_as_uint(f);
    u += 0x7fff + ((u >> 16) & 1);
    return (unsigned short)(u >> 16);
}
__device__ inline float bf2f(unsigned short u) {
    return __uint_as_float(((unsigned int)u) << 16);
}
__device__ inline void gll16(const short* g, short* l) {
    __builtin_amdgcn_global_load_lds((const __attribute__((address_space(1))) void*)g,
                                     (__attribute__((address_space(3))) void*)l, 16, 0, 0);
}

// ---------------- fused pre-pass: lhs_pre (U1), rhs (U3), rr3 (W3), Xt (bf16 transpose) ----------------
// grid (16 b, 16 ch) x 384. ch = group of 64 nodes. x fp32 read happens ONLY here.
__global__ __launch_bounds__(384) void k_pre(const float* __restrict__ x,
                                             const float* __restrict__ U1,
                                             const float* __restrict__ U3,
                                             const float* __restrict__ W3,
                                             float* __restrict__ lhs_pre,
                                             float* __restrict__ rhs,
                                             float* __restrict__ rr3,
                                             unsigned short* __restrict__ Xt)
{
    __shared__ float xs[8 * 384];
    __shared__ unsigned short xtile[64 * 392];   // [n_local][j], pad 392 (16B-aligned rows)
    int b = blockIdx.x, ch = blockIdx.y, tid = threadIdx.x;
    float acc = 0.f;
    for (int c8 = 0; c8 < 8; c8++) {
        int n0 = ch * 64 + c8 * 8;
        size_t r0 = (size_t)b * NN + n0;
        __syncthreads();
        for (int i = 0; i < 8; i++) xs[i * 384 + tid] = x[(r0 + i) * 384 + tid];
        __syncthreads();
        for (int i = 0; i < 8; i++) {
            float v = xs[i * 384 + tid];
            acc += v * U1[n0 + i];
            xtile[(c8 * 8 + i) * 392 + tid] = cvt_bf(v);
        }
        if (tid < 192) {
            int half = tid / 96;
            int r = tid - half * 96;
            int i = r / 12, t = r - i * 12;
            const float* wv = half ? W3 : U3;
            float s = 0.f;
            for (int f = 0; f < 32; f++) s += wv[f] * xs[i * 384 + f * 12 + t];
            float* outp = half ? rr3 : rhs;
            outp[(r0 + i) * 12 + t] = s;
        }
    }
    {
        int f = tid / 12, t = tid - f * 12;
        atomicAdd(&lhs_pre[b * 384 + t * 32 + f], acc);
    }
    __syncthreads();
    // Xt[b][j=tid][ch*64 + 0..63]: 128B contiguous per thread
    unsigned short* orow = Xt + ((size_t)b * 384 + tid) * NN + ch * 64;
#pragma unroll
    for (int g = 0; g < 8; g++) {
        unsigned int w0 = (unsigned int)xtile[(g * 8 + 0) * 392 + tid] | ((unsigned int)xtile[(g * 8 + 1) * 392 + tid] << 16);
        unsigned int w1 = (unsigned int)xtile[(g * 8 + 2) * 392 + tid] | ((unsigned int)xtile[(g * 8 + 3) * 392 + tid] << 16);
        unsigned int w2 = (unsigned int)xtile[(g * 8 + 4) * 392 + tid] | ((unsigned int)xtile[(g * 8 + 5) * 392 + tid] << 16);
        unsigned int w3 = (unsigned int)xtile[(g * 8 + 6) * 392 + tid] | ((unsigned int)xtile[(g * 8 + 7) * 392 + tid] << 16);
        uint4 pk; pk.x = w0; pk.y = w1; pk.z = w2; pk.w = w3;
        *(uint4*)(orow + g * 8) = pk;
    }
}

__global__ __launch_bounds__(256) void k_lhs(const float* __restrict__ lhs_pre,
                                             const float* __restrict__ U2,
                                             float* __restrict__ lhs)
{
    int bt = blockIdx.x;
    int tid = threadIdx.x;
    __shared__ float lp[32];
    if (tid < 32) lp[tid] = lhs_pre[bt * 32 + tid];
    __syncthreads();
    for (int q = 0; q < 4; q++) {
        int n = q * 256 + tid;
        float a = 0.f;
        for (int f = 0; f < 32; f++) a += lp[f] * U2[f * NN + n];
        lhs[(size_t)bt * NN + n] = a;
    }
}

__global__ __launch_bounds__(64) void k_prod(const float* __restrict__ lhs,
                                             const float* __restrict__ rhs,
                                             float* __restrict__ prod)
{
    int blk = blockIdx.x;
    int b = blk / 144, r = blk - b * 144;
    int s = r / 12, u = r - s * 12;
    int tid = threadIdx.x;
    float p = 0.f;
    for (int n = tid; n < NN; n += 64)
        p += lhs[((size_t)b * 12 + s) * NN + n] * rhs[((size_t)b * NN + n) * 12 + u];
    for (int o = 32; o > 0; o >>= 1) p += __shfl_xor(p, o);
    if (tid == 0) prod[blk] = p;
}

// E (softmax over t) + EW1[b][t] = sum_u E[b,t,u]*W1[u]
__global__ __launch_bounds__(192) void k_E(const float* __restrict__ prod,
                                           const float* __restrict__ be,
                                           const float* __restrict__ Ve,
                                           const float* __restrict__ W1,
                                           float* __restrict__ E,
                                           float* __restrict__ EW1)
{
    int b = blockIdx.x, tid = threadIdx.x;
    __shared__ float ssig[144], sE[144], mx[12], sm[12];
    if (tid < 144) ssig[tid] = 1.f / (1.f + expf(-(prod[b * 144 + tid] + be[tid])));
    __syncthreads();
    if (tid < 144) {
        int t = tid / 12, u = tid - t * 12;
        float a = 0.f;
        for (int s2 = 0; s2 < 12; s2++) a += Ve[t * 12 + s2] * ssig[s2 * 12 + u];
        sE[tid] = a;
    }
    __syncthreads();
    if (tid < 12) {
        float m = -1e30f;
        for (int t = 0; t < 12; t++) m = fmaxf(m, sE[t * 12 + tid]);
        float s = 0.f;
        for (int t = 0; t < 12; t++) s += expf(sE[t * 12 + tid] - m);
        mx[tid] = m; sm[tid] = s;
    }
    __syncthreads();
    float val = 0.f;
    if (tid < 144) {
        int u = tid % 12;
        val = expf(sE[tid] - mx[u]) / sm[u];
        E[b * 144 + tid] = val;
    }
    __syncthreads();
    if (tid < 144) sE[tid] = val;
    __syncthreads();
    if (tid < 12) {
        float a = 0.f;
        for (int u = 0; u < 12; u++) a += sE[tid * 12 + u] * W1[u];
        EW1[b * 12 + tid] = a;
    }
}

// ---------------- l2/r2 from Xt (bf16) ----------------
// l2[b,n,u] = sum_f (sum_t x[b,n,f,t]*EW1[b,t]) * W2[f,u]
// r2[b,u,n] = sum_t rr3[b,n,t]*E[b,t,u]
__global__ __launch_bounds__(384) void k_l2r2x(const unsigned short* __restrict__ Xt,
                                               const float* __restrict__ rr3,
                                               const float* __restrict__ E,
                                               const float* __restrict__ EW1,
                                               const float* __restrict__ W2,
                                               float* __restrict__ l2,
                                               float* __restrict__ r2)
{
    __shared__ float xs[8 * 384];
    __shared__ float Es[144], ew[12], rrs[96], lp[8][32];
    int b = blockIdx.y, tid = threadIdx.x;
    int n0 = blockIdx.x * 8;
    size_t r0 = (size_t)b * NN + n0;
    if (tid < 144) Es[tid] = E[b * 144 + tid];
    if (tid < 12) ew[tid] = EW1[b * 12 + tid];
    if (tid < 96) rrs[tid] = rr3[(r0 + tid / 12) * 12 + (tid % 12)];
    size_t xrow = (size_t)b * 384 * NN + n0;
    for (int i2 = tid; i2 < 3072; i2 += 384) {
        int j = i2 >> 3, node = i2 & 7;
        xs[node * 384 + j] = bf2f(Xt[xrow + (size_t)j * NN + node]);
    }
    __syncthreads();
    if (tid < 256) {
        int i = tid >> 5, f = tid & 31;
        float a = 0.f;
#pragma unroll
        for (int t = 0; t < 12; t++) a += xs[i * 384 + f * 12 + t] * ew[t];
        lp[i][f] = a;
    }
    __syncthreads();
    if (tid < 96) {
        int i = tid / 12, u = tid - i * 12;
        float a = 0.f;
        for (int f = 0; f < 32; f++) a += lp[i][f] * W2[f * 12 + u];
        l2[(r0 + i) * 12 + u] = a;
        float rv = 0.f;
#pragma unroll
        for (int t = 0; t < 12; t++) rv += rrs[i * 12 + t] * Es[t * 12 + u];
        r2[((size_t)b * 12 + u) * NN + n0 + i] = rv;
    }
}

// ---------------- tiled P: Pt[b][k][m] = bf16(sigmoid(l2[b,m,:]·r2[b,:,k] + bs[m,k])) ----------------
// grid (16 kt, 16 mt, 16 b) x 256; bs transposed in LDS
__global__ __launch_bounds__(256) void k_Ptile(const float* __restrict__ l2,
                                               const float* __restrict__ r2,
                                               const float* __restrict__ bsin,
                                               unsigned short* __restrict__ Pt)
{
    __shared__ float l2s[64][13];
    __shared__ float r2s[12][64];
    __shared__ float bsS[64][65];
    int k0 = blockIdx.x * 64, m0 = blockIdx.y * 64, b = blockIdx.z;
    int tid = threadIdx.x;
    for (int i = tid; i < 768; i += 256) {
        int r = i / 12, t = i - r * 12;
        l2s[r][t] = l2[((size_t)b * NN + m0 + r) * 12 + t];
    }
    for (int i = tid; i < 768; i += 256) {
        int t = i >> 6, k = i & 63;
        r2s[t][k] = r2[((size_t)b * 12 + t) * NN + k0 + k];
    }
    for (int i = tid; i < 4096; i += 256) {
        int r = i >> 6, c = i & 63;
        bsS[r][c] = bsin[(size_t)(m0 + r) * NN + k0 + c];
    }
    __syncthreads();
    int m = tid & 63, kg = tid >> 6;
    float lv[12];
#pragma unroll
    for (int t = 0; t < 12; t++) lv[t] = l2s[m][t];
#pragma unroll
    for (int s = 0; s < 16; s++) {
        int kl = kg * 16 + s;
        float p = bsS[m][kl];
#pragma unroll
        for (int t = 0; t < 12; t++) p += lv[t] * r2s[t][kl];
        float sg = 1.f / (1.f + expf(-p));
        Pt[((size_t)b * NN + k0 + kl) * NN + m0 + m] = cvt_bf(sg);
    }
}

// Vs fp32 -> bf16
__global__ __launch_bounds__(256) void k_cvt(const float* __restrict__ s,
                                             unsigned short* __restrict__ d)
{
    size_t i = ((size_t)blockIdx.x * 256 + threadIdx.x) * 4;
    float4 v = *(const float4*)(s + i);
    unsigned int p0 = (unsigned int)cvt_bf(v.x) | ((unsigned int)cvt_bf(v.y) << 16);
    unsigned int p1 = (unsigned int)cvt_bf(v.z) | ((unsigned int)cvt_bf(v.w) << 16);
    *(unsigned int*)(d + i) = p0;
    *(unsigned int*)(d + i + 2) = p1;
}

// bf16 transpose 1024x1024
__global__ __launch_bounds__(256) void k_tb16(const unsigned short* __restrict__ s,
                                              unsigned short* __restrict__ d)
{
    __shared__ unsigned short tl[64][65];
    int r0 = blockIdx.y * 64, c0 = blockIdx.x * 64;
    int tid = threadIdx.x;
    int c = tid & 63, rr = tid >> 6;
    for (int i = 0; i < 16; i++)
        tl[rr + i * 4][c] = s[(size_t)(r0 + rr + i * 4) * NN + c0 + c];
    __syncthreads();
    for (int i = 0; i < 16; i++)
        d[(size_t)(c0 + rr + i * 4) * NN + r0 + c] = tl[c][rr + i * 4];
}

// ---------------- MFMA bf16 NT GEMM ----------------
// MODE 1: bf16 out. MODE 2: fp32 exp(out) + colsum atomics. MODE 3: split-K fp32 atomicAdd (bz = k-chunk).
template<int MODE>
__global__ __launch_bounds__(256) void mgemm(const short* __restrict__ A,
                                             const short* __restrict__ B,
                                             void* __restrict__ Cv,
                                             int Kd, int kchunk,
                                             int ldA, int ldB, int ldC,
                                             long sA, long sB, long sC,
                                             float* __restrict__ colsum)
{
    int bz = blockIdx.z;
    const short* Ab = A + (size_t)bz * sA;
    const short* Bb = B + (size_t)bz * sB;
    int i0 = blockIdx.y * 128, j0 = blockIdx.x * 128;
    __shared__ short sm[16384];            // As [128][64] @0, Bs [128][64] @8192
    int tid = threadIdx.x;
    int ln = tid & 63, wv = tid >> 6;
    int wm = (wv >> 1) * 64, wn = (wv & 1) * 64;
    int fr = ln & 15, fk = ln >> 4;
    f32x4 acc[4][4];
#pragma unroll
    for (int a = 0; a < 4; a++)
#pragma unroll
        for (int b2 = 0; b2 < 4; b2++) acc[a][b2] = (f32x4)(0.f);

    int k_lo = 0, k_hi = Kd;
    if constexpr (MODE == 3) { k_lo = bz * kchunk; k_hi = k_lo + kchunk; }

    for (int k0 = k_lo; k0 < k_hi; k0 += 64) {
#pragma unroll
        for (int q = 0; q < 4; q++) {
            int e = q * 2048 + tid * 8;
            const short* src = Ab + (size_t)(i0 + (e >> 6)) * ldA + k0 + (e & 63);
            gll16(src, sm + e);
        }
#pragma unroll
        for (int q = 0; q < 4; q++) {
            int e = q * 2048 + tid * 8;
            const short* src = Bb + (size_t)(j0 + (e >> 6)) * ldB + k0 + (e & 63);
            gll16(src, sm + 8192 + e);
        }
        __syncthreads();
#pragma unroll
        for (int ks = 0; ks < 2; ks++) {
            bf16x8 av[4], bv[4];
#pragma unroll
            for (int mi = 0; mi < 4; mi++)
                av[mi] = *(const bf16x8*)(sm + (wm + mi * 16 + fr) * 64 + ks * 32 + fk * 8);
#pragma unroll
            for (int nj = 0; nj < 4; nj++)
                bv[nj] = *(const bf16x8*)(sm + 8192 + (wn + nj * 16 + fr) * 64 + ks * 32 + fk * 8);
#pragma unroll
            for (int mi = 0; mi < 4; mi++)
#pragma unroll
                for (int nj = 0; nj < 4; nj++)
                    acc[mi][nj] = __builtin_amdgcn_mfma_f32_16x16x32_bf16(av[mi], bv[nj], acc[mi][nj], 0, 0, 0);
        }
        __syncthreads();
    }
    if constexpr (MODE == 2) {
        float* Cb = (float*)Cv + (size_t)bz * sC;
#pragma unroll
        for (int nj = 0; nj < 4; nj++) {
            float cs = 0.f;
            int col = j0 + wn + nj * 16 + fr;
#pragma unroll
            for (int mi = 0; mi < 4; mi++) {
                int row = i0 + wm + mi * 16 + fk * 4;
#pragma unroll
                for (int r = 0; r < 4; r++) {
                    float e = expf(acc[mi][nj][r]);
                    Cb[(size_t)(row + r) * ldC + col] = e;
                    cs += e;
                }
            }
            cs += __shfl_xor(cs, 16);
            cs += __shfl_xor(cs, 32);
            if (ln < 16) atomicAdd(&colsum[(size_t)bz * NN + col], cs);
        }
    } else if constexpr (MODE == 3) {
        float* Cb = (float*)Cv;
#pragma unroll
        for (int mi = 0; mi < 4; mi++)
#pragma unroll
            for (int nj = 0; nj < 4; nj++) {
                int row = i0 + wm + mi * 16 + fk * 4;
                int col = j0 + wn + nj * 16 + fr;
#pragma unroll
                for (int r = 0; r < 4; r++)
                    atomicAdd(&Cb[(size_t)(row + r) * ldC + col], acc[mi][nj][r]);
            }
    } else {
#pragma unroll
        for (int mi = 0; mi < 4; mi++)
#pragma unroll
            for (int nj = 0; nj < 4; nj++) {
                int row = i0 + wm + mi * 16 + fk * 4;
                int col = j0 + wn + nj * 16 + fr;
                unsigned short* Cb = (unsigned short*)Cv + (size_t)bz * sC;
#pragma unroll
                for (int r = 0; r < 4; r++)
                    Cb[(size_t)(row + r) * ldC + col] = cvt_bf(acc[mi][nj][r]);
            }
    }
}

// ---------------- normalize + threshold + At1 + At2 (fully fused) ----------------
__global__ __launch_bounds__(256) void k_normprep2(float* __restrict__ spat,
                                                   const float* __restrict__ colsum,
                                                   const float* __restrict__ sup,
                                                   const float* __restrict__ supsq,
                                                   unsigned short* __restrict__ At1,
                                                   unsigned short* __restrict__ At2)
{
    __shared__ unsigned short t1[64][66];
    __shared__ unsigned short t2[64][66];
    int b = blockIdx.z;
    int n0 = blockIdx.y * 64, m0 = blockIdx.x * 64;
    int tid = threadIdx.x;
    int c = tid & 63, r0 = tid >> 6;
    const float thr = (1.0f / 1024.0f) / 0.6f;
    float inv = 1.f / colsum[(size_t)b * NN + m0 + c];
    float* sp = spat + (size_t)b * NN * NN;
    for (int i = 0; i < 16; i++) {
        int r = r0 + i * 4;
        size_t idx = (size_t)(n0 + r) * NN + m0 + c;
        float v = sp[idx] * inv;
        v = (v < thr) ? 0.f : v;
        sp[idx] = v;
        t1[r][c] = cvt_bf(sup[(size_t)(n0 + r) * NN + m0 + c] * v);
        float p2 = 2.f * supsq[(size_t)(n0 + r) * NN + m0 + c]
                 - (((n0 + r) == (m0 + c)) ? 1.f : 0.f);
        t2[r][c] = cvt_bf(p2 * v);
    }
    __syncthreads();
    int c2 = tid & 31, r4 = tid >> 5;
    size_t ob = ((size_t)b * NN + m0) * NN + n0;
    for (int i = 0; i < 8; i++) {
        int rr = r4 + i * 8;
        unsigned int v1 = (unsigned int)t1[2 * c2][rr] | ((unsigned int)t1[2 * c2 + 1][rr] << 16);
        unsigned int v2 = (unsigned int)t2[2 * c2][rr] | ((unsigned int)t2[2 * c2 + 1][rr] << 16);
        *(unsigned int*)(At1 + ob + (size_t)rr * NN + 2 * c2) = v1;
        *(unsigned int*)(At2 + ob + (size_t)rr * NN + 2 * c2) = v2;
    }
}

// ---------------- support graph (fp32 + bf16 copies) ----------------
__global__ __launch_bounds__(256) void k_sup(const float* __restrict__ emb,
                                             float* __restrict__ sup,
                                             unsigned short* __restrict__ supB)
{
    int n = blockIdx.x, tid = threadIdx.x;
    __shared__ float en[16];
    if (tid < 16) en[tid] = emb[n * 16 + tid];
    __syncthreads();
    float v[4];
#pragma unroll
    for (int q = 0; q < 4; q++) {
        int m = q * 256 + tid;
        float d = 0.f;
#pragma unroll
        for (int dd = 0; dd < 16; dd++) d += en[dd] * emb[m * 16 + dd];
        v[q] = fmaxf(d, 0.f);
    }
    float mx = fmaxf(fmaxf(v[0], v[1]), fmaxf(v[2], v[3]));
    for (int o = 32; o > 0; o >>= 1) mx = fmaxf(mx, __shfl_xor(mx, o));
    __shared__ float red[4];
    if ((tid & 63) == 0) red[tid >> 6] = mx;
    __syncthreads();
    mx = fmaxf(fmaxf(red[0], red[1]), fmaxf(red[2], red[3]));
    float e[4];
    float s = 0.f;
#pragma unroll
    for (int q = 0; q < 4; q++) { e[q] = expf(v[q] - mx); s += e[q]; }
    for (int o = 32; o > 0; o >>= 1) s += __shfl_xor(s, o);
    __shared__ float red2[4];
    if ((tid & 63) == 0) red2[tid >> 6] = s;
    __syncthreads();
    s = red2[0] + red2[1] + red2[2] + red2[3];
    float inv = 1.f / s;
#pragma unroll
    for (int q = 0; q < 4; q++) {
        float val = e[q] * inv;
        sup[(size_t)n * NN + q * 256 + tid] = val;
        supB[(size_t)n * NN + q * 256 + tid] = cvt_bf(val);
    }
}

// ---------------- weight prep ----------------
__global__ __launch_bounds__(192) void k_wnorm(const float* __restrict__ tcv,
                                               const float* __restrict__ tcg,
                                               unsigned short* __restrict__ Wr)
{
    int o = blockIdx.x, tid = threadIdx.x;
    float t = tcv[o * 192 + tid];
    float p = t * t;
    for (int off = 32; off > 0; off >>= 1) p += __shfl_xor(p, off);
    __shared__ float wsr[3];
    if ((tid & 63) == 0) wsr[tid >> 6] = p;
    __syncthreads();
    float sum = wsr[0] + wsr[1] + wsr[2];
    int c = tid / 3, dt = tid - c * 3;
    Wr[o * 192 + dt * 64 + c] = cvt_bf(t * (tcg[o] / sqrtf(sum)));
}

__global__ __launch_bounds__(256) void k_prepw(const float* __restrict__ Theta,
                                               const float* __restrict__ rcw,
                                               unsigned short* __restrict__ Th,
                                               unsigned short* __restrict__ Rc)
{
    int tid = threadIdx.x;
    for (int i = tid; i < 6144; i += 256) {
        int o = i / 96, rem = i - o * 96;
        int kind = rem >> 5, f = rem & 31;
        Th[i] = cvt_bf(Theta[kind * 2048 + f * 64 + o]);
    }
    for (int i = tid; i < 2048; i += 256) Rc[i] = cvt_bf(rcw[i]);
}

// ---------------- MFMA fused tail (x read via Xt bf16) ----------------
__global__ __launch_bounds__(256) void k_tail(const unsigned short* __restrict__ Xt,
                                              const unsigned short* __restrict__ h1,
                                              const unsigned short* __restrict__ h2,
                                              const float* __restrict__ spat,
                                              const unsigned short* __restrict__ Th,
                                              const unsigned short* __restrict__ Wr,
                                              const unsigned short* __restrict__ Rc,
                                              const float* __restrict__ tcb,
                                              const float* __restrict__ rcb,
                                              const float* __restrict__ lnw,
                                              const float* __restrict__ lnb,
                                              float* __restrict__ out)
{
    int b = blockIdx.y;
    int node0 = blockIdx.x * 8;
    int tid = threadIdx.x;
    int ln = tid & 63, wv = tid >> 6;
    int fr = ln & 15, fk = ln >> 4;

    __shared__ union {
        struct { unsigned short xt[3840], h1t[3840], h2t[3840], gcn[8064]; } a;
        float Y[96 * 65];
    } u;
    __shared__ float sdp[96];
    __shared__ float lnwS[64], lnbS[64], tbS[64];
    __shared__ float muS[96], rsS[96];

    size_t rowb = ((size_t)b * NN + node0) * 384;
    for (int i = tid; i < 3072; i += 256) {
        int node = i / 384, j = i - node * 384;
        int f = j / 12, t = j - f * 12;
        int la = node * 480 + t * 40 + f;
        u.a.h1t[la] = h1[rowb + i];
        u.a.h2t[la] = h2[rowb + i];
    }
    size_t xrow = (size_t)b * 384 * NN + node0;
    for (int i = tid; i < 3072; i += 256) {
        int j = i >> 3, node = i & 7;
        int f = j / 12, t = j - f * 12;
        u.a.xt[node * 480 + t * 40 + f] = Xt[xrow + (size_t)j * NN + node];
    }
    for (int i = tid; i < 1152; i += 256) {
        int node = i / 144, r = i - node * 144;
        int rr = (r < 72) ? 0 : 13;
        u.a.gcn[node * 1008 + rr * 72 + (r % 72)] = 0;
    }
    if (tid < 96) {
        int node = tid / 12;
        sdp[tid] = spat[(size_t)b * NN * NN + (size_t)(node0 + node) * NN + node0 + node];
    }
    if (tid < 64) { lnwS[tid] = lnw[tid]; lnbS[tid] = lnb[tid]; tbS[tid] = tcb[tid] + rcb[tid]; }

    int ocol = wv * 16 + fr;
    bf16x8 bTh[3], bWr[6], bRc;
#pragma unroll
    for (int kb = 0; kb < 3; kb++)
        bTh[kb] = *(const bf16x8*)((const short*)Th + (size_t)ocol * 96 + kb * 32 + fk * 8);
#pragma unroll
    for (int kb = 0; kb < 6; kb++)
        bWr[kb] = *(const bf16x8*)((const short*)Wr + (size_t)ocol * 192 + kb * 32 + fk * 8);
    bRc = *(const bf16x8*)((const short*)Rc + (size_t)ocol * 32 + fk * 8);

    int na[6], ta[6];
#pragma unroll
    for (int rb = 0; rb < 6; rb++) {
        int p = rb * 16 + fr;
        na[rb] = p / 12; ta[rb] = p - na[rb] * 12;
    }
    __syncthreads();

    f32x4 acc[6];
#pragma unroll
    for (int rb = 0; rb < 6; rb++) {
        int ax = na[rb] * 480 + ta[rb] * 40 + fk * 8;
        bf16x8 avx = *(const bf16x8*)(u.a.xt + ax);
        f32x4 z = (f32x4)(0.f);
        acc[rb] = __builtin_amdgcn_mfma_f32_16x16x32_bf16(avx, bTh[0], z, 0, 0, 0);
#pragma unroll
        for (int r = 0; r < 4; r++) acc[rb][r] *= sdp[rb * 16 + fk * 4 + r];
        bf16x8 av1 = *(const bf16x8*)(u.a.h1t + ax);
        acc[rb] = __builtin_amdgcn_mfma_f32_16x16x32_bf16(av1, bTh[1], acc[rb], 0, 0, 0);
        bf16x8 av2 = *(const bf16x8*)(u.a.h2t + ax);
        acc[rb] = __builtin_amdgcn_mfma_f32_16x16x32_bf16(av2, bTh[2], acc[rb], 0, 0, 0);
    }
#pragma unroll
    for (int rb = 0; rb < 6; rb++) {
#pragma unroll
        for (int r = 0; r < 4; r++) {
            int pc = rb * 16 + fk * 4 + r;
            int nc = pc / 12, tc2 = pc - nc * 12;
            u.a.gcn[nc * 1008 + (tc2 + 1) * 72 + wv * 16 + fr] = cvt_bf(fmaxf(acc[rb][r], 0.f));
        }
    }
    __syncthreads();
#pragma unroll
    for (int rb = 0; rb < 6; rb++) {
        f32x4 a2 = (f32x4)(0.f);
#pragma unroll
        for (int kb = 0; kb < 6; kb++) {
            int dt = kb >> 1, c0 = (kb & 1) * 32;
            bf16x8 ag = *(const bf16x8*)(u.a.gcn + na[rb] * 1008 + (ta[rb] + dt) * 72 + c0 + fk * 8);
            a2 = __builtin_amdgcn_mfma_f32_16x16x32_bf16(ag, bWr[kb], a2, 0, 0, 0);
        }
        int ax = na[rb] * 480 + ta[rb] * 40 + fk * 8;
        bf16x8 avx = *(const bf16x8*)(u.a.xt + ax);
        acc[rb] = __builtin_amdgcn_mfma_f32_16x16x32_bf16(avx, bRc, a2, 0, 0, 0);
    }
    __syncthreads();
    float tb = tbS[ocol];
#pragma unroll
    for (int rb = 0; rb < 6; rb++)
#pragma unroll
        for (int r = 0; r < 4; r++)
            u.Y[(rb * 16 + fk * 4 + r) * 65 + ocol] = acc[rb][r] + tb;
    __syncthreads();
    if (tid < 96) {
        float s = 0.f, s2 = 0.f;
        for (int o = 0; o < 64; o++) {
            float v = u.Y[tid * 65 + o];
            s += v; s2 += v * v;
        }
        float mm = s * (1.f / 64.f);
        float var = s2 * (1.f / 64.f) - mm * mm;
        muS[tid] = mm; rsS[tid] = rsqrtf(var + 1e-5f);
    }
    __syncthreads();
    float* ob = out + rowb * 2;
    for (int i = tid; i < 6144; i += 256) {
        int node = i / 768, rr = i - node * 768;
        int o = rr / 12, t = rr - o * 12;
        int p = node * 12 + t;
        ob[i] = (u.Y[p * 65 + o] - muS[p]) * rsS[p] * lnwS[o] + lnbS[o];
    }
}

extern "C" void kernel_launch(void* const* d_in, const int* in_sizes, int n_in,
                              void* d_out, int out_size, void* d_ws, size_t ws_size,
                              hipStream_t stream)
{
    const float* x    = (const float*)d_in[0];
    const float* emb  = (const float*)d_in[1];
    const float* W1   = (const float*)d_in[2];
    const float* W2   = (const float*)d_in[3];
    const float* W3   = (const float*)d_in[4];
    const float* bs   = (const float*)d_in[5];
    const float* Vs   = (const float*)d_in[6];
    const float* U1   = (const float*)d_in[7];
    const float* U2   = (const float*)d_in[8];
    const float* U3   = (const float*)d_in[9];
    const float* be   = (const float*)d_in[10];
    const float* Ve   = (const float*)d_in[11];
    const float* Theta= (const float*)d_in[12];
    const float* tcv  = (const float*)d_in[13];
    const float* tcg  = (const float*)d_in[14];
    const float* tcb  = (const float*)d_in[15];
    const float* rcw  = (const float*)d_in[16];
    const float* rcb  = (const float*)d_in[17];
    const float* lnw  = (const float*)d_in[18];
    const float* lnb  = (const float*)d_in[19];

    float* xres = (float*)d_out;                       // B*N*FT*T fp32 (scratch for At2 until k_tail)
    float* spat = xres + (size_t)NB * NN * NFT * NT;   // B*N*N fp32

    char* base = (char*)d_ws;
    unsigned short* Pt   = (unsigned short*)(base + 0);   // then supB/supT, then At1
    unsigned short* supB = (unsigned short*)(base + 0);
    unsigned short* supT = (unsigned short*)(base + 2097152);
    unsigned short* At1  = (unsigned short*)(base + 0);
    unsigned short* At2  = (unsigned short*)xres;          // d_out scratch (32 MB < 48 MB)
    unsigned short* Xt  = (unsigned short*)(base + 33554432);   // live k_pre -> k_tail
    unsigned short* h1  = (unsigned short*)(base + 46137344);
    unsigned short* h2  = (unsigned short*)(base + 58720256);
    unsigned short* Vsb = (unsigned short*)(base + 71303168);
    float* colsum  = (float*)(base + 73400320);
    float* sup     = (float*)(base + 77594624);
    float* supsq   = (float*)(base + 81788928);
    float* lhs_pre = (float*)(base + 85983232);
    float* lhs     = (float*)(base + 86007808);
    float* rhs     = (float*)(base + 86794240);
    float* rr3     = (float*)(base + 87580672);
    float* prod    = (float*)(base + 88367104);
    float* E       = (float*)(base + 88376320);
    float* EW1     = (float*)(base + 88385536);
    float* l2      = (float*)(base + 88386560);
    float* r2      = (float*)(base + 89172992);
    unsigned short* Wr = (unsigned short*)(base + 89959424);
    unsigned short* Th = (unsigned short*)(base + 89984000);
    unsigned short* Rc = (unsigned short*)(base + 89996288);

    hipMemsetAsync(lhs_pre, 0, 6144 * sizeof(float), stream);
    hipMemsetAsync(supsq, 0, (size_t)NN * NN * sizeof(float), stream);

    // pre-pass: x read ONCE -> lhs_pre, rhs, rr3, Xt(bf16 transposed)
    k_pre<<<dim3(16, 16), 384, 0, stream>>>(x, U1, U3, W3, lhs_pre, rhs, rr3, Xt);
    k_lhs<<<192, 256, 0, stream>>>(lhs_pre, U2, lhs);
    k_prod<<<2304, 64, 0, stream>>>(lhs, rhs, prod);
    k_E<<<16, 192, 0, stream>>>(prod, be, Ve, W1, E, EW1);
    // spatial attention
    k_l2r2x<<<dim3(128, 16), 384, 0, stream>>>(Xt, rr3, E, EW1, W2, l2, r2);
    k_Ptile<<<dim3(16, 16, 16), 256, 0, stream>>>(l2, r2, bs, Pt);
    k_cvt<<<1024, 256, 0, stream>>>(Vs, Vsb);
    hipMemsetAsync(colsum, 0, (size_t)NB * NN * sizeof(float), stream);
    mgemm<2><<<dim3(8, 8, 16), 256, 0, stream>>>((const short*)Vsb, (const short*)Pt,
        (void*)spat, NN, 0, NN, NN, NN, 0L, (long)NN * NN, (long)NN * NN, colsum);
    // graph supports
    k_sup<<<1024, 256, 0, stream>>>(emb, sup, supB);
    k_tb16<<<dim3(16, 16), 256, 0, stream>>>(supB, supT);
    mgemm<3><<<dim3(8, 8, 4), 256, 0, stream>>>((const short*)supB, (const short*)supT,
        (void*)supsq, NN, 256, NN, NN, NN, 0L, 0L, 0L, nullptr);
    // normalize + threshold + both masked adjacencies, one pass
    k_normprep2<<<dim3(16, 16, 16), 256, 0, stream>>>(spat, colsum, sup, supsq, At1, At2);
    mgemm<1><<<dim3(3, 8, 16), 256, 0, stream>>>((const short*)At1, (const short*)Xt,
        (void*)h1, NN, 0, NN, NN, 384, (long)NN * NN, 384L * NN, (long)NN * 384, nullptr);
    mgemm<1><<<dim3(3, 8, 16), 256, 0, stream>>>((const short*)At2, (const short*)Xt,
        (void*)h2, NN, 0, NN, NN, 384, (long)NN * NN, 384L * NN, (long)NN * 384, nullptr);
    // tail
    k_wnorm<<<64, 192, 0, stream>>>(tcv, tcg, Wr);
    k_prepw<<<1, 256, 0, stream>>>(Theta, rcw, Th, Rc);
    k_tail<<<dim3(128, 16), 256, 0, stream>>>(Xt, h1, h2, spat, Th, Wr, Rc,
                                              tcb, rcb, lnw, lnb, xres);
}

// Round 7
// 353.473 us; speedup vs baseline: 1.0976x; 1.0976x over previous
//
#include <hip/hip_runtime.h>
#include <math.h>

#define NB 16      // B
#define NN 1024    // N
#define NF 32      // F
#define NT 12      // T
#define NFC 64
#define NFT 64

typedef __attribute__((ext_vector_type(8))) short bf16x8;
typedef __attribute__((ext_vector_type(4))) float f32x4;

__device__ inline unsigned short cvt_bf(float f) {
    unsigned int u = __float_as_uint(f);
    u += 0x7fff + ((u >> 16) & 1);
    return (unsigned short)(u >> 16);
}
__device__ inline void gll16(const short* g, short* l) {
    __builtin_amdgcn_global_load_lds((const __attribute__((address_space(1))) void*)g,
                                     (__attribute__((address_space(3))) void*)l, 16, 0, 0);
}

// ---------------- fused pre-pass: lhs_pre (U1), rhs (U3), rr3 (W3) ----------------
__global__ __launch_bounds__(384) void k_pre(const float* __restrict__ x,
                                             const float* __restrict__ U1,
                                             const float* __restrict__ U3,
                                             const float* __restrict__ W3,
                                             float* __restrict__ lhs_pre,
                                             float* __restrict__ rhs,
                                             float* __restrict__ rr3)
{
    __shared__ float xs[8 * 384];
    int b = blockIdx.x, ch = blockIdx.y, tid = threadIdx.x;
    float acc = 0.f;
    for (int c8 = 0; c8 < 8; c8++) {
        int n0 = ch * 64 + c8 * 8;
        size_t r0 = (size_t)b * NN + n0;
        __syncthreads();
        for (int i = 0; i < 8; i++) xs[i * 384 + tid] = x[(r0 + i) * 384 + tid];
        __syncthreads();
        for (int i = 0; i < 8; i++) acc += xs[i * 384 + tid] * U1[n0 + i];
        if (tid < 192) {
            int half = tid / 96;
            int r = tid - half * 96;
            int i = r / 12, t = r - i * 12;
            const float* wv = half ? W3 : U3;
            float s = 0.f;
            for (int f = 0; f < 32; f++) s += wv[f] * xs[i * 384 + f * 12 + t];
            float* outp = half ? rr3 : rhs;
            outp[(r0 + i) * 12 + t] = s;
        }
    }
    int f = tid / 12, t = tid - f * 12;
    atomicAdd(&lhs_pre[b * 384 + t * 32 + f], acc);
}

__global__ __launch_bounds__(256) void k_lhs(const float* __restrict__ lhs_pre,
                                             const float* __restrict__ U2,
                                             float* __restrict__ lhs)
{
    int bt = blockIdx.x;
    int tid = threadIdx.x;
    __shared__ float lp[32];
    if (tid < 32) lp[tid] = lhs_pre[bt * 32 + tid];
    __syncthreads();
    for (int q = 0; q < 4; q++) {
        int n = q * 256 + tid;
        float a = 0.f;
        for (int f = 0; f < 32; f++) a += lp[f] * U2[f * NN + n];
        lhs[(size_t)bt * NN + n] = a;
    }
}

__global__ __launch_bounds__(64) void k_prod(const float* __restrict__ lhs,
                                             const float* __restrict__ rhs,
                                             float* __restrict__ prod)
{
    int blk = blockIdx.x;
    int b = blk / 144, r = blk - b * 144;
    int s = r / 12, u = r - s * 12;
    int tid = threadIdx.x;
    float p = 0.f;
    for (int n = tid; n < NN; n += 64)
        p += lhs[((size_t)b * 12 + s) * NN + n] * rhs[((size_t)b * NN + n) * 12 + u];
    for (int o = 32; o > 0; o >>= 1) p += __shfl_xor(p, o);
    if (tid == 0) prod[blk] = p;
}

// E (softmax over t) + EW1[b][t] = sum_u E[b,t,u]*W1[u]
__global__ __launch_bounds__(192) void k_E(const float* __restrict__ prod,
                                           const float* __restrict__ be,
                                           const float* __restrict__ Ve,
                                           const float* __restrict__ W1,
                                           float* __restrict__ E,
                                           float* __restrict__ EW1)
{
    int b = blockIdx.x, tid = threadIdx.x;
    __shared__ float ssig[144], sE[144], mx[12], sm[12];
    if (tid < 144) ssig[tid] = 1.f / (1.f + expf(-(prod[b * 144 + tid] + be[tid])));
    __syncthreads();
    if (tid < 144) {
        int t = tid / 12, u = tid - t * 12;
        float a = 0.f;
        for (int s2 = 0; s2 < 12; s2++) a += Ve[t * 12 + s2] * ssig[s2 * 12 + u];
        sE[tid] = a;
    }
    __syncthreads();
    if (tid < 12) {
        float m = -1e30f;
        for (int t = 0; t < 12; t++) m = fmaxf(m, sE[t * 12 + tid]);
        float s = 0.f;
        for (int t = 0; t < 12; t++) s += expf(sE[t * 12 + tid] - m);
        mx[tid] = m; sm[tid] = s;
    }
    __syncthreads();
    float val = 0.f;
    if (tid < 144) {
        int u = tid % 12;
        val = expf(sE[tid] - mx[u]) / sm[u];
        E[b * 144 + tid] = val;
    }
    __syncthreads();
    if (tid < 144) sE[tid] = val;
    __syncthreads();
    if (tid < 12) {
        float a = 0.f;
        for (int u = 0; u < 12; u++) a += sE[tid * 12 + u] * W1[u];
        EW1[b * 12 + tid] = a;
    }
}

// ---------------- l2/r2 directly from x ----------------
__global__ __launch_bounds__(384) void k_l2r2x(const float* __restrict__ x,
                                               const float* __restrict__ rr3,
                                               const float* __restrict__ E,
                                               const float* __restrict__ EW1,
                                               const float* __restrict__ W2,
                                               float* __restrict__ l2,
                                               float* __restrict__ r2)
{
    __shared__ float xs[8 * 384];
    __shared__ float Es[144], ew[12], rrs[96], lp[8][32];
    int b = blockIdx.y, tid = threadIdx.x;
    int n0 = blockIdx.x * 8;
    size_t r0 = (size_t)b * NN + n0;
    if (tid < 144) Es[tid] = E[b * 144 + tid];
    if (tid < 12) ew[tid] = EW1[b * 12 + tid];
    if (tid < 96) rrs[tid] = rr3[(r0 + tid / 12) * 12 + (tid % 12)];
    for (int i = 0; i < 8; i++) xs[i * 384 + tid] = x[(r0 + i) * 384 + tid];
    __syncthreads();
    if (tid < 256) {
        int i = tid >> 5, f = tid & 31;
        float a = 0.f;
#pragma unroll
        for (int t = 0; t < 12; t++) a += xs[i * 384 + f * 12 + t] * ew[t];
        lp[i][f] = a;
    }
    __syncthreads();
    if (tid < 96) {
        int i = tid / 12, u = tid - i * 12;
        float a = 0.f;
        for (int f = 0; f < 32; f++) a += lp[i][f] * W2[f * 12 + u];
        l2[(r0 + i) * 12 + u] = a;
        float rv = 0.f;
#pragma unroll
        for (int t = 0; t < 12; t++) rv += rrs[i * 12 + t] * Es[t * 12 + u];
        r2[((size_t)b * 12 + u) * NN + n0 + i] = rv;
    }
}

// ---------------- tiled P: Pt[b][k][m] = bf16(sigmoid(l2[b,m,:]·r2[b,:,k] + bs[m,k])) ----------------
__global__ __launch_bounds__(256) void k_Ptile(const float* __restrict__ l2,
                                               const float* __restrict__ r2,
                                               const float* __restrict__ bsin,
                                               unsigned short* __restrict__ Pt)
{
    __shared__ float l2s[64][13];
    __shared__ float r2s[12][64];
    __shared__ float bsS[64][65];
    int k0 = blockIdx.x * 64, m0 = blockIdx.y * 64, b = blockIdx.z;
    int tid = threadIdx.x;
    for (int i = tid; i < 768; i += 256) {
        int r = i / 12, t = i - r * 12;
        l2s[r][t] = l2[((size_t)b * NN + m0 + r) * 12 + t];
    }
    for (int i = tid; i < 768; i += 256) {
        int t = i >> 6, k = i & 63;
        r2s[t][k] = r2[((size_t)b * 12 + t) * NN + k0 + k];
    }
    for (int i = tid; i < 4096; i += 256) {
        int r = i >> 6, c = i & 63;
        bsS[r][c] = bsin[(size_t)(m0 + r) * NN + k0 + c];
    }
    __syncthreads();
    int m = tid & 63, kg = tid >> 6;
    float lv[12];
#pragma unroll
    for (int t = 0; t < 12; t++) lv[t] = l2s[m][t];
#pragma unroll
    for (int s = 0; s < 16; s++) {
        int kl = kg * 16 + s;
        float p = bsS[m][kl];
#pragma unroll
        for (int t = 0; t < 12; t++) p += lv[t] * r2s[t][kl];
        float sg = 1.f / (1.f + expf(-p));
        Pt[((size_t)b * NN + k0 + kl) * NN + m0 + m] = cvt_bf(sg);
    }
}

// Vs fp32 -> bf16
__global__ __launch_bounds__(256) void k_cvt(const float* __restrict__ s,
                                             unsigned short* __restrict__ d)
{
    size_t i = ((size_t)blockIdx.x * 256 + threadIdx.x) * 4;
    float4 v = *(const float4*)(s + i);
    unsigned int p0 = (unsigned int)cvt_bf(v.x) | ((unsigned int)cvt_bf(v.y) << 16);
    unsigned int p1 = (unsigned int)cvt_bf(v.z) | ((unsigned int)cvt_bf(v.w) << 16);
    *(unsigned int*)(d + i) = p0;
    *(unsigned int*)(d + i + 2) = p1;
}

// bf16 transpose 1024x1024
__global__ __launch_bounds__(256) void k_tb16(const unsigned short* __restrict__ s,
                                              unsigned short* __restrict__ d)
{
    __shared__ unsigned short tl[64][65];
    int r0 = blockIdx.y * 64, c0 = blockIdx.x * 64;
    int tid = threadIdx.x;
    int c = tid & 63, rr = tid >> 6;
    for (int i = 0; i < 16; i++)
        tl[rr + i * 4][c] = s[(size_t)(r0 + rr + i * 4) * NN + c0 + c];
    __syncthreads();
    for (int i = 0; i < 16; i++)
        d[(size_t)(c0 + rr + i * 4) * NN + r0 + c] = tl[c][rr + i * 4];
}

// ---------------- MFMA bf16 NT GEMM ----------------
// MODE 2: fp32 exp(out) + colsum atomics. MODE 3: split-K fp32 atomicAdd (bz = k-chunk).
template<int MODE>
__global__ __launch_bounds__(256) void mgemm(const short* __restrict__ A,
                                             const short* __restrict__ B,
                                             void* __restrict__ Cv,
                                             int Kd, int kchunk,
                                             int ldA, int ldB, int ldC,
                                             long sA, long sB, long sC,
                                             float* __restrict__ colsum)
{
    int bz = blockIdx.z;
    const short* Ab = A + (size_t)bz * sA;
    const short* Bb = B + (size_t)bz * sB;
    int i0 = blockIdx.y * 128, j0 = blockIdx.x * 128;
    __shared__ short sm[16384];            // As [128][64] @0, Bs [128][64] @8192
    int tid = threadIdx.x;
    int ln = tid & 63, wv = tid >> 6;
    int wm = (wv >> 1) * 64, wn = (wv & 1) * 64;
    int fr = ln & 15, fk = ln >> 4;
    f32x4 acc[4][4];
#pragma unroll
    for (int a = 0; a < 4; a++)
#pragma unroll
        for (int b2 = 0; b2 < 4; b2++) acc[a][b2] = (f32x4)(0.f);

    int k_lo = 0, k_hi = Kd;
    if constexpr (MODE == 3) { k_lo = bz * kchunk; k_hi = k_lo + kchunk; }

    for (int k0 = k_lo; k0 < k_hi; k0 += 64) {
#pragma unroll
        for (int q = 0; q < 4; q++) {
            int e = q * 2048 + tid * 8;
            const short* src = Ab + (size_t)(i0 + (e >> 6)) * ldA + k0 + (e & 63);
            gll16(src, sm + e);
        }
#pragma unroll
        for (int q = 0; q < 4; q++) {
            int e = q * 2048 + tid * 8;
            const short* src = Bb + (size_t)(j0 + (e >> 6)) * ldB + k0 + (e & 63);
            gll16(src, sm + 8192 + e);
        }
        __syncthreads();
#pragma unroll
        for (int ks = 0; ks < 2; ks++) {
            bf16x8 av[4], bv[4];
#pragma unroll
            for (int mi = 0; mi < 4; mi++)
                av[mi] = *(const bf16x8*)(sm + (wm + mi * 16 + fr) * 64 + ks * 32 + fk * 8);
#pragma unroll
            for (int nj = 0; nj < 4; nj++)
                bv[nj] = *(const bf16x8*)(sm + 8192 + (wn + nj * 16 + fr) * 64 + ks * 32 + fk * 8);
#pragma unroll
            for (int mi = 0; mi < 4; mi++)
#pragma unroll
                for (int nj = 0; nj < 4; nj++)
                    acc[mi][nj] = __builtin_amdgcn_mfma_f32_16x16x32_bf16(av[mi], bv[nj], acc[mi][nj], 0, 0, 0);
        }
        __syncthreads();
    }
    if constexpr (MODE == 2) {
        float* Cb = (float*)Cv + (size_t)bz * sC;
#pragma unroll
        for (int nj = 0; nj < 4; nj++) {
            float cs = 0.f;
            int col = j0 + wn + nj * 16 + fr;
#pragma unroll
            for (int mi = 0; mi < 4; mi++) {
                int row = i0 + wm + mi * 16 + fk * 4;
#pragma unroll
                for (int r = 0; r < 4; r++) {
                    float e = expf(acc[mi][nj][r]);
                    Cb[(size_t)(row + r) * ldC + col] = e;
                    cs += e;
                }
            }
            cs += __shfl_xor(cs, 16);
            cs += __shfl_xor(cs, 32);
            if (ln < 16) atomicAdd(&colsum[(size_t)bz * NN + col], cs);
        }
    } else if constexpr (MODE == 3) {
        float* Cb = (float*)Cv;
#pragma unroll
        for (int mi = 0; mi < 4; mi++)
#pragma unroll
            for (int nj = 0; nj < 4; nj++) {
                int row = i0 + wm + mi * 16 + fk * 4;
                int col = j0 + wn + nj * 16 + fr;
#pragma unroll
                for (int r = 0; r < 4; r++)
                    atomicAdd(&Cb[(size_t)(row + r) * ldC + col], acc[mi][nj][r]);
            }
    }
}

// ---------------- dual-A MFMA GEMM for h1/h2: stages Xt B-tile once ----------------
// C1[b][m][j] = sum_n At1[b][m][n]*Xt[b][j][n];  C2 same with At2. 128x128 tiles, K=1024.
__global__ __launch_bounds__(256) void mgemm_h2(const short* __restrict__ A1,
                                                const short* __restrict__ A2,
                                                const short* __restrict__ B,
                                                unsigned short* __restrict__ C1,
                                                unsigned short* __restrict__ C2)
{
    int b = blockIdx.z;
    const short* A1b = A1 + (size_t)b * NN * NN;
    const short* A2b = A2 + (size_t)b * NN * NN;
    const short* Bb  = B  + (size_t)b * 384 * NN;
    int i0 = blockIdx.y * 128, j0 = blockIdx.x * 128;
    __shared__ short sm[24576];     // A1 @0, A2 @8192, B @16384
    int tid = threadIdx.x;
    int ln = tid & 63, wv = tid >> 6;
    int wm = (wv >> 1) * 64, wn = (wv & 1) * 64;
    int fr = ln & 15, fk = ln >> 4;
    f32x4 acc1[4][4], acc2[4][4];
#pragma unroll
    for (int a = 0; a < 4; a++)
#pragma unroll
        for (int c = 0; c < 4; c++) { acc1[a][c] = (f32x4)(0.f); acc2[a][c] = (f32x4)(0.f); }

    for (int k0 = 0; k0 < NN; k0 += 64) {
#pragma unroll
        for (int q = 0; q < 4; q++) {
            int e = q * 2048 + tid * 8;
            gll16(A1b + (size_t)(i0 + (e >> 6)) * NN + k0 + (e & 63), sm + e);
        }
#pragma unroll
        for (int q = 0; q < 4; q++) {
            int e = q * 2048 + tid * 8;
            gll16(A2b + (size_t)(i0 + (e >> 6)) * NN + k0 + (e & 63), sm + 8192 + e);
        }
#pragma unroll
        for (int q = 0; q < 4; q++) {
            int e = q * 2048 + tid * 8;
            gll16(Bb + (size_t)(j0 + (e >> 6)) * NN + k0 + (e & 63), sm + 16384 + e);
        }
        __syncthreads();
#pragma unroll
        for (int ks = 0; ks < 2; ks++) {
            bf16x8 a1v[4], a2v[4], bv[4];
#pragma unroll
            for (int mi = 0; mi < 4; mi++) {
                int off = (wm + mi * 16 + fr) * 64 + ks * 32 + fk * 8;
                a1v[mi] = *(const bf16x8*)(sm + off);
                a2v[mi] = *(const bf16x8*)(sm + 8192 + off);
            }
#pragma unroll
            for (int nj = 0; nj < 4; nj++)
                bv[nj] = *(const bf16x8*)(sm + 16384 + (wn + nj * 16 + fr) * 64 + ks * 32 + fk * 8);
#pragma unroll
            for (int mi = 0; mi < 4; mi++)
#pragma unroll
                for (int nj = 0; nj < 4; nj++) {
                    acc1[mi][nj] = __builtin_amdgcn_mfma_f32_16x16x32_bf16(a1v[mi], bv[nj], acc1[mi][nj], 0, 0, 0);
                    acc2[mi][nj] = __builtin_amdgcn_mfma_f32_16x16x32_bf16(a2v[mi], bv[nj], acc2[mi][nj], 0, 0, 0);
                }
        }
        __syncthreads();
    }
#pragma unroll
    for (int mi = 0; mi < 4; mi++)
#pragma unroll
        for (int nj = 0; nj < 4; nj++) {
            int row = i0 + wm + mi * 16 + fk * 4;
            int col = j0 + wn + nj * 16 + fr;
#pragma unroll
            for (int r = 0; r < 4; r++) {
                size_t o = ((size_t)b * NN + row + r) * 384 + col;
                C1[o] = cvt_bf(acc1[mi][nj][r]);
                C2[o] = cvt_bf(acc2[mi][nj][r]);
            }
        }
}

// ---------------- normalize + threshold + At1 + At2 + sdiag (fully fused) ----------------
__global__ __launch_bounds__(256) void k_normprep2(float* __restrict__ spat,
                                                   const float* __restrict__ colsum,
                                                   const float* __restrict__ sup,
                                                   const float* __restrict__ supsq,
                                                   unsigned short* __restrict__ At1,
                                                   unsigned short* __restrict__ At2,
                                                   float* __restrict__ sdiag)
{
    __shared__ unsigned short t1[64][66];
    __shared__ unsigned short t2[64][66];
    int b = blockIdx.z;
    int n0 = blockIdx.y * 64, m0 = blockIdx.x * 64;
    int tid = threadIdx.x;
    int c = tid & 63, r0 = tid >> 6;
    const float thr = (1.0f / 1024.0f) / 0.6f;
    float inv = 1.f / colsum[(size_t)b * NN + m0 + c];
    float* sp = spat + (size_t)b * NN * NN;
    for (int i = 0; i < 16; i++) {
        int r = r0 + i * 4;
        size_t idx = (size_t)(n0 + r) * NN + m0 + c;
        float v = sp[idx] * inv;
        v = (v < thr) ? 0.f : v;
        sp[idx] = v;
        if (n0 + r == m0 + c) sdiag[(size_t)b * NN + n0 + r] = v;
        t1[r][c] = cvt_bf(sup[(size_t)(n0 + r) * NN + m0 + c] * v);
        float p2 = 2.f * supsq[(size_t)(n0 + r) * NN + m0 + c]
                 - (((n0 + r) == (m0 + c)) ? 1.f : 0.f);
        t2[r][c] = cvt_bf(p2 * v);
    }
    __syncthreads();
    int c2 = tid & 31, r4 = tid >> 5;
    size_t ob = ((size_t)b * NN + m0) * NN + n0;
    for (int i = 0; i < 8; i++) {
        int rr = r4 + i * 8;
        unsigned int v1 = (unsigned int)t1[2 * c2][rr] | ((unsigned int)t1[2 * c2 + 1][rr] << 16);
        unsigned int v2 = (unsigned int)t2[2 * c2][rr] | ((unsigned int)t2[2 * c2 + 1][rr] << 16);
        *(unsigned int*)(At1 + ob + (size_t)rr * NN + 2 * c2) = v1;
        *(unsigned int*)(At2 + ob + (size_t)rr * NN + 2 * c2) = v2;
    }
}

// ---------------- support graph (fp32 + bf16 copies) ----------------
__global__ __launch_bounds__(256) void k_sup(const float* __restrict__ emb,
                                             float* __restrict__ sup,
                                             unsigned short* __restrict__ supB)
{
    int n = blockIdx.x, tid = threadIdx.x;
    __shared__ float en[16];
    if (tid < 16) en[tid] = emb[n * 16 + tid];
    __syncthreads();
    float v[4];
#pragma unroll
    for (int q = 0; q < 4; q++) {
        int m = q * 256 + tid;
        float d = 0.f;
#pragma unroll
        for (int dd = 0; dd < 16; dd++) d += en[dd] * emb[m * 16 + dd];
        v[q] = fmaxf(d, 0.f);
    }
    float mx = fmaxf(fmaxf(v[0], v[1]), fmaxf(v[2], v[3]));
    for (int o = 32; o > 0; o >>= 1) mx = fmaxf(mx, __shfl_xor(mx, o));
    __shared__ float red[4];
    if ((tid & 63) == 0) red[tid >> 6] = mx;
    __syncthreads();
    mx = fmaxf(fmaxf(red[0], red[1]), fmaxf(red[2], red[3]));
    float e[4];
    float s = 0.f;
#pragma unroll
    for (int q = 0; q < 4; q++) { e[q] = expf(v[q] - mx); s += e[q]; }
    for (int o = 32; o > 0; o >>= 1) s += __shfl_xor(s, o);
    __shared__ float red2[4];
    if ((tid & 63) == 0) red2[tid >> 6] = s;
    __syncthreads();
    s = red2[0] + red2[1] + red2[2] + red2[3];
    float inv = 1.f / s;
#pragma unroll
    for (int q = 0; q < 4; q++) {
        float val = e[q] * inv;
        sup[(size_t)n * NN + q * 256 + tid] = val;
        supB[(size_t)n * NN + q * 256 + tid] = cvt_bf(val);
    }
}

// Xt[b][j][n] = bf16(x[b][n][j])  (B operand for h-GEMMs)
__global__ __launch_bounds__(256) void k_xt(const float* __restrict__ x,
                                            unsigned short* __restrict__ Xt)
{
    __shared__ float tl[64][65];
    int b = blockIdx.z;
    int n0 = blockIdx.y * 64, j0 = blockIdx.x * 64;
    int tid = threadIdx.x;
    int c = tid & 63, r0 = tid >> 6;
    for (int i = 0; i < 16; i++) {
        int r = r0 + i * 4;
        tl[r][c] = x[((size_t)b * NN + n0 + r) * 384 + j0 + c];
    }
    __syncthreads();
    int c2 = tid & 31, r4 = tid >> 5;
    unsigned short* ob = Xt + ((size_t)b * 384 + j0) * NN + n0;
    for (int i = 0; i < 8; i++) {
        int jj = r4 + i * 8;
        unsigned int v0 = cvt_bf(tl[2 * c2][jj]);
        unsigned int v1 = cvt_bf(tl[2 * c2 + 1][jj]);
        *(unsigned int*)(ob + (size_t)jj * NN + 2 * c2) = v0 | (v1 << 16);
    }
}

// ---------------- weight prep ----------------
__global__ __launch_bounds__(192) void k_wnorm(const float* __restrict__ tcv,
                                               const float* __restrict__ tcg,
                                               unsigned short* __restrict__ Wr)
{
    int o = blockIdx.x, tid = threadIdx.x;
    float t = tcv[o * 192 + tid];
    float p = t * t;
    for (int off = 32; off > 0; off >>= 1) p += __shfl_xor(p, off);
    __shared__ float wsr[3];
    if ((tid & 63) == 0) wsr[tid >> 6] = p;
    __syncthreads();
    float sum = wsr[0] + wsr[1] + wsr[2];
    int c = tid / 3, dt = tid - c * 3;
    Wr[o * 192 + dt * 64 + c] = cvt_bf(t * (tcg[o] / sqrtf(sum)));
}

__global__ __launch_bounds__(256) void k_prepw(const float* __restrict__ Theta,
                                               const float* __restrict__ rcw,
                                               unsigned short* __restrict__ Th,
                                               unsigned short* __restrict__ Rc)
{
    int tid = threadIdx.x;
    for (int i = tid; i < 6144; i += 256) {
        int o = i / 96, rem = i - o * 96;
        int kind = rem >> 5, f = rem & 31;
        Th[i] = cvt_bf(Theta[kind * 2048 + f * 64 + o]);
    }
    for (int i = tid; i < 2048; i += 256) Rc[i] = cvt_bf(rcw[i]);
}

// ---------------- MFMA fused tail: 4 nodes/block, sdiag buffer ----------------
__global__ __launch_bounds__(256) void k_tail(const float* __restrict__ x,
                                              const unsigned short* __restrict__ h1,
                                              const unsigned short* __restrict__ h2,
                                              const float* __restrict__ sdiag,
                                              const unsigned short* __restrict__ Th,
                                              const unsigned short* __restrict__ Wr,
                                              const unsigned short* __restrict__ Rc,
                                              const float* __restrict__ tcb,
                                              const float* __restrict__ rcb,
                                              const float* __restrict__ lnw,
                                              const float* __restrict__ lnb,
                                              float* __restrict__ out)
{
    int b = blockIdx.y;
    int node0 = blockIdx.x * 4;
    int tid = threadIdx.x;
    int ln = tid & 63, wv = tid >> 6;
    int fr = ln & 15, fk = ln >> 4;

    __shared__ union {
        struct { unsigned short xt[1920], h1t[1920], h2t[1920], gcn[4032]; } a;
        float Y[48 * 65];
    } u;
    __shared__ float sdp[48];
    __shared__ float lnwS[64], lnbS[64], tbS[64];
    __shared__ float muS[48], rsS[48];

    size_t rowb = ((size_t)b * NN + node0) * 384;
    for (int i = tid; i < 1536; i += 256) {
        int node = i / 384, j = i - node * 384;
        int f = j / 12, t = j - f * 12;
        int la = node * 480 + t * 40 + f;
        u.a.xt[la]  = cvt_bf(x[rowb + i]);
        u.a.h1t[la] = h1[rowb + i];
        u.a.h2t[la] = h2[rowb + i];
    }
    for (int i = tid; i < 576; i += 256) {
        int node = i / 144, r = i - node * 144;
        int rr = (r < 72) ? 0 : 13;
        u.a.gcn[node * 1008 + rr * 72 + (r % 72)] = 0;
    }
    if (tid < 48) sdp[tid] = sdiag[(size_t)b * NN + node0 + tid / 12];
    if (tid < 64) { lnwS[tid] = lnw[tid]; lnbS[tid] = lnb[tid]; tbS[tid] = tcb[tid] + rcb[tid]; }

    int ocol = wv * 16 + fr;
    bf16x8 bTh[3], bWr[6], bRc;
#pragma unroll
    for (int kb = 0; kb < 3; kb++)
        bTh[kb] = *(const bf16x8*)((const short*)Th + (size_t)ocol * 96 + kb * 32 + fk * 8);
#pragma unroll
    for (int kb = 0; kb < 6; kb++)
        bWr[kb] = *(const bf16x8*)((const short*)Wr + (size_t)ocol * 192 + kb * 32 + fk * 8);
    bRc = *(const bf16x8*)((const short*)Rc + (size_t)ocol * 32 + fk * 8);

    int na[3], ta[3];
#pragma unroll
    for (int rb = 0; rb < 3; rb++) {
        int p = rb * 16 + fr;
        na[rb] = p / 12; ta[rb] = p - na[rb] * 12;
    }
    __syncthreads();

    f32x4 acc[3];
#pragma unroll
    for (int rb = 0; rb < 3; rb++) {
        int ax = na[rb] * 480 + ta[rb] * 40 + fk * 8;
        bf16x8 avx = *(const bf16x8*)(u.a.xt + ax);
        f32x4 z = (f32x4)(0.f);
        acc[rb] = __builtin_amdgcn_mfma_f32_16x16x32_bf16(avx, bTh[0], z, 0, 0, 0);
#pragma unroll
        for (int r = 0; r < 4; r++) acc[rb][r] *= sdp[rb * 16 + fk * 4 + r];
        bf16x8 av1 = *(const bf16x8*)(u.a.h1t + ax);
        acc[rb] = __builtin_amdgcn_mfma_f32_16x16x32_bf16(av1, bTh[1], acc[rb], 0, 0, 0);
        bf16x8 av2 = *(const bf16x8*)(u.a.h2t + ax);
        acc[rb] = __builtin_amdgcn_mfma_f32_16x16x32_bf16(av2, bTh[2], acc[rb], 0, 0, 0);
    }
#pragma unroll
    for (int rb = 0; rb < 3; rb++) {
#pragma unroll
        for (int r = 0; r < 4; r++) {
            int pc = rb * 16 + fk * 4 + r;
            int nc = pc / 12, tc2 = pc - nc * 12;
            u.a.gcn[nc * 1008 + (tc2 + 1) * 72 + wv * 16 + fr] = cvt_bf(fmaxf(acc[rb][r], 0.f));
        }
    }
    __syncthreads();
#pragma unroll
    for (int rb = 0; rb < 3; rb++) {
        f32x4 a2 = (f32x4)(0.f);
#pragma unroll
        for (int kb = 0; kb < 6; kb++) {
            int dt = kb >> 1, c0 = (kb & 1) * 32;
            bf16x8 ag = *(const bf16x8*)(u.a.gcn + na[rb] * 1008 + (ta[rb] + dt) * 72 + c0 + fk * 8);
            a2 = __builtin_amdgcn_mfma_f32_16x16x32_bf16(ag, bWr[kb], a2, 0, 0, 0);
        }
        int ax = na[rb] * 480 + ta[rb] * 40 + fk * 8;
        bf16x8 avx = *(const bf16x8*)(u.a.xt + ax);
        acc[rb] = __builtin_amdgcn_mfma_f32_16x16x32_bf16(avx, bRc, a2, 0, 0, 0);
    }
    __syncthreads();
    float tb = tbS[ocol];
#pragma unroll
    for (int rb = 0; rb < 3; rb++)
#pragma unroll
        for (int r = 0; r < 4; r++)
            u.Y[(rb * 16 + fk * 4 + r) * 65 + ocol] = acc[rb][r] + tb;
    __syncthreads();
    if (tid < 48) {
        float s = 0.f, s2 = 0.f;
        for (int o = 0; o < 64; o++) {
            float v = u.Y[tid * 65 + o];
            s += v; s2 += v * v;
        }
        float mm = s * (1.f / 64.f);
        float var = s2 * (1.f / 64.f) - mm * mm;
        muS[tid] = mm; rsS[tid] = rsqrtf(var + 1e-5f);
    }
    __syncthreads();
    float* ob = out + rowb * 2;
    for (int i = tid; i < 3072; i += 256) {
        int node = i / 768, rr = i - node * 768;
        int o = rr / 12, t = rr - o * 12;
        int p = node * 12 + t;
        ob[i] = (u.Y[p * 65 + o] - muS[p]) * rsS[p] * lnwS[o] + lnbS[o];
    }
}

extern "C" void kernel_launch(void* const* d_in, const int* in_sizes, int n_in,
                              void* d_out, int out_size, void* d_ws, size_t ws_size,
                              hipStream_t stream)
{
    const float* x    = (const float*)d_in[0];
    const float* emb  = (const float*)d_in[1];
    const float* W1   = (const float*)d_in[2];
    const float* W2   = (const float*)d_in[3];
    const float* W3   = (const float*)d_in[4];
    const float* bs   = (const float*)d_in[5];
    const float* Vs   = (const float*)d_in[6];
    const float* U1   = (const float*)d_in[7];
    const float* U2   = (const float*)d_in[8];
    const float* U3   = (const float*)d_in[9];
    const float* be   = (const float*)d_in[10];
    const float* Ve   = (const float*)d_in[11];
    const float* Theta= (const float*)d_in[12];
    const float* tcv  = (const float*)d_in[13];
    const float* tcg  = (const float*)d_in[14];
    const float* tcb  = (const float*)d_in[15];
    const float* rcw  = (const float*)d_in[16];
    const float* rcb  = (const float*)d_in[17];
    const float* lnw  = (const float*)d_in[18];
    const float* lnb  = (const float*)d_in[19];

    float* xres = (float*)d_out;                       // B*N*FT*T fp32 (scratch for At2 until k_tail)
    float* spat = xres + (size_t)NB * NN * NFT * NT;   // B*N*N fp32

    char* base = (char*)d_ws;
    unsigned short* Pt   = (unsigned short*)(base + 0);   // then supB/supT, then At1
    unsigned short* supB = (unsigned short*)(base + 0);
    unsigned short* supT = (unsigned short*)(base + 2097152);
    unsigned short* At1  = (unsigned short*)(base + 0);
    unsigned short* At2  = (unsigned short*)xres;          // d_out scratch (32 MB < 48 MB)
    unsigned short* Xt  = (unsigned short*)(base + 33554432);   // live k_xt -> mgemm_h2
    unsigned short* h1  = (unsigned short*)(base + 46137344);
    unsigned short* h2  = (unsigned short*)(base + 58720256);
    unsigned short* Vsb = (unsigned short*)(base + 71303168);
    float* colsum  = (float*)(base + 73400320);
    float* sdiag   = (float*)(base + 73465856);
    float* sup     = (float*)(base + 77594624);
    float* supsq   = (float*)(base + 81788928);
    float* lhs_pre = (float*)(base + 85983232);
    float* lhs     = (float*)(base + 86007808);
    float* rhs     = (float*)(base + 86794240);
    float* rr3     = (float*)(base + 87580672);
    float* prod    = (float*)(base + 88367104);
    float* E       = (float*)(base + 88376320);
    float* EW1     = (float*)(base + 88385536);
    float* l2      = (float*)(base + 88386560);
    float* r2      = (float*)(base + 89172992);
    unsigned short* Wr = (unsigned short*)(base + 89959424);
    unsigned short* Th = (unsigned short*)(base + 89984000);
    unsigned short* Rc = (unsigned short*)(base + 89996288);

    hipMemsetAsync(lhs_pre, 0, 6144 * sizeof(float), stream);
    hipMemsetAsync(supsq, 0, (size_t)NN * NN * sizeof(float), stream);

    // pre-pass
    k_pre<<<dim3(16, 16), 384, 0, stream>>>(x, U1, U3, W3, lhs_pre, rhs, rr3);
    k_lhs<<<192, 256, 0, stream>>>(lhs_pre, U2, lhs);
    k_prod<<<2304, 64, 0, stream>>>(lhs, rhs, prod);
    k_E<<<16, 192, 0, stream>>>(prod, be, Ve, W1, E, EW1);
    // spatial attention
    k_l2r2x<<<dim3(128, 16), 384, 0, stream>>>(x, rr3, E, EW1, W2, l2, r2);
    k_Ptile<<<dim3(16, 16, 16), 256, 0, stream>>>(l2, r2, bs, Pt);
    k_cvt<<<1024, 256, 0, stream>>>(Vs, Vsb);
    hipMemsetAsync(colsum, 0, (size_t)NB * NN * sizeof(float), stream);
    mgemm<2><<<dim3(8, 8, 16), 256, 0, stream>>>((const short*)Vsb, (const short*)Pt,
        (void*)spat, NN, 0, NN, NN, NN, 0L, (long)NN * NN, (long)NN * NN, colsum);
    // graph supports
    k_sup<<<1024, 256, 0, stream>>>(emb, sup, supB);
    k_tb16<<<dim3(16, 16), 256, 0, stream>>>(supB, supT);
    mgemm<3><<<dim3(8, 8, 4), 256, 0, stream>>>((const short*)supB, (const short*)supT,
        (void*)supsq, NN, 256, NN, NN, NN, 0L, 0L, 0L, nullptr);
    // normalize + threshold + masked adjacencies + diagonal
    k_normprep2<<<dim3(16, 16, 16), 256, 0, stream>>>(spat, colsum, sup, supsq, At1, At2, sdiag);
    k_xt<<<dim3(6, 16, 16), 256, 0, stream>>>(x, Xt);
    mgemm_h2<<<dim3(3, 8, 16), 256, 0, stream>>>((const short*)At1, (const short*)At2,
        (const short*)Xt, h1, h2);
    // tail
    k_wnorm<<<64, 192, 0, stream>>>(tcv, tcg, Wr);
    k_prepw<<<1, 256, 0, stream>>>(Theta, rcw, Th, Rc);
    k_tail<<<dim3(256, 16), 256, 0, stream>>>(x, h1, h2, sdiag, Th, Wr, Rc,
                                              tcb, rcb, lnw, lnb, xres);
}

// Round 8
// 337.288 us; speedup vs baseline: 1.1503x; 1.0480x over previous
//
#include <hip/hip_runtime.h>
#include <math.h>

#define NB 16      // B
#define NN 1024    // N
#define NF 32      // F
#define NT 12      // T
#define NFC 64
#define NFT 64

typedef __attribute__((ext_vector_type(8))) short bf16x8;
typedef __attribute__((ext_vector_type(4))) float f32x4;

__device__ inline unsigned short cvt_bf(float f) {
    unsigned int u = __float_as_uint(f);
    u += 0x7fff + ((u >> 16) & 1);
    return (unsigned short)(u >> 16);
}
__device__ inline float bf2f(unsigned short u) {
    return __uint_as_float(((unsigned int)u) << 16);
}
__device__ inline void gll16(const short* g, short* l) {
    __builtin_amdgcn_global_load_lds((const __attribute__((address_space(1))) void*)g,
                                     (__attribute__((address_space(3))) void*)l, 16, 0, 0);
}

// ---------------- fused pre-pass: lhs_pre (U1), rhs (U3), rr3 (W3), Xrow (bf16) ----------------
// x fp32 read -> also emit bf16 row-major copy for l2r2x/xt consumers.
__global__ __launch_bounds__(384) void k_pre(const float* __restrict__ x,
                                             const float* __restrict__ U1,
                                             const float* __restrict__ U3,
                                             const float* __restrict__ W3,
                                             float* __restrict__ lhs_pre,
                                             float* __restrict__ rhs,
                                             float* __restrict__ rr3,
                                             unsigned short* __restrict__ Xrow)
{
    __shared__ float xs[8 * 384];
    int b = blockIdx.x, ch = blockIdx.y, tid = threadIdx.x;
    float acc = 0.f;
    for (int c8 = 0; c8 < 8; c8++) {
        int n0 = ch * 64 + c8 * 8;
        size_t r0 = (size_t)b * NN + n0;
        __syncthreads();
        for (int i = 0; i < 8; i++) xs[i * 384 + tid] = x[(r0 + i) * 384 + tid];
        __syncthreads();
        for (int i = 0; i < 8; i++) {
            float v = xs[i * 384 + tid];
            acc += v * U1[n0 + i];
            Xrow[(r0 + i) * 384 + tid] = cvt_bf(v);
        }
        if (tid < 192) {
            int half = tid / 96;
            int r = tid - half * 96;
            int i = r / 12, t = r - i * 12;
            const float* wv = half ? W3 : U3;
            float s = 0.f;
            for (int f = 0; f < 32; f++) s += wv[f] * xs[i * 384 + f * 12 + t];
            float* outp = half ? rr3 : rhs;
            outp[(r0 + i) * 12 + t] = s;
        }
    }
    int f = tid / 12, t = tid - f * 12;
    atomicAdd(&lhs_pre[b * 384 + t * 32 + f], acc);
}

__global__ __launch_bounds__(256) void k_lhs(const float* __restrict__ lhs_pre,
                                             const float* __restrict__ U2,
                                             float* __restrict__ lhs)
{
    int bt = blockIdx.x;
    int tid = threadIdx.x;
    __shared__ float lp[32];
    if (tid < 32) lp[tid] = lhs_pre[bt * 32 + tid];
    __syncthreads();
    for (int q = 0; q < 4; q++) {
        int n = q * 256 + tid;
        float a = 0.f;
        for (int f = 0; f < 32; f++) a += lp[f] * U2[f * NN + n];
        lhs[(size_t)bt * NN + n] = a;
    }
}

__global__ __launch_bounds__(64) void k_prod(const float* __restrict__ lhs,
                                             const float* __restrict__ rhs,
                                             float* __restrict__ prod)
{
    int blk = blockIdx.x;
    int b = blk / 144, r = blk - b * 144;
    int s = r / 12, u = r - s * 12;
    int tid = threadIdx.x;
    float p = 0.f;
    for (int n = tid; n < NN; n += 64)
        p += lhs[((size_t)b * 12 + s) * NN + n] * rhs[((size_t)b * NN + n) * 12 + u];
    for (int o = 32; o > 0; o >>= 1) p += __shfl_xor(p, o);
    if (tid == 0) prod[blk] = p;
}

// E (softmax over t) + EW1[b][t] = sum_u E[b,t,u]*W1[u]
__global__ __launch_bounds__(192) void k_E(const float* __restrict__ prod,
                                           const float* __restrict__ be,
                                           const float* __restrict__ Ve,
                                           const float* __restrict__ W1,
                                           float* __restrict__ E,
                                           float* __restrict__ EW1)
{
    int b = blockIdx.x, tid = threadIdx.x;
    __shared__ float ssig[144], sE[144], mx[12], sm[12];
    if (tid < 144) ssig[tid] = 1.f / (1.f + expf(-(prod[b * 144 + tid] + be[tid])));
    __syncthreads();
    if (tid < 144) {
        int t = tid / 12, u = tid - t * 12;
        float a = 0.f;
        for (int s2 = 0; s2 < 12; s2++) a += Ve[t * 12 + s2] * ssig[s2 * 12 + u];
        sE[tid] = a;
    }
    __syncthreads();
    if (tid < 12) {
        float m = -1e30f;
        for (int t = 0; t < 12; t++) m = fmaxf(m, sE[t * 12 + tid]);
        float s = 0.f;
        for (int t = 0; t < 12; t++) s += expf(sE[t * 12 + tid] - m);
        mx[tid] = m; sm[tid] = s;
    }
    __syncthreads();
    float val = 0.f;
    if (tid < 144) {
        int u = tid % 12;
        val = expf(sE[tid] - mx[u]) / sm[u];
        E[b * 144 + tid] = val;
    }
    __syncthreads();
    if (tid < 144) sE[tid] = val;
    __syncthreads();
    if (tid < 12) {
        float a = 0.f;
        for (int u = 0; u < 12; u++) a += sE[tid * 12 + u] * W1[u];
        EW1[b * 12 + tid] = a;
    }
}

// ---------------- l2/r2 from Xrow (bf16) ----------------
__global__ __launch_bounds__(384) void k_l2r2x(const unsigned short* __restrict__ Xrow,
                                               const float* __restrict__ rr3,
                                               const float* __restrict__ E,
                                               const float* __restrict__ EW1,
                                               const float* __restrict__ W2,
                                               float* __restrict__ l2,
                                               float* __restrict__ r2)
{
    __shared__ float xs[8 * 384];
    __shared__ float Es[144], ew[12], rrs[96], lp[8][32];
    int b = blockIdx.y, tid = threadIdx.x;
    int n0 = blockIdx.x * 8;
    size_t r0 = (size_t)b * NN + n0;
    if (tid < 144) Es[tid] = E[b * 144 + tid];
    if (tid < 12) ew[tid] = EW1[b * 12 + tid];
    if (tid < 96) rrs[tid] = rr3[(r0 + tid / 12) * 12 + (tid % 12)];
    for (int i = 0; i < 8; i++) xs[i * 384 + tid] = bf2f(Xrow[(r0 + i) * 384 + tid]);
    __syncthreads();
    if (tid < 256) {
        int i = tid >> 5, f = tid & 31;
        float a = 0.f;
#pragma unroll
        for (int t = 0; t < 12; t++) a += xs[i * 384 + f * 12 + t] * ew[t];
        lp[i][f] = a;
    }
    __syncthreads();
    if (tid < 96) {
        int i = tid / 12, u = tid - i * 12;
        float a = 0.f;
        for (int f = 0; f < 32; f++) a += lp[i][f] * W2[f * 12 + u];
        l2[(r0 + i) * 12 + u] = a;
        float rv = 0.f;
#pragma unroll
        for (int t = 0; t < 12; t++) rv += rrs[i * 12 + t] * Es[t * 12 + u];
        r2[((size_t)b * 12 + u) * NN + n0 + i] = rv;
    }
}

// Xt[b][j][n] = Xrow[b][n][j]  (pure bf16 transpose; B operand for h-GEMMs)
__global__ __launch_bounds__(256) void k_xt(const unsigned short* __restrict__ Xrow,
                                            unsigned short* __restrict__ Xt)
{
    __shared__ unsigned short tl[64][66];
    int b = blockIdx.z;
    int n0 = blockIdx.y * 64, j0 = blockIdx.x * 64;
    int tid = threadIdx.x;
    int c = tid & 63, r0 = tid >> 6;
    for (int i = 0; i < 16; i++) {
        int r = r0 + i * 4;
        tl[r][c] = Xrow[((size_t)b * NN + n0 + r) * 384 + j0 + c];
    }
    __syncthreads();
    int c2 = tid & 31, r4 = tid >> 5;
    unsigned short* ob = Xt + ((size_t)b * 384 + j0) * NN + n0;
    for (int i = 0; i < 8; i++) {
        int jr = r4 + i * 8;
        unsigned int v0 = (unsigned int)tl[2 * c2][jr] | ((unsigned int)tl[2 * c2 + 1][jr] << 16);
        *(unsigned int*)(ob + (size_t)jr * NN + 2 * c2) = v0;
    }
}

// ---------------- tiled P: Pt[b][k][m] = bf16(sigmoid(l2[b,m,:]·r2[b,:,k] + bs[m,k])) ----------------
__global__ __launch_bounds__(256) void k_Ptile(const float* __restrict__ l2,
                                               const float* __restrict__ r2,
                                               const float* __restrict__ bsin,
                                               unsigned short* __restrict__ Pt)
{
    __shared__ float l2s[64][13];
    __shared__ float r2s[12][64];
    __shared__ float bsS[64][65];
    int k0 = blockIdx.x * 64, m0 = blockIdx.y * 64, b = blockIdx.z;
    int tid = threadIdx.x;
    for (int i = tid; i < 768; i += 256) {
        int r = i / 12, t = i - r * 12;
        l2s[r][t] = l2[((size_t)b * NN + m0 + r) * 12 + t];
    }
    for (int i = tid; i < 768; i += 256) {
        int t = i >> 6, k = i & 63;
        r2s[t][k] = r2[((size_t)b * 12 + t) * NN + k0 + k];
    }
    for (int i = tid; i < 4096; i += 256) {
        int r = i >> 6, c = i & 63;
        bsS[r][c] = bsin[(size_t)(m0 + r) * NN + k0 + c];
    }
    __syncthreads();
    int m = tid & 63, kg = tid >> 6;
    float lv[12];
#pragma unroll
    for (int t = 0; t < 12; t++) lv[t] = l2s[m][t];
#pragma unroll
    for (int s = 0; s < 16; s++) {
        int kl = kg * 16 + s;
        float p = bsS[m][kl];
#pragma unroll
        for (int t = 0; t < 12; t++) p += lv[t] * r2s[t][kl];
        float sg = 1.f / (1.f + expf(-p));
        Pt[((size_t)b * NN + k0 + kl) * NN + m0 + m] = cvt_bf(sg);
    }
}

// Vs fp32 -> bf16
__global__ __launch_bounds__(256) void k_cvt(const float* __restrict__ s,
                                             unsigned short* __restrict__ d)
{
    size_t i = ((size_t)blockIdx.x * 256 + threadIdx.x) * 4;
    float4 v = *(const float4*)(s + i);
    unsigned int p0 = (unsigned int)cvt_bf(v.x) | ((unsigned int)cvt_bf(v.y) << 16);
    unsigned int p1 = (unsigned int)cvt_bf(v.z) | ((unsigned int)cvt_bf(v.w) << 16);
    *(unsigned int*)(d + i) = p0;
    *(unsigned int*)(d + i + 2) = p1;
}

// bf16 transpose 1024x1024
__global__ __launch_bounds__(256) void k_tb16(const unsigned short* __restrict__ s,
                                              unsigned short* __restrict__ d)
{
    __shared__ unsigned short tl[64][65];
    int r0 = blockIdx.y * 64, c0 = blockIdx.x * 64;
    int tid = threadIdx.x;
    int c = tid & 63, rr = tid >> 6;
    for (int i = 0; i < 16; i++)
        tl[rr + i * 4][c] = s[(size_t)(r0 + rr + i * 4) * NN + c0 + c];
    __syncthreads();
    for (int i = 0; i < 16; i++)
        d[(size_t)(c0 + rr + i * 4) * NN + r0 + c] = tl[c][rr + i * 4];
}

// ---------------- MFMA bf16 NT GEMM ----------------
// MODE 2: fp32 exp(out) + colsum atomics. MODE 3: split-K fp32 atomicAdd (bz = k-chunk).
template<int MODE>
__global__ __launch_bounds__(256) void mgemm(const short* __restrict__ A,
                                             const short* __restrict__ B,
                                             void* __restrict__ Cv,
                                             int Kd, int kchunk,
                                             int ldA, int ldB, int ldC,
                                             long sA, long sB, long sC,
                                             float* __restrict__ colsum)
{
    int bz = blockIdx.z;
    const short* Ab = A + (size_t)bz * sA;
    const short* Bb = B + (size_t)bz * sB;
    int i0 = blockIdx.y * 128, j0 = blockIdx.x * 128;
    __shared__ short sm[16384];            // As [128][64] @0, Bs [128][64] @8192
    int tid = threadIdx.x;
    int ln = tid & 63, wv = tid >> 6;
    int wm = (wv >> 1) * 64, wn = (wv & 1) * 64;
    int fr = ln & 15, fk = ln >> 4;
    f32x4 acc[4][4];
#pragma unroll
    for (int a = 0; a < 4; a++)
#pragma unroll
        for (int b2 = 0; b2 < 4; b2++) acc[a][b2] = (f32x4)(0.f);

    int k_lo = 0, k_hi = Kd;
    if constexpr (MODE == 3) { k_lo = bz * kchunk; k_hi = k_lo + kchunk; }

    for (int k0 = k_lo; k0 < k_hi; k0 += 64) {
#pragma unroll
        for (int q = 0; q < 4; q++) {
            int e = q * 2048 + tid * 8;
            const short* src = Ab + (size_t)(i0 + (e >> 6)) * ldA + k0 + (e & 63);
            gll16(src, sm + e);
        }
#pragma unroll
        for (int q = 0; q < 4; q++) {
            int e = q * 2048 + tid * 8;
            const short* src = Bb + (size_t)(j0 + (e >> 6)) * ldB + k0 + (e & 63);
            gll16(src, sm + 8192 + e);
        }
        __syncthreads();
#pragma unroll
        for (int ks = 0; ks < 2; ks++) {
            bf16x8 av[4], bv[4];
#pragma unroll
            for (int mi = 0; mi < 4; mi++)
                av[mi] = *(const bf16x8*)(sm + (wm + mi * 16 + fr) * 64 + ks * 32 + fk * 8);
#pragma unroll
            for (int nj = 0; nj < 4; nj++)
                bv[nj] = *(const bf16x8*)(sm + 8192 + (wn + nj * 16 + fr) * 64 + ks * 32 + fk * 8);
#pragma unroll
            for (int mi = 0; mi < 4; mi++)
#pragma unroll
                for (int nj = 0; nj < 4; nj++)
                    acc[mi][nj] = __builtin_amdgcn_mfma_f32_16x16x32_bf16(av[mi], bv[nj], acc[mi][nj], 0, 0, 0);
        }
        __syncthreads();
    }
    if constexpr (MODE == 2) {
        float* Cb = (float*)Cv + (size_t)bz * sC;
#pragma unroll
        for (int nj = 0; nj < 4; nj++) {
            float cs = 0.f;
            int col = j0 + wn + nj * 16 + fr;
#pragma unroll
            for (int mi = 0; mi < 4; mi++) {
                int row = i0 + wm + mi * 16 + fk * 4;
#pragma unroll
                for (int r = 0; r < 4; r++) {
                    float e = expf(acc[mi][nj][r]);
                    Cb[(size_t)(row + r) * ldC + col] = e;
                    cs += e;
                }
            }
            cs += __shfl_xor(cs, 16);
            cs += __shfl_xor(cs, 32);
            if (ln < 16) atomicAdd(&colsum[(size_t)bz * NN + col], cs);
        }
    } else if constexpr (MODE == 3) {
        float* Cb = (float*)Cv;
#pragma unroll
        for (int mi = 0; mi < 4; mi++)
#pragma unroll
            for (int nj = 0; nj < 4; nj++) {
                int row = i0 + wm + mi * 16 + fk * 4;
                int col = j0 + wn + nj * 16 + fr;
#pragma unroll
                for (int r = 0; r < 4; r++)
                    atomicAdd(&Cb[(size_t)(row + r) * ldC + col], acc[mi][nj][r]);
            }
    }
}

// ---------------- h-GEMM: C[b][m][j] = sum_n A[b][m][n]*Xt[b][j][n], bf16 out ----------------
// 1D grid of 384 with XCD-batch swizzle: each XCD gets 2 whole batches (L2 locality).
__global__ __launch_bounds__(256) void mgemm_h(const short* __restrict__ A,
                                               const short* __restrict__ B,
                                               unsigned short* __restrict__ C)
{
    int id = blockIdx.x;
    int xcd = id & 7, jj = id >> 3;            // jj 0..47
    int b = (xcd << 1) | (jj / 24);
    int r = jj % 24;
    int i0 = (r / 3) * 128, j0 = (r % 3) * 128;
    const short* Ab = A + (size_t)b * NN * NN;
    const short* Bb = B + (size_t)b * 384 * NN;
    __shared__ short sm[16384];
    int tid = threadIdx.x;
    int ln = tid & 63, wv = tid >> 6;
    int wm = (wv >> 1) * 64, wn = (wv & 1) * 64;
    int fr = ln & 15, fk = ln >> 4;
    f32x4 acc[4][4];
#pragma unroll
    for (int a = 0; a < 4; a++)
#pragma unroll
        for (int b2 = 0; b2 < 4; b2++) acc[a][b2] = (f32x4)(0.f);

    for (int k0 = 0; k0 < NN; k0 += 64) {
#pragma unroll
        for (int q = 0; q < 4; q++) {
            int e = q * 2048 + tid * 8;
            gll16(Ab + (size_t)(i0 + (e >> 6)) * NN + k0 + (e & 63), sm + e);
        }
#pragma unroll
        for (int q = 0; q < 4; q++) {
            int e = q * 2048 + tid * 8;
            gll16(Bb + (size_t)(j0 + (e >> 6)) * NN + k0 + (e & 63), sm + 8192 + e);
        }
        __syncthreads();
#pragma unroll
        for (int ks = 0; ks < 2; ks++) {
            bf16x8 av[4], bv[4];
#pragma unroll
            for (int mi = 0; mi < 4; mi++)
                av[mi] = *(const bf16x8*)(sm + (wm + mi * 16 + fr) * 64 + ks * 32 + fk * 8);
#pragma unroll
            for (int nj = 0; nj < 4; nj++)
                bv[nj] = *(const bf16x8*)(sm + 8192 + (wn + nj * 16 + fr) * 64 + ks * 32 + fk * 8);
#pragma unroll
            for (int mi = 0; mi < 4; mi++)
#pragma unroll
                for (int nj = 0; nj < 4; nj++)
                    acc[mi][nj] = __builtin_amdgcn_mfma_f32_16x16x32_bf16(av[mi], bv[nj], acc[mi][nj], 0, 0, 0);
        }
        __syncthreads();
    }
#pragma unroll
    for (int mi = 0; mi < 4; mi++)
#pragma unroll
        for (int nj = 0; nj < 4; nj++) {
            int row = i0 + wm + mi * 16 + fk * 4;
            int col = j0 + wn + nj * 16 + fr;
#pragma unroll
            for (int r2 = 0; r2 < 4; r2++)
                C[((size_t)b * NN + row + r2) * 384 + col] = cvt_bf(acc[mi][nj][r2]);
        }
}

// ---------------- normalize + threshold + At1 + At2 + sdiag (fully fused) ----------------
__global__ __launch_bounds__(256) void k_normprep2(float* __restrict__ spat,
                                                   const float* __restrict__ colsum,
                                                   const float* __restrict__ sup,
                                                   const float* __restrict__ supsq,
                                                   unsigned short* __restrict__ At1,
                                                   unsigned short* __restrict__ At2,
                                                   float* __restrict__ sdiag)
{
    __shared__ unsigned short t1[64][66];
    __shared__ unsigned short t2[64][66];
    int b = blockIdx.z;
    int n0 = blockIdx.y * 64, m0 = blockIdx.x * 64;
    int tid = threadIdx.x;
    int c = tid & 63, r0 = tid >> 6;
    const float thr = (1.0f / 1024.0f) / 0.6f;
    float inv = 1.f / colsum[(size_t)b * NN + m0 + c];
    float* sp = spat + (size_t)b * NN * NN;
    for (int i = 0; i < 16; i++) {
        int r = r0 + i * 4;
        size_t idx = (size_t)(n0 + r) * NN + m0 + c;
        float v = sp[idx] * inv;
        v = (v < thr) ? 0.f : v;
        sp[idx] = v;
        if (n0 + r == m0 + c) sdiag[(size_t)b * NN + n0 + r] = v;
        t1[r][c] = cvt_bf(sup[(size_t)(n0 + r) * NN + m0 + c] * v);
        float p2 = 2.f * supsq[(size_t)(n0 + r) * NN + m0 + c]
                 - (((n0 + r) == (m0 + c)) ? 1.f : 0.f);
        t2[r][c] = cvt_bf(p2 * v);
    }
    __syncthreads();
    int c2 = tid & 31, r4 = tid >> 5;
    size_t ob = ((size_t)b * NN + m0) * NN + n0;
    for (int i = 0; i < 8; i++) {
        int rr = r4 + i * 8;
        unsigned int v1 = (unsigned int)t1[2 * c2][rr] | ((unsigned int)t1[2 * c2 + 1][rr] << 16);
        unsigned int v2 = (unsigned int)t2[2 * c2][rr] | ((unsigned int)t2[2 * c2 + 1][rr] << 16);
        *(unsigned int*)(At1 + ob + (size_t)rr * NN + 2 * c2) = v1;
        *(unsigned int*)(At2 + ob + (size_t)rr * NN + 2 * c2) = v2;
    }
}

// ---------------- support graph (fp32 + bf16 copies) ----------------
__global__ __launch_bounds__(256) void k_sup(const float* __restrict__ emb,
                                             float* __restrict__ sup,
                                             unsigned short* __restrict__ supB)
{
    int n = blockIdx.x, tid = threadIdx.x;
    __shared__ float en[16];
    if (tid < 16) en[tid] = emb[n * 16 + tid];
    __syncthreads();
    float v[4];
#pragma unroll
    for (int q = 0; q < 4; q++) {
        int m = q * 256 + tid;
        float d = 0.f;
#pragma unroll
        for (int dd = 0; dd < 16; dd++) d += en[dd] * emb[m * 16 + dd];
        v[q] = fmaxf(d, 0.f);
    }
    float mx = fmaxf(fmaxf(v[0], v[1]), fmaxf(v[2], v[3]));
    for (int o = 32; o > 0; o >>= 1) mx = fmaxf(mx, __shfl_xor(mx, o));
    __shared__ float red[4];
    if ((tid & 63) == 0) red[tid >> 6] = mx;
    __syncthreads();
    mx = fmaxf(fmaxf(red[0], red[1]), fmaxf(red[2], red[3]));
    float e[4];
    float s = 0.f;
#pragma unroll
    for (int q = 0; q < 4; q++) { e[q] = expf(v[q] - mx); s += e[q]; }
    for (int o = 32; o > 0; o >>= 1) s += __shfl_xor(s, o);
    __shared__ float red2[4];
    if ((tid & 63) == 0) red2[tid >> 6] = s;
    __syncthreads();
    s = red2[0] + red2[1] + red2[2] + red2[3];
    float inv = 1.f / s;
#pragma unroll
    for (int q = 0; q < 4; q++) {
        float val = e[q] * inv;
        sup[(size_t)n * NN + q * 256 + tid] = val;
        supB[(size_t)n * NN + q * 256 + tid] = cvt_bf(val);
    }
}

// ---------------- weight prep ----------------
__global__ __launch_bounds__(192) void k_wnorm(const float* __restrict__ tcv,
                                               const float* __restrict__ tcg,
                                               unsigned short* __restrict__ Wr)
{
    int o = blockIdx.x, tid = threadIdx.x;
    float t = tcv[o * 192 + tid];
    float p = t * t;
    for (int off = 32; off > 0; off >>= 1) p += __shfl_xor(p, off);
    __shared__ float wsr[3];
    if ((tid & 63) == 0) wsr[tid >> 6] = p;
    __syncthreads();
    float sum = wsr[0] + wsr[1] + wsr[2];
    int c = tid / 3, dt = tid - c * 3;
    Wr[o * 192 + dt * 64 + c] = cvt_bf(t * (tcg[o] / sqrtf(sum)));
}

__global__ __launch_bounds__(256) void k_prepw(const float* __restrict__ Theta,
                                               const float* __restrict__ rcw,
                                               unsigned short* __restrict__ Th,
                                               unsigned short* __restrict__ Rc)
{
    int tid = threadIdx.x;
    for (int i = tid; i < 6144; i += 256) {
        int o = i / 96, rem = i - o * 96;
        int kind = rem >> 5, f = rem & 31;
        Th[i] = cvt_bf(Theta[kind * 2048 + f * 64 + o]);
    }
    for (int i = tid; i < 2048; i += 256) Rc[i] = cvt_bf(rcw[i]);
}

// ---------------- MFMA fused tail: 4 nodes/block, sdiag buffer ----------------
__global__ __launch_bounds__(256) void k_tail(const float* __restrict__ x,
                                              const unsigned short* __restrict__ h1,
                                              const unsigned short* __restrict__ h2,
                                              const float* __restrict__ sdiag,
                                              const unsigned short* __restrict__ Th,
                                              const unsigned short* __restrict__ Wr,
                                              const unsigned short* __restrict__ Rc,
                                              const float* __restrict__ tcb,
                                              const float* __restrict__ rcb,
                                              const float* __restrict__ lnw,
                                              const float* __restrict__ lnb,
                                              float* __restrict__ out)
{
    int b = blockIdx.y;
    int node0 = blockIdx.x * 4;
    int tid = threadIdx.x;
    int ln = tid & 63, wv = tid >> 6;
    int fr = ln & 15, fk = ln >> 4;

    __shared__ union {
        struct { unsigned short xt[1920], h1t[1920], h2t[1920], gcn[4032]; } a;
        float Y[48 * 65];
    } u;
    __shared__ float sdp[48];
    __shared__ float lnwS[64], lnbS[64], tbS[64];
    __shared__ float muS[48], rsS[48];

    size_t rowb = ((size_t)b * NN + node0) * 384;
    for (int i = tid; i < 1536; i += 256) {
        int node = i / 384, j = i - node * 384;
        int f = j / 12, t = j - f * 12;
        int la = node * 480 + t * 40 + f;
        u.a.xt[la]  = cvt_bf(x[rowb + i]);
        u.a.h1t[la] = h1[rowb + i];
        u.a.h2t[la] = h2[rowb + i];
    }
    for (int i = tid; i < 576; i += 256) {
        int node = i / 144, r = i - node * 144;
        int rr = (r < 72) ? 0 : 13;
        u.a.gcn[node * 1008 + rr * 72 + (r % 72)] = 0;
    }
    if (tid < 48) sdp[tid] = sdiag[(size_t)b * NN + node0 + tid / 12];
    if (tid < 64) { lnwS[tid] = lnw[tid]; lnbS[tid] = lnb[tid]; tbS[tid] = tcb[tid] + rcb[tid]; }

    int ocol = wv * 16 + fr;
    bf16x8 bTh[3], bWr[6], bRc;
#pragma unroll
    for (int kb = 0; kb < 3; kb++)
        bTh[kb] = *(const bf16x8*)((const short*)Th + (size_t)ocol * 96 + kb * 32 + fk * 8);
#pragma unroll
    for (int kb = 0; kb < 6; kb++)
        bWr[kb] = *(const bf16x8*)((const short*)Wr + (size_t)ocol * 192 + kb * 32 + fk * 8);
    bRc = *(const bf16x8*)((const short*)Rc + (size_t)ocol * 32 + fk * 8);

    int na[3], ta[3];
#pragma unroll
    for (int rb = 0; rb < 3; rb++) {
        int p = rb * 16 + fr;
        na[rb] = p / 12; ta[rb] = p - na[rb] * 12;
    }
    __syncthreads();

    f32x4 acc[3];
#pragma unroll
    for (int rb = 0; rb < 3; rb++) {
        int ax = na[rb] * 480 + ta[rb] * 40 + fk * 8;
        bf16x8 avx = *(const bf16x8*)(u.a.xt + ax);
        f32x4 z = (f32x4)(0.f);
        acc[rb] = __builtin_amdgcn_mfma_f32_16x16x32_bf16(avx, bTh[0], z, 0, 0, 0);
#pragma unroll
        for (int r = 0; r < 4; r++) acc[rb][r] *= sdp[rb * 16 + fk * 4 + r];
        bf16x8 av1 = *(const bf16x8*)(u.a.h1t + ax);
        acc[rb] = __builtin_amdgcn_mfma_f32_16x16x32_bf16(av1, bTh[1], acc[rb], 0, 0, 0);
        bf16x8 av2 = *(const bf16x8*)(u.a.h2t + ax);
        acc[rb] = __builtin_amdgcn_mfma_f32_16x16x32_bf16(av2, bTh[2], acc[rb], 0, 0, 0);
    }
#pragma unroll
    for (int rb = 0; rb < 3; rb++) {
#pragma unroll
        for (int r = 0; r < 4; r++) {
            int pc = rb * 16 + fk * 4 + r;
            int nc = pc / 12, tc2 = pc - nc * 12;
            u.a.gcn[nc * 1008 + (tc2 + 1) * 72 + wv * 16 + fr] = cvt_bf(fmaxf(acc[rb][r], 0.f));
        }
    }
    __syncthreads();
#pragma unroll
    for (int rb = 0; rb < 3; rb++) {
        f32x4 a2 = (f32x4)(0.f);
#pragma unroll
        for (int kb = 0; kb < 6; kb++) {
            int dt = kb >> 1, c0 = (kb & 1) * 32;
            bf16x8 ag = *(const bf16x8*)(u.a.gcn + na[rb] * 1008 + (ta[rb] + dt) * 72 + c0 + fk * 8);
            a2 = __builtin_amdgcn_mfma_f32_16x16x32_bf16(ag, bWr[kb], a2, 0, 0, 0);
        }
        int ax = na[rb] * 480 + ta[rb] * 40 + fk * 8;
        bf16x8 avx = *(const bf16x8*)(u.a.xt + ax);
        acc[rb] = __builtin_amdgcn_mfma_f32_16x16x32_bf16(avx, bRc, a2, 0, 0, 0);
    }
    __syncthreads();
    float tb = tbS[ocol];
#pragma unroll
    for (int rb = 0; rb < 3; rb++)
#pragma unroll
        for (int r = 0; r < 4; r++)
            u.Y[(rb * 16 + fk * 4 + r) * 65 + ocol] = acc[rb][r] + tb;
    __syncthreads();
    if (tid < 48) {
        float s = 0.f, s2 = 0.f;
        for (int o = 0; o < 64; o++) {
            float v = u.Y[tid * 65 + o];
            s += v; s2 += v * v;
        }
        float mm = s * (1.f / 64.f);
        float var = s2 * (1.f / 64.f) - mm * mm;
        muS[tid] = mm; rsS[tid] = rsqrtf(var + 1e-5f);
    }
    __syncthreads();
    float* ob = out + rowb * 2;
    for (int i = tid; i < 3072; i += 256) {
        int node = i / 768, rr = i - node * 768;
        int o = rr / 12, t = rr - o * 12;
        int p = node * 12 + t;
        ob[i] = (u.Y[p * 65 + o] - muS[p]) * rsS[p] * lnwS[o] + lnbS[o];
    }
}

extern "C" void kernel_launch(void* const* d_in, const int* in_sizes, int n_in,
                              void* d_out, int out_size, void* d_ws, size_t ws_size,
                              hipStream_t stream)
{
    const float* x    = (const float*)d_in[0];
    const float* emb  = (const float*)d_in[1];
    const float* W1   = (const float*)d_in[2];
    const float* W2   = (const float*)d_in[3];
    const float* W3   = (const float*)d_in[4];
    const float* bs   = (const float*)d_in[5];
    const float* Vs   = (const float*)d_in[6];
    const float* U1   = (const float*)d_in[7];
    const float* U2   = (const float*)d_in[8];
    const float* U3   = (const float*)d_in[9];
    const float* be   = (const float*)d_in[10];
    const float* Ve   = (const float*)d_in[11];
    const float* Theta= (const float*)d_in[12];
    const float* tcv  = (const float*)d_in[13];
    const float* tcg  = (const float*)d_in[14];
    const float* tcb  = (const float*)d_in[15];
    const float* rcw  = (const float*)d_in[16];
    const float* rcb  = (const float*)d_in[17];
    const float* lnw  = (const float*)d_in[18];
    const float* lnb  = (const float*)d_in[19];

    float* xres = (float*)d_out;                       // B*N*FT*T fp32 (scratch for At2 until k_tail)
    float* spat = xres + (size_t)NB * NN * NFT * NT;   // B*N*N fp32

    char* base = (char*)d_ws;
    // base+0 (32MB) timeline: Xrow (k_pre->k_xt) -> Pt (k_Ptile->mgemm<2>) -> supB/supT -> At1
    unsigned short* Xrow = (unsigned short*)(base + 0);
    unsigned short* Pt   = (unsigned short*)(base + 0);
    unsigned short* supB = (unsigned short*)(base + 0);
    unsigned short* supT = (unsigned short*)(base + 2097152);
    unsigned short* At1  = (unsigned short*)(base + 0);
    unsigned short* At2  = (unsigned short*)xres;          // d_out scratch (32 MB < 48 MB)
    unsigned short* Xt  = (unsigned short*)(base + 33554432);   // live k_xt -> mgemm_h
    unsigned short* h1  = (unsigned short*)(base + 46137344);
    unsigned short* h2  = (unsigned short*)(base + 58720256);
    unsigned short* Vsb = (unsigned short*)(base + 71303168);
    float* colsum  = (float*)(base + 73400320);
    float* sdiag   = (float*)(base + 73465856);
    float* sup     = (float*)(base + 77594624);
    float* supsq   = (float*)(base + 81788928);
    float* lhs_pre = (float*)(base + 85983232);
    float* lhs     = (float*)(base + 86007808);
    float* rhs     = (float*)(base + 86794240);
    float* rr3     = (float*)(base + 87580672);
    float* prod    = (float*)(base + 88367104);
    float* E       = (float*)(base + 88376320);
    float* EW1     = (float*)(base + 88385536);
    float* l2      = (float*)(base + 88386560);
    float* r2      = (float*)(base + 89172992);
    unsigned short* Wr = (unsigned short*)(base + 89959424);
    unsigned short* Th = (unsigned short*)(base + 89984000);
    unsigned short* Rc = (unsigned short*)(base + 89996288);

    hipMemsetAsync(lhs_pre, 0, 6144 * sizeof(float), stream);
    hipMemsetAsync(supsq, 0, (size_t)NN * NN * sizeof(float), stream);

    // pre-pass: x fp32 -> lhs_pre, rhs, rr3, Xrow(bf16)
    k_pre<<<dim3(16, 16), 384, 0, stream>>>(x, U1, U3, W3, lhs_pre, rhs, rr3, Xrow);
    k_lhs<<<192, 256, 0, stream>>>(lhs_pre, U2, lhs);
    k_prod<<<2304, 64, 0, stream>>>(lhs, rhs, prod);
    k_E<<<16, 192, 0, stream>>>(prod, be, Ve, W1, E, EW1);
    // spatial attention (l2/r2 + Xt transpose read Xrow bf16)
    k_l2r2x<<<dim3(128, 16), 384, 0, stream>>>(Xrow, rr3, E, EW1, W2, l2, r2);
    k_xt<<<dim3(6, 16, 16), 256, 0, stream>>>(Xrow, Xt);       // before Pt overwrites Xrow
    k_Ptile<<<dim3(16, 16, 16), 256, 0, stream>>>(l2, r2, bs, Pt);
    k_cvt<<<1024, 256, 0, stream>>>(Vs, Vsb);
    hipMemsetAsync(colsum, 0, (size_t)NB * NN * sizeof(float), stream);
    mgemm<2><<<dim3(8, 8, 16), 256, 0, stream>>>((const short*)Vsb, (const short*)Pt,
        (void*)spat, NN, 0, NN, NN, NN, 0L, (long)NN * NN, (long)NN * NN, colsum);
    // graph supports
    k_sup<<<1024, 256, 0, stream>>>(emb, sup, supB);
    k_tb16<<<dim3(16, 16), 256, 0, stream>>>(supB, supT);
    mgemm<3><<<dim3(8, 8, 4), 256, 0, stream>>>((const short*)supB, (const short*)supT,
        (void*)supsq, NN, 256, NN, NN, NN, 0L, 0L, 0L, nullptr);
    // normalize + threshold + masked adjacencies + diagonal
    k_normprep2<<<dim3(16, 16, 16), 256, 0, stream>>>(spat, colsum, sup, supsq, At1, At2, sdiag);
    // h-GEMMs with XCD-batch swizzle
    mgemm_h<<<384, 256, 0, stream>>>((const short*)At1, (const short*)Xt, h1);
    mgemm_h<<<384, 256, 0, stream>>>((const short*)At2, (const short*)Xt, h2);
    // tail
    k_wnorm<<<64, 192, 0, stream>>>(tcv, tcg, Wr);
    k_prepw<<<1, 256, 0, stream>>>(Theta, rcw, Th, Rc);
    k_tail<<<dim3(256, 16), 256, 0, stream>>>(x, h1, h2, sdiag, Th, Wr, Rc,
                                              tcb, rcb, lnw, lnb, xres);
}

// Round 9
// 336.889 us; speedup vs baseline: 1.1517x; 1.0012x over previous
//
#include <hip/hip_runtime.h>
#include <math.h>

#define NB 16      // B
#define NN 1024    // N
#define NF 32      // F
#define NT 12      // T
#define NFC 64
#define NFT 64

typedef __attribute__((ext_vector_type(8))) short bf16x8;
typedef __attribute__((ext_vector_type(4))) float f32x4;

__device__ inline unsigned short cvt_bf(float f) {
    unsigned int u = __float_as_uint(f);
    u += 0x7fff + ((u >> 16) & 1);
    return (unsigned short)(u >> 16);
}
__device__ inline float bf2f(unsigned short u) {
    return __uint_as_float(((unsigned int)u) << 16);
}
__device__ inline void gll16(const short* g, short* l) {
    __builtin_amdgcn_global_load_lds((const __attribute__((address_space(1))) void*)g,
                                     (__attribute__((address_space(3))) void*)l, 16, 0, 0);
}

// ---------------- fused pre-pass: lhs_pre (U1), rhs (U3), rr3 (W3), Xrow (bf16, packed writes) ----------------
__global__ __launch_bounds__(384) void k_pre(const float* __restrict__ x,
                                             const float* __restrict__ U1,
                                             const float* __restrict__ U3,
                                             const float* __restrict__ W3,
                                             float* __restrict__ lhs_pre,
                                             float* __restrict__ rhs,
                                             float* __restrict__ rr3,
                                             unsigned short* __restrict__ Xrow)
{
    __shared__ float xs[8 * 384];
    int b = blockIdx.x, ch = blockIdx.y, tid = threadIdx.x;
    float acc = 0.f;
    for (int c8 = 0; c8 < 8; c8++) {
        int n0 = ch * 64 + c8 * 8;
        size_t r0 = (size_t)b * NN + n0;
        __syncthreads();
        for (int i = 0; i < 8; i++) xs[i * 384 + tid] = x[(r0 + i) * 384 + tid];
        __syncthreads();
        for (int i = 0; i < 8; i++) acc += xs[i * 384 + tid] * U1[n0 + i];
        // packed bf16 writes (uint = 2 elems), rows contiguous
        for (int idx = tid; idx < 1536; idx += 384) {
            int row = idx / 192, jj = (idx - row * 192) * 2;
            unsigned int w = (unsigned int)cvt_bf(xs[row * 384 + jj])
                           | ((unsigned int)cvt_bf(xs[row * 384 + jj + 1]) << 16);
            *(unsigned int*)(Xrow + (r0 + row) * 384 + jj) = w;
        }
        if (tid < 192) {
            int half = tid / 96;
            int r = tid - half * 96;
            int i = r / 12, t = r - i * 12;
            const float* wv = half ? W3 : U3;
            float s = 0.f;
            for (int f = 0; f < 32; f++) s += wv[f] * xs[i * 384 + f * 12 + t];
            float* outp = half ? rr3 : rhs;
            outp[(r0 + i) * 12 + t] = s;
        }
    }
    int f = tid / 12, t = tid - f * 12;
    atomicAdd(&lhs_pre[b * 384 + t * 32 + f], acc);
}

__global__ __launch_bounds__(256) void k_lhs(const float* __restrict__ lhs_pre,
                                             const float* __restrict__ U2,
                                             float* __restrict__ lhs)
{
    int bt = blockIdx.x;
    int tid = threadIdx.x;
    __shared__ float lp[32];
    if (tid < 32) lp[tid] = lhs_pre[bt * 32 + tid];
    __syncthreads();
    for (int q = 0; q < 4; q++) {
        int n = q * 256 + tid;
        float a = 0.f;
        for (int f = 0; f < 32; f++) a += lp[f] * U2[f * NN + n];
        lhs[(size_t)bt * NN + n] = a;
    }
}

__global__ __launch_bounds__(64) void k_prod(const float* __restrict__ lhs,
                                             const float* __restrict__ rhs,
                                             float* __restrict__ prod)
{
    int blk = blockIdx.x;
    int b = blk / 144, r = blk - b * 144;
    int s = r / 12, u = r - s * 12;
    int tid = threadIdx.x;
    float p = 0.f;
    for (int n = tid; n < NN; n += 64)
        p += lhs[((size_t)b * 12 + s) * NN + n] * rhs[((size_t)b * NN + n) * 12 + u];
    for (int o = 32; o > 0; o >>= 1) p += __shfl_xor(p, o);
    if (tid == 0) prod[blk] = p;
}

// E (softmax over t) + EW1[b][t] = sum_u E[b,t,u]*W1[u]
__global__ __launch_bounds__(192) void k_E(const float* __restrict__ prod,
                                           const float* __restrict__ be,
                                           const float* __restrict__ Ve,
                                           const float* __restrict__ W1,
                                           float* __restrict__ E,
                                           float* __restrict__ EW1)
{
    int b = blockIdx.x, tid = threadIdx.x;
    __shared__ float ssig[144], sE[144], mx[12], sm[12];
    if (tid < 144) ssig[tid] = 1.f / (1.f + expf(-(prod[b * 144 + tid] + be[tid])));
    __syncthreads();
    if (tid < 144) {
        int t = tid / 12, u = tid - t * 12;
        float a = 0.f;
        for (int s2 = 0; s2 < 12; s2++) a += Ve[t * 12 + s2] * ssig[s2 * 12 + u];
        sE[tid] = a;
    }
    __syncthreads();
    if (tid < 12) {
        float m = -1e30f;
        for (int t = 0; t < 12; t++) m = fmaxf(m, sE[t * 12 + tid]);
        float s = 0.f;
        for (int t = 0; t < 12; t++) s += expf(sE[t * 12 + tid] - m);
        mx[tid] = m; sm[tid] = s;
    }
    __syncthreads();
    float val = 0.f;
    if (tid < 144) {
        int u = tid % 12;
        val = expf(sE[tid] - mx[u]) / sm[u];
        E[b * 144 + tid] = val;
    }
    __syncthreads();
    if (tid < 144) sE[tid] = val;
    __syncthreads();
    if (tid < 12) {
        float a = 0.f;
        for (int u = 0; u < 12; u++) a += sE[tid * 12 + u] * W1[u];
        EW1[b * 12 + tid] = a;
    }
}

// ---------------- l2/r2 from Xrow (bf16, packed loads) ----------------
__global__ __launch_bounds__(384) void k_l2r2x(const unsigned short* __restrict__ Xrow,
                                               const float* __restrict__ rr3,
                                               const float* __restrict__ E,
                                               const float* __restrict__ EW1,
                                               const float* __restrict__ W2,
                                               float* __restrict__ l2,
                                               float* __restrict__ r2)
{
    __shared__ float xs[8 * 384];
    __shared__ float Es[144], ew[12], rrs[96], lp[8][32];
    int b = blockIdx.y, tid = threadIdx.x;
    int n0 = blockIdx.x * 8;
    size_t r0 = (size_t)b * NN + n0;
    if (tid < 144) Es[tid] = E[b * 144 + tid];
    if (tid < 12) ew[tid] = EW1[b * 12 + tid];
    if (tid < 96) rrs[tid] = rr3[(r0 + tid / 12) * 12 + (tid % 12)];
    const unsigned int* Xr = (const unsigned int*)(Xrow + r0 * 384);
    for (int i2 = tid; i2 < 1536; i2 += 384) {
        unsigned int w = Xr[i2];
        xs[2 * i2]     = bf2f((unsigned short)(w & 0xffff));
        xs[2 * i2 + 1] = bf2f((unsigned short)(w >> 16));
    }
    __syncthreads();
    if (tid < 256) {
        int i = tid >> 5, f = tid & 31;
        float a = 0.f;
#pragma unroll
        for (int t = 0; t < 12; t++) a += xs[i * 384 + f * 12 + t] * ew[t];
        lp[i][f] = a;
    }
    __syncthreads();
    if (tid < 96) {
        int i = tid / 12, u = tid - i * 12;
        float a = 0.f;
        for (int f = 0; f < 32; f++) a += lp[i][f] * W2[f * 12 + u];
        l2[(r0 + i) * 12 + u] = a;
        float rv = 0.f;
#pragma unroll
        for (int t = 0; t < 12; t++) rv += rrs[i * 12 + t] * Es[t * 12 + u];
        r2[((size_t)b * 12 + u) * NN + n0 + i] = rv;
    }
}

// Xt[b][j][n] = Xrow[b][n][j]  (pure bf16 transpose; B operand for h-GEMMs)
__global__ __launch_bounds__(256) void k_xt(const unsigned short* __restrict__ Xrow,
                                            unsigned short* __restrict__ Xt)
{
    __shared__ unsigned short tl[64][66];
    int b = blockIdx.z;
    int n0 = blockIdx.y * 64, j0 = blockIdx.x * 64;
    int tid = threadIdx.x;
    int c = tid & 63, r0 = tid >> 6;
    for (int i = 0; i < 16; i++) {
        int r = r0 + i * 4;
        tl[r][c] = Xrow[((size_t)b * NN + n0 + r) * 384 + j0 + c];
    }
    __syncthreads();
    int c2 = tid & 31, r4 = tid >> 5;
    unsigned short* ob = Xt + ((size_t)b * 384 + j0) * NN + n0;
    for (int i = 0; i < 8; i++) {
        int jr = r4 + i * 8;
        unsigned int v0 = (unsigned int)tl[2 * c2][jr] | ((unsigned int)tl[2 * c2 + 1][jr] << 16);
        *(unsigned int*)(ob + (size_t)jr * NN + 2 * c2) = v0;
    }
}

// ---------------- tiled P: Pt[b][k][m] = bf16(sigmoid(l2[b,m,:]·r2[b,:,k] + bs[m,k])) ----------------
__global__ __launch_bounds__(256) void k_Ptile(const float* __restrict__ l2,
                                               const float* __restrict__ r2,
                                               const float* __restrict__ bsin,
                                               unsigned short* __restrict__ Pt)
{
    __shared__ float l2s[64][13];
    __shared__ float r2s[12][64];
    __shared__ float bsS[64][65];
    int k0 = blockIdx.x * 64, m0 = blockIdx.y * 64, b = blockIdx.z;
    int tid = threadIdx.x;
    for (int i = tid; i < 768; i += 256) {
        int r = i / 12, t = i - r * 12;
        l2s[r][t] = l2[((size_t)b * NN + m0 + r) * 12 + t];
    }
    for (int i = tid; i < 768; i += 256) {
        int t = i >> 6, k = i & 63;
        r2s[t][k] = r2[((size_t)b * 12 + t) * NN + k0 + k];
    }
    for (int i = tid; i < 4096; i += 256) {
        int r = i >> 6, c = i & 63;
        bsS[r][c] = bsin[(size_t)(m0 + r) * NN + k0 + c];
    }
    __syncthreads();
    int m = tid & 63, kg = tid >> 6;
    float lv[12];
#pragma unroll
    for (int t = 0; t < 12; t++) lv[t] = l2s[m][t];
#pragma unroll
    for (int s = 0; s < 16; s++) {
        int kl = kg * 16 + s;
        float p = bsS[m][kl];
#pragma unroll
        for (int t = 0; t < 12; t++) p += lv[t] * r2s[t][kl];
        float sg = 1.f / (1.f + expf(-p));
        Pt[((size_t)b * NN + k0 + kl) * NN + m0 + m] = cvt_bf(sg);
    }
}

// Vs fp32 -> bf16
__global__ __launch_bounds__(256) void k_cvt(const float* __restrict__ s,
                                             unsigned short* __restrict__ d)
{
    size_t i = ((size_t)blockIdx.x * 256 + threadIdx.x) * 4;
    float4 v = *(const float4*)(s + i);
    unsigned int p0 = (unsigned int)cvt_bf(v.x) | ((unsigned int)cvt_bf(v.y) << 16);
    unsigned int p1 = (unsigned int)cvt_bf(v.z) | ((unsigned int)cvt_bf(v.w) << 16);
    *(unsigned int*)(d + i) = p0;
    *(unsigned int*)(d + i + 2) = p1;
}

// bf16 transpose 1024x1024
__global__ __launch_bounds__(256) void k_tb16(const unsigned short* __restrict__ s,
                                              unsigned short* __restrict__ d)
{
    __shared__ unsigned short tl[64][65];
    int r0 = blockIdx.y * 64, c0 = blockIdx.x * 64;
    int tid = threadIdx.x;
    int c = tid & 63, rr = tid >> 6;
    for (int i = 0; i < 16; i++)
        tl[rr + i * 4][c] = s[(size_t)(r0 + rr + i * 4) * NN + c0 + c];
    __syncthreads();
    for (int i = 0; i < 16; i++)
        d[(size_t)(c0 + rr + i * 4) * NN + r0 + c] = tl[c][rr + i * 4];
}

// ---------------- MFMA bf16 NT GEMM ----------------
// MODE 2: fp32 exp(out) + colsum atomics. MODE 3: split-K fp32 atomicAdd (bz = k-chunk).
template<int MODE>
__global__ __launch_bounds__(256) void mgemm(const short* __restrict__ A,
                                             const short* __restrict__ B,
                                             void* __restrict__ Cv,
                                             int Kd, int kchunk,
                                             int ldA, int ldB, int ldC,
                                             long sA, long sB, long sC,
                                             float* __restrict__ colsum)
{
    int bz = blockIdx.z;
    const short* Ab = A + (size_t)bz * sA;
    const short* Bb = B + (size_t)bz * sB;
    int i0 = blockIdx.y * 128, j0 = blockIdx.x * 128;
    __shared__ short sm[16384];            // As [128][64] @0, Bs [128][64] @8192
    int tid = threadIdx.x;
    int ln = tid & 63, wv = tid >> 6;
    int wm = (wv >> 1) * 64, wn = (wv & 1) * 64;
    int fr = ln & 15, fk = ln >> 4;
    f32x4 acc[4][4];
#pragma unroll
    for (int a = 0; a < 4; a++)
#pragma unroll
        for (int b2 = 0; b2 < 4; b2++) acc[a][b2] = (f32x4)(0.f);

    int k_lo = 0, k_hi = Kd;
    if constexpr (MODE == 3) { k_lo = bz * kchunk; k_hi = k_lo + kchunk; }

    for (int k0 = k_lo; k0 < k_hi; k0 += 64) {
#pragma unroll
        for (int q = 0; q < 4; q++) {
            int e = q * 2048 + tid * 8;
            const short* src = Ab + (size_t)(i0 + (e >> 6)) * ldA + k0 + (e & 63);
            gll16(src, sm + e);
        }
#pragma unroll
        for (int q = 0; q < 4; q++) {
            int e = q * 2048 + tid * 8;
            const short* src = Bb + (size_t)(j0 + (e >> 6)) * ldB + k0 + (e & 63);
            gll16(src, sm + 8192 + e);
        }
        __syncthreads();
#pragma unroll
        for (int ks = 0; ks < 2; ks++) {
            bf16x8 av[4], bv[4];
#pragma unroll
            for (int mi = 0; mi < 4; mi++)
                av[mi] = *(const bf16x8*)(sm + (wm + mi * 16 + fr) * 64 + ks * 32 + fk * 8);
#pragma unroll
            for (int nj = 0; nj < 4; nj++)
                bv[nj] = *(const bf16x8*)(sm + 8192 + (wn + nj * 16 + fr) * 64 + ks * 32 + fk * 8);
#pragma unroll
            for (int mi = 0; mi < 4; mi++)
#pragma unroll
                for (int nj = 0; nj < 4; nj++)
                    acc[mi][nj] = __builtin_amdgcn_mfma_f32_16x16x32_bf16(av[mi], bv[nj], acc[mi][nj], 0, 0, 0);
        }
        __syncthreads();
    }
    if constexpr (MODE == 2) {
        float* Cb = (float*)Cv + (size_t)bz * sC;
#pragma unroll
        for (int nj = 0; nj < 4; nj++) {
            float cs = 0.f;
            int col = j0 + wn + nj * 16 + fr;
#pragma unroll
            for (int mi = 0; mi < 4; mi++) {
                int row = i0 + wm + mi * 16 + fk * 4;
#pragma unroll
                for (int r = 0; r < 4; r++) {
                    float e = expf(acc[mi][nj][r]);
                    Cb[(size_t)(row + r) * ldC + col] = e;
                    cs += e;
                }
            }
            cs += __shfl_xor(cs, 16);
            cs += __shfl_xor(cs, 32);
            if (ln < 16) atomicAdd(&colsum[(size_t)bz * NN + col], cs);
        }
    } else if constexpr (MODE == 3) {
        float* Cb = (float*)Cv;
#pragma unroll
        for (int mi = 0; mi < 4; mi++)
#pragma unroll
            for (int nj = 0; nj < 4; nj++) {
                int row = i0 + wm + mi * 16 + fk * 4;
                int col = j0 + wn + nj * 16 + fr;
#pragma unroll
                for (int r = 0; r < 4; r++)
                    atomicAdd(&Cb[(size_t)(row + r) * ldC + col], acc[mi][nj][r]);
            }
    }
}

// ---------------- h-GEMM with XCD-batch swizzle ----------------
__global__ __launch_bounds__(256) void mgemm_h(const short* __restrict__ A,
                                               const short* __restrict__ B,
                                               unsigned short* __restrict__ C)
{
    int id = blockIdx.x;
    int xcd = id & 7, jj = id >> 3;            // jj 0..47
    int b = (xcd << 1) | (jj / 24);
    int r = jj % 24;
    int i0 = (r / 3) * 128, j0 = (r % 3) * 128;
    const short* Ab = A + (size_t)b * NN * NN;
    const short* Bb = B + (size_t)b * 384 * NN;
    __shared__ short sm[16384];
    int tid = threadIdx.x;
    int ln = tid & 63, wv = tid >> 6;
    int wm = (wv >> 1) * 64, wn = (wv & 1) * 64;
    int fr = ln & 15, fk = ln >> 4;
    f32x4 acc[4][4];
#pragma unroll
    for (int a = 0; a < 4; a++)
#pragma unroll
        for (int b2 = 0; b2 < 4; b2++) acc[a][b2] = (f32x4)(0.f);

    for (int k0 = 0; k0 < NN; k0 += 64) {
#pragma unroll
        for (int q = 0; q < 4; q++) {
            int e = q * 2048 + tid * 8;
            gll16(Ab + (size_t)(i0 + (e >> 6)) * NN + k0 + (e & 63), sm + e);
        }
#pragma unroll
        for (int q = 0; q < 4; q++) {
            int e = q * 2048 + tid * 8;
            gll16(Bb + (size_t)(j0 + (e >> 6)) * NN + k0 + (e & 63), sm + 8192 + e);
        }
        __syncthreads();
#pragma unroll
        for (int ks = 0; ks < 2; ks++) {
            bf16x8 av[4], bv[4];
#pragma unroll
            for (int mi = 0; mi < 4; mi++)
                av[mi] = *(const bf16x8*)(sm + (wm + mi * 16 + fr) * 64 + ks * 32 + fk * 8);
#pragma unroll
            for (int nj = 0; nj < 4; nj++)
                bv[nj] = *(const bf16x8*)(sm + 8192 + (wn + nj * 16 + fr) * 64 + ks * 32 + fk * 8);
#pragma unroll
            for (int mi = 0; mi < 4; mi++)
#pragma unroll
                for (int nj = 0; nj < 4; nj++)
                    acc[mi][nj] = __builtin_amdgcn_mfma_f32_16x16x32_bf16(av[mi], bv[nj], acc[mi][nj], 0, 0, 0);
        }
        __syncthreads();
    }
#pragma unroll
    for (int mi = 0; mi < 4; mi++)
#pragma unroll
        for (int nj = 0; nj < 4; nj++) {
            int row = i0 + wm + mi * 16 + fk * 4;
            int col = j0 + wn + nj * 16 + fr;
#pragma unroll
            for (int r2 = 0; r2 < 4; r2++)
                C[((size_t)b * NN + row + r2) * 384 + col] = cvt_bf(acc[mi][nj][r2]);
        }
}

// ---------------- normalize + threshold + At1 + At2 + sdiag (fully fused) ----------------
__global__ __launch_bounds__(256) void k_normprep2(float* __restrict__ spat,
                                                   const float* __restrict__ colsum,
                                                   const float* __restrict__ sup,
                                                   const float* __restrict__ supsq,
                                                   unsigned short* __restrict__ At1,
                                                   unsigned short* __restrict__ At2,
                                                   float* __restrict__ sdiag)
{
    __shared__ unsigned short t1[64][66];
    __shared__ unsigned short t2[64][66];
    int b = blockIdx.z;
    int n0 = blockIdx.y * 64, m0 = blockIdx.x * 64;
    int tid = threadIdx.x;
    int c = tid & 63, r0 = tid >> 6;
    const float thr = (1.0f / 1024.0f) / 0.6f;
    float inv = 1.f / colsum[(size_t)b * NN + m0 + c];
    float* sp = spat + (size_t)b * NN * NN;
    for (int i = 0; i < 16; i++) {
        int r = r0 + i * 4;
        size_t idx = (size_t)(n0 + r) * NN + m0 + c;
        float v = sp[idx] * inv;
        v = (v < thr) ? 0.f : v;
        sp[idx] = v;
        if (n0 + r == m0 + c) sdiag[(size_t)b * NN + n0 + r] = v;
        t1[r][c] = cvt_bf(sup[(size_t)(n0 + r) * NN + m0 + c] * v);
        float p2 = 2.f * supsq[(size_t)(n0 + r) * NN + m0 + c]
                 - (((n0 + r) == (m0 + c)) ? 1.f : 0.f);
        t2[r][c] = cvt_bf(p2 * v);
    }
    __syncthreads();
    int c2 = tid & 31, r4 = tid >> 5;
    size_t ob = ((size_t)b * NN + m0) * NN + n0;
    for (int i = 0; i < 8; i++) {
        int rr = r4 + i * 8;
        unsigned int v1 = (unsigned int)t1[2 * c2][rr] | ((unsigned int)t1[2 * c2 + 1][rr] << 16);
        unsigned int v2 = (unsigned int)t2[2 * c2][rr] | ((unsigned int)t2[2 * c2 + 1][rr] << 16);
        *(unsigned int*)(At1 + ob + (size_t)rr * NN + 2 * c2) = v1;
        *(unsigned int*)(At2 + ob + (size_t)rr * NN + 2 * c2) = v2;
    }
}

// ---------------- support graph (fp32 + bf16 copies) ----------------
__global__ __launch_bounds__(256) void k_sup(const float* __restrict__ emb,
                                             float* __restrict__ sup,
                                             unsigned short* __restrict__ supB)
{
    int n = blockIdx.x, tid = threadIdx.x;
    __shared__ float en[16];
    if (tid < 16) en[tid] = emb[n * 16 + tid];
    __syncthreads();
    float v[4];
#pragma unroll
    for (int q = 0; q < 4; q++) {
        int m = q * 256 + tid;
        float d = 0.f;
#pragma unroll
        for (int dd = 0; dd < 16; dd++) d += en[dd] * emb[m * 16 + dd];
        v[q] = fmaxf(d, 0.f);
    }
    float mx = fmaxf(fmaxf(v[0], v[1]), fmaxf(v[2], v[3]));
    for (int o = 32; o > 0; o >>= 1) mx = fmaxf(mx, __shfl_xor(mx, o));
    __shared__ float red[4];
    if ((tid & 63) == 0) red[tid >> 6] = mx;
    __syncthreads();
    mx = fmaxf(fmaxf(red[0], red[1]), fmaxf(red[2], red[3]));
    float e[4];
    float s = 0.f;
#pragma unroll
    for (int q = 0; q < 4; q++) { e[q] = expf(v[q] - mx); s += e[q]; }
    for (int o = 32; o > 0; o >>= 1) s += __shfl_xor(s, o);
    __shared__ float red2[4];
    if ((tid & 63) == 0) red2[tid >> 6] = s;
    __syncthreads();
    s = red2[0] + red2[1] + red2[2] + red2[3];
    float inv = 1.f / s;
#pragma unroll
    for (int q = 0; q < 4; q++) {
        float val = e[q] * inv;
        sup[(size_t)n * NN + q * 256 + tid] = val;
        supB[(size_t)n * NN + q * 256 + tid] = cvt_bf(val);
    }
}

// ---------------- merged weight prep: blocks 0..63 = wnorm, block 64 = Theta/rcw ----------------
__global__ __launch_bounds__(256) void k_wprep(const float* __restrict__ tcv,
                                               const float* __restrict__ tcg,
                                               const float* __restrict__ Theta,
                                               const float* __restrict__ rcw,
                                               unsigned short* __restrict__ Wr,
                                               unsigned short* __restrict__ Th,
                                               unsigned short* __restrict__ Rc)
{
    int tid = threadIdx.x;
    if (blockIdx.x < 64) {
        int o = blockIdx.x;
        float t = 0.f, p = 0.f;
        if (tid < 192) { t = tcv[o * 192 + tid]; p = t * t; }
        for (int off = 32; off > 0; off >>= 1) p += __shfl_xor(p, off);
        __shared__ float wsr[3];
        if (tid < 192 && (tid & 63) == 0) wsr[tid >> 6] = p;
        __syncthreads();
        if (tid < 192) {
            float sum = wsr[0] + wsr[1] + wsr[2];
            int c = tid / 3, dt = tid - c * 3;
            Wr[o * 192 + dt * 64 + c] = cvt_bf(t * (tcg[o] / sqrtf(sum)));
        }
    } else {
        for (int i = tid; i < 6144; i += 256) {
            int o = i / 96, rem = i - o * 96;
            int kind = rem >> 5, f = rem & 31;
            Th[i] = cvt_bf(Theta[kind * 2048 + f * 64 + o]);
        }
        for (int i = tid; i < 2048; i += 256) Rc[i] = cvt_bf(rcw[i]);
    }
}

// ---------------- MFMA fused tail: 4 nodes/block, vectorized staging + output ----------------
__global__ __launch_bounds__(256) void k_tail(const float* __restrict__ x,
                                              const unsigned short* __restrict__ h1,
                                              const unsigned short* __restrict__ h2,
                                              const float* __restrict__ sdiag,
                                              const unsigned short* __restrict__ Th,
                                              const unsigned short* __restrict__ Wr,
                                              const unsigned short* __restrict__ Rc,
                                              const float* __restrict__ tcb,
                                              const float* __restrict__ rcb,
                                              const float* __restrict__ lnw,
                                              const float* __restrict__ lnb,
                                              float* __restrict__ out)
{
    int b = blockIdx.y;
    int node0 = blockIdx.x * 4;
    int tid = threadIdx.x;
    int ln = tid & 63, wv = tid >> 6;
    int fr = ln & 15, fk = ln >> 4;

    __shared__ union {
        struct { unsigned short xt[1920], h1t[1920], h2t[1920], gcn[4032]; } a;
        float Y[48 * 65];
    } u;
    __shared__ float sdp[48];
    __shared__ float lnwS[64], lnbS[64], tbS[64];
    __shared__ float muS[48], rsS[48];

    size_t rowb = ((size_t)b * NN + node0) * 384;
    {
        const float2* xp = (const float2*)(x + rowb);
        const unsigned int* h1p = (const unsigned int*)(h1 + rowb);
        const unsigned int* h2p = (const unsigned int*)(h2 + rowb);
        for (int q = tid; q < 768; q += 256) {
            int j0 = q * 2;
            int node = j0 / 384, j = j0 - node * 384;
            int f = j / 12, t = j - f * 12;
            int t2 = t + 1, f2 = f;
            if (t2 == 12) { t2 = 0; f2 = f + 1; }
            int la0 = node * 480 + t * 40 + f;
            int la1 = node * 480 + t2 * 40 + f2;
            float2 xv = xp[q];
            unsigned int w1 = h1p[q], w2 = h2p[q];
            u.a.xt[la0] = cvt_bf(xv.x);  u.a.xt[la1] = cvt_bf(xv.y);
            u.a.h1t[la0] = (unsigned short)(w1 & 0xffff); u.a.h1t[la1] = (unsigned short)(w1 >> 16);
            u.a.h2t[la0] = (unsigned short)(w2 & 0xffff); u.a.h2t[la1] = (unsigned short)(w2 >> 16);
        }
    }
    for (int i = tid; i < 576; i += 256) {
        int node = i / 144, r = i - node * 144;
        int rr = (r < 72) ? 0 : 13;
        u.a.gcn[node * 1008 + rr * 72 + (r % 72)] = 0;
    }
    if (tid < 48) sdp[tid] = sdiag[(size_t)b * NN + node0 + tid / 12];
    if (tid < 64) { lnwS[tid] = lnw[tid]; lnbS[tid] = lnb[tid]; tbS[tid] = tcb[tid] + rcb[tid]; }

    int ocol = wv * 16 + fr;
    bf16x8 bTh[3], bWr[6], bRc;
#pragma unroll
    for (int kb = 0; kb < 3; kb++)
        bTh[kb] = *(const bf16x8*)((const short*)Th + (size_t)ocol * 96 + kb * 32 + fk * 8);
#pragma unroll
    for (int kb = 0; kb < 6; kb++)
        bWr[kb] = *(const bf16x8*)((const short*)Wr + (size_t)ocol * 192 + kb * 32 + fk * 8);
    bRc = *(const bf16x8*)((const short*)Rc + (size_t)ocol * 32 + fk * 8);

    int na[3], ta[3];
#pragma unroll
    for (int rb = 0; rb < 3; rb++) {
        int p = rb * 16 + fr;
        na[rb] = p / 12; ta[rb] = p - na[rb] * 12;
    }
    __syncthreads();

    f32x4 acc[3];
#pragma unroll
    for (int rb = 0; rb < 3; rb++) {
        int ax = na[rb] * 480 + ta[rb] * 40 + fk * 8;
        bf16x8 avx = *(const bf16x8*)(u.a.xt + ax);
        f32x4 z = (f32x4)(0.f);
        acc[rb] = __builtin_amdgcn_mfma_f32_16x16x32_bf16(avx, bTh[0], z, 0, 0, 0);
#pragma unroll
        for (int r = 0; r < 4; r++) acc[rb][r] *= sdp[rb * 16 + fk * 4 + r];
        bf16x8 av1 = *(const bf16x8*)(u.a.h1t + ax);
        acc[rb] = __builtin_amdgcn_mfma_f32_16x16x32_bf16(av1, bTh[1], acc[rb], 0, 0, 0);
        bf16x8 av2 = *(const bf16x8*)(u.a.h2t + ax);
        acc[rb] = __builtin_amdgcn_mfma_f32_16x16x32_bf16(av2, bTh[2], acc[rb], 0, 0, 0);
    }
#pragma unroll
    for (int rb = 0; rb < 3; rb++) {
#pragma unroll
        for (int r = 0; r < 4; r++) {
            int pc = rb * 16 + fk * 4 + r;
            int nc = pc / 12, tc2 = pc - nc * 12;
            u.a.gcn[nc * 1008 + (tc2 + 1) * 72 + wv * 16 + fr] = cvt_bf(fmaxf(acc[rb][r], 0.f));
        }
    }
    __syncthreads();
#pragma unroll
    for (int rb = 0; rb < 3; rb++) {
        f32x4 a2 = (f32x4)(0.f);
#pragma unroll
        for (int kb = 0; kb < 6; kb++) {
            int dt = kb >> 1, c0 = (kb & 1) * 32;
            bf16x8 ag = *(const bf16x8*)(u.a.gcn + na[rb] * 1008 + (ta[rb] + dt) * 72 + c0 + fk * 8);
            a2 = __builtin_amdgcn_mfma_f32_16x16x32_bf16(ag, bWr[kb], a2, 0, 0, 0);
        }
        int ax = na[rb] * 480 + ta[rb] * 40 + fk * 8;
        bf16x8 avx = *(const bf16x8*)(u.a.xt + ax);
        acc[rb] = __builtin_amdgcn_mfma_f32_16x16x32_bf16(avx, bRc, a2, 0, 0, 0);
    }
    __syncthreads();
    float tb = tbS[ocol];
#pragma unroll
    for (int rb = 0; rb < 3; rb++)
#pragma unroll
        for (int r = 0; r < 4; r++)
            u.Y[(rb * 16 + fk * 4 + r) * 65 + ocol] = acc[rb][r] + tb;
    __syncthreads();
    if (tid < 48) {
        float s = 0.f, s2 = 0.f;
        for (int o = 0; o < 64; o++) {
            float v = u.Y[tid * 65 + o];
            s += v; s2 += v * v;
        }
        float mm = s * (1.f / 64.f);
        float var = s2 * (1.f / 64.f) - mm * mm;
        muS[tid] = mm; rsS[tid] = rsqrtf(var + 1e-5f);
    }
    __syncthreads();
    float2* obv = (float2*)(out + rowb * 2);
    for (int q = tid; q < 1536; q += 256) {
        int i = q * 2;
        int node = i / 768, rr = i - node * 768;
        int o = rr / 12, t = rr - o * 12;
        int p0 = node * 12 + t;
        float v0 = (u.Y[p0 * 65 + o] - muS[p0]) * rsS[p0] * lnwS[o] + lnbS[o];
        int t1 = t + 1, o1 = o;
        if (t1 == 12) { t1 = 0; o1 = o + 1; }
        int p1 = node * 12 + t1;
        float v1 = (u.Y[p1 * 65 + o1] - muS[p1]) * rsS[p1] * lnwS[o1] + lnbS[o1];
        float2 pk; pk.x = v0; pk.y = v1;
        obv[q] = pk;
    }
}

extern "C" void kernel_launch(void* const* d_in, const int* in_sizes, int n_in,
                              void* d_out, int out_size, void* d_ws, size_t ws_size,
                              hipStream_t stream)
{
    const float* x    = (const float*)d_in[0];
    const float* emb  = (const float*)d_in[1];
    const float* W1   = (const float*)d_in[2];
    const float* W2   = (const float*)d_in[3];
    const float* W3   = (const float*)d_in[4];
    const float* bs   = (const float*)d_in[5];
    const float* Vs   = (const float*)d_in[6];
    const float* U1   = (const float*)d_in[7];
    const float* U2   = (const float*)d_in[8];
    const float* U3   = (const float*)d_in[9];
    const float* be   = (const float*)d_in[10];
    const float* Ve   = (const float*)d_in[11];
    const float* Theta= (const float*)d_in[12];
    const float* tcv  = (const float*)d_in[13];
    const float* tcg  = (const float*)d_in[14];
    const float* tcb  = (const float*)d_in[15];
    const float* rcw  = (const float*)d_in[16];
    const float* rcb  = (const float*)d_in[17];
    const float* lnw  = (const float*)d_in[18];
    const float* lnb  = (const float*)d_in[19];

    float* xres = (float*)d_out;                       // B*N*FT*T fp32 (scratch for At2 until k_tail)
    float* spat = xres + (size_t)NB * NN * NFT * NT;   // B*N*N fp32

    char* base = (char*)d_ws;
    unsigned short* Xrow = (unsigned short*)(base + 0);
    unsigned short* Pt   = (unsigned short*)(base + 0);
    unsigned short* supB = (unsigned short*)(base + 0);
    unsigned short* supT = (unsigned short*)(base + 2097152);
    unsigned short* At1  = (unsigned short*)(base + 0);
    unsigned short* At2  = (unsigned short*)xres;          // d_out scratch
    unsigned short* Xt  = (unsigned short*)(base + 33554432);
    unsigned short* h1  = (unsigned short*)(base + 46137344);
    unsigned short* h2  = (unsigned short*)(base + 58720256);
    unsigned short* Vsb = (unsigned short*)(base + 71303168);
    float* colsum  = (float*)(base + 73400320);
    float* sdiag   = (float*)(base + 73465856);
    float* sup     = (float*)(base + 77594624);
    float* supsq   = (float*)(base + 81788928);
    float* lhs_pre = (float*)(base + 85983232);
    float* lhs     = (float*)(base + 86007808);
    float* rhs     = (float*)(base + 86794240);
    float* rr3     = (float*)(base + 87580672);
    float* prod    = (float*)(base + 88367104);
    float* E       = (float*)(base + 88376320);
    float* EW1     = (float*)(base + 88385536);
    float* l2      = (float*)(base + 88386560);
    float* r2      = (float*)(base + 89172992);
    unsigned short* Wr = (unsigned short*)(base + 89959424);
    unsigned short* Th = (unsigned short*)(base + 89984000);
    unsigned short* Rc = (unsigned short*)(base + 89996288);

    hipMemsetAsync(lhs_pre, 0, 6144 * sizeof(float), stream);
    hipMemsetAsync(supsq, 0, (size_t)NN * NN * sizeof(float), stream);

    // pre-pass: x fp32 -> lhs_pre, rhs, rr3, Xrow(bf16)
    k_pre<<<dim3(16, 16), 384, 0, stream>>>(x, U1, U3, W3, lhs_pre, rhs, rr3, Xrow);
    k_lhs<<<192, 256, 0, stream>>>(lhs_pre, U2, lhs);
    k_prod<<<2304, 64, 0, stream>>>(lhs, rhs, prod);
    k_E<<<16, 192, 0, stream>>>(prod, be, Ve, W1, E, EW1);
    // spatial attention
    k_l2r2x<<<dim3(128, 16), 384, 0, stream>>>(Xrow, rr3, E, EW1, W2, l2, r2);
    k_xt<<<dim3(6, 16, 16), 256, 0, stream>>>(Xrow, Xt);       // before Pt overwrites Xrow
    k_Ptile<<<dim3(16, 16, 16), 256, 0, stream>>>(l2, r2, bs, Pt);
    k_cvt<<<1024, 256, 0, stream>>>(Vs, Vsb);
    hipMemsetAsync(colsum, 0, (size_t)NB * NN * sizeof(float), stream);
    mgemm<2><<<dim3(8, 8, 16), 256, 0, stream>>>((const short*)Vsb, (const short*)Pt,
        (void*)spat, NN, 0, NN, NN, NN, 0L, (long)NN * NN, (long)NN * NN, colsum);
    // graph supports
    k_sup<<<1024, 256, 0, stream>>>(emb, sup, supB);
    k_tb16<<<dim3(16, 16), 256, 0, stream>>>(supB, supT);
    mgemm<3><<<dim3(8, 8, 4), 256, 0, stream>>>((const short*)supB, (const short*)supT,
        (void*)supsq, NN, 256, NN, NN, NN, 0L, 0L, 0L, nullptr);
    // normalize + threshold + masked adjacencies + diagonal
    k_normprep2<<<dim3(16, 16, 16), 256, 0, stream>>>(spat, colsum, sup, supsq, At1, At2, sdiag);
    // h-GEMMs with XCD-batch swizzle
    mgemm_h<<<384, 256, 0, stream>>>((const short*)At1, (const short*)Xt, h1);
    mgemm_h<<<384, 256, 0, stream>>>((const short*)At2, (const short*)Xt, h2);
    // tail
    k_wprep<<<65, 256, 0, stream>>>(tcv, tcg, Theta, rcw, Wr, Th, Rc);
    k_tail<<<dim3(256, 16), 256, 0, stream>>>(x, h1, h2, sdiag, Th, Wr, Rc,
                                              tcb, rcb, lnw, lnb, xres);
}

// Round 10
// 316.280 us; speedup vs baseline: 1.2267x; 1.0652x over previous
//
#include <hip/hip_runtime.h>
#include <math.h>

#define NB 16      // B
#define NN 1024    // N
#define NF 32      // F
#define NT 12      // T
#define NFC 64
#define NFT 64

typedef __attribute__((ext_vector_type(8))) short bf16x8;
typedef __attribute__((ext_vector_type(4))) float f32x4;

__device__ inline unsigned short cvt_bf(float f) {
    unsigned int u = __float_as_uint(f);
    u += 0x7fff + ((u >> 16) & 1);
    return (unsigned short)(u >> 16);
}
__device__ inline float bf2f(unsigned short u) {
    return __uint_as_float(((unsigned int)u) << 16);
}
__device__ inline void gll16(const short* g, short* l) {
    __builtin_amdgcn_global_load_lds((const __attribute__((address_space(1))) void*)g,
                                     (__attribute__((address_space(3))) void*)l, 16, 0, 0);
}

// ---------------- fused pre-pass: lhs_pre (U1), rhs (U3), rr3 (W3), Xrow (bf16, packed writes) ----------------
__global__ __launch_bounds__(384) void k_pre(const float* __restrict__ x,
                                             const float* __restrict__ U1,
                                             const float* __restrict__ U3,
                                             const float* __restrict__ W3,
                                             float* __restrict__ lhs_pre,
                                             float* __restrict__ rhs,
                                             float* __restrict__ rr3,
                                             unsigned short* __restrict__ Xrow)
{
    __shared__ float xs[8 * 384];
    int b = blockIdx.x, ch = blockIdx.y, tid = threadIdx.x;
    float acc = 0.f;
    for (int c8 = 0; c8 < 8; c8++) {
        int n0 = ch * 64 + c8 * 8;
        size_t r0 = (size_t)b * NN + n0;
        __syncthreads();
        for (int i = 0; i < 8; i++) xs[i * 384 + tid] = x[(r0 + i) * 384 + tid];
        __syncthreads();
        for (int i = 0; i < 8; i++) acc += xs[i * 384 + tid] * U1[n0 + i];
        for (int idx = tid; idx < 1536; idx += 384) {
            int row = idx / 192, jj = (idx - row * 192) * 2;
            unsigned int w = (unsigned int)cvt_bf(xs[row * 384 + jj])
                           | ((unsigned int)cvt_bf(xs[row * 384 + jj + 1]) << 16);
            *(unsigned int*)(Xrow + (r0 + row) * 384 + jj) = w;
        }
        if (tid < 192) {
            int half = tid / 96;
            int r = tid - half * 96;
            int i = r / 12, t = r - i * 12;
            const float* wv = half ? W3 : U3;
            float s = 0.f;
            for (int f = 0; f < 32; f++) s += wv[f] * xs[i * 384 + f * 12 + t];
            float* outp = half ? rr3 : rhs;
            outp[(r0 + i) * 12 + t] = s;
        }
    }
    int f = tid / 12, t = tid - f * 12;
    atomicAdd(&lhs_pre[b * 384 + t * 32 + f], acc);
}

__global__ __launch_bounds__(256) void k_lhs(const float* __restrict__ lhs_pre,
                                             const float* __restrict__ U2,
                                             float* __restrict__ lhs)
{
    int bt = blockIdx.x;
    int tid = threadIdx.x;
    __shared__ float lp[32];
    if (tid < 32) lp[tid] = lhs_pre[bt * 32 + tid];
    __syncthreads();
    for (int q = 0; q < 4; q++) {
        int n = q * 256 + tid;
        float a = 0.f;
        for (int f = 0; f < 32; f++) a += lp[f] * U2[f * NN + n];
        lhs[(size_t)bt * NN + n] = a;
    }
}

__global__ __launch_bounds__(64) void k_prod(const float* __restrict__ lhs,
                                             const float* __restrict__ rhs,
                                             float* __restrict__ prod)
{
    int blk = blockIdx.x;
    int b = blk / 144, r = blk - b * 144;
    int s = r / 12, u = r - s * 12;
    int tid = threadIdx.x;
    float p = 0.f;
    for (int n = tid; n < NN; n += 64)
        p += lhs[((size_t)b * 12 + s) * NN + n] * rhs[((size_t)b * NN + n) * 12 + u];
    for (int o = 32; o > 0; o >>= 1) p += __shfl_xor(p, o);
    if (tid == 0) prod[blk] = p;
}

// E (softmax over t) + EW1[b][t] = sum_u E[b,t,u]*W1[u]
__global__ __launch_bounds__(192) void k_E(const float* __restrict__ prod,
                                           const float* __restrict__ be,
                                           const float* __restrict__ Ve,
                                           const float* __restrict__ W1,
                                           float* __restrict__ E,
                                           float* __restrict__ EW1)
{
    int b = blockIdx.x, tid = threadIdx.x;
    __shared__ float ssig[144], sE[144], mx[12], sm[12];
    if (tid < 144) ssig[tid] = 1.f / (1.f + expf(-(prod[b * 144 + tid] + be[tid])));
    __syncthreads();
    if (tid < 144) {
        int t = tid / 12, u = tid - t * 12;
        float a = 0.f;
        for (int s2 = 0; s2 < 12; s2++) a += Ve[t * 12 + s2] * ssig[s2 * 12 + u];
        sE[tid] = a;
    }
    __syncthreads();
    if (tid < 12) {
        float m = -1e30f;
        for (int t = 0; t < 12; t++) m = fmaxf(m, sE[t * 12 + tid]);
        float s = 0.f;
        for (int t = 0; t < 12; t++) s += expf(sE[t * 12 + tid] - m);
        mx[tid] = m; sm[tid] = s;
    }
    __syncthreads();
    float val = 0.f;
    if (tid < 144) {
        int u = tid % 12;
        val = expf(sE[tid] - mx[u]) / sm[u];
        E[b * 144 + tid] = val;
    }
    __syncthreads();
    if (tid < 144) sE[tid] = val;
    __syncthreads();
    if (tid < 12) {
        float a = 0.f;
        for (int u = 0; u < 12; u++) a += sE[tid * 12 + u] * W1[u];
        EW1[b * 12 + tid] = a;
    }
}

// ---------------- l2/r2 from Xrow (bf16, packed loads) ----------------
__global__ __launch_bounds__(384) void k_l2r2x(const unsigned short* __restrict__ Xrow,
                                               const float* __restrict__ rr3,
                                               const float* __restrict__ E,
                                               const float* __restrict__ EW1,
                                               const float* __restrict__ W2,
                                               float* __restrict__ l2,
                                               float* __restrict__ r2)
{
    __shared__ float xs[8 * 384];
    __shared__ float Es[144], ew[12], rrs[96], lp[8][32];
    int b = blockIdx.y, tid = threadIdx.x;
    int n0 = blockIdx.x * 8;
    size_t r0 = (size_t)b * NN + n0;
    if (tid < 144) Es[tid] = E[b * 144 + tid];
    if (tid < 12) ew[tid] = EW1[b * 12 + tid];
    if (tid < 96) rrs[tid] = rr3[(r0 + tid / 12) * 12 + (tid % 12)];
    const unsigned int* Xr = (const unsigned int*)(Xrow + r0 * 384);
    for (int i2 = tid; i2 < 1536; i2 += 384) {
        unsigned int w = Xr[i2];
        xs[2 * i2]     = bf2f((unsigned short)(w & 0xffff));
        xs[2 * i2 + 1] = bf2f((unsigned short)(w >> 16));
    }
    __syncthreads();
    if (tid < 256) {
        int i = tid >> 5, f = tid & 31;
        float a = 0.f;
#pragma unroll
        for (int t = 0; t < 12; t++) a += xs[i * 384 + f * 12 + t] * ew[t];
        lp[i][f] = a;
    }
    __syncthreads();
    if (tid < 96) {
        int i = tid / 12, u = tid - i * 12;
        float a = 0.f;
        for (int f = 0; f < 32; f++) a += lp[i][f] * W2[f * 12 + u];
        l2[(r0 + i) * 12 + u] = a;
        float rv = 0.f;
#pragma unroll
        for (int t = 0; t < 12; t++) rv += rrs[i * 12 + t] * Es[t * 12 + u];
        r2[((size_t)b * 12 + u) * NN + n0 + i] = rv;
    }
}

// Xt[b][j][n] = Xrow[b][n][j]
__global__ __launch_bounds__(256) void k_xt(const unsigned short* __restrict__ Xrow,
                                            unsigned short* __restrict__ Xt)
{
    __shared__ unsigned short tl[64][66];
    int b = blockIdx.z;
    int n0 = blockIdx.y * 64, j0 = blockIdx.x * 64;
    int tid = threadIdx.x;
    int c = tid & 63, r0 = tid >> 6;
    for (int i = 0; i < 16; i++) {
        int r = r0 + i * 4;
        tl[r][c] = Xrow[((size_t)b * NN + n0 + r) * 384 + j0 + c];
    }
    __syncthreads();
    int c2 = tid & 31, r4 = tid >> 5;
    unsigned short* ob = Xt + ((size_t)b * 384 + j0) * NN + n0;
    for (int i = 0; i < 8; i++) {
        int jr = r4 + i * 8;
        unsigned int v0 = (unsigned int)tl[2 * c2][jr] | ((unsigned int)tl[2 * c2 + 1][jr] << 16);
        *(unsigned int*)(ob + (size_t)jr * NN + 2 * c2) = v0;
    }
}

// ---------------- tiled P ----------------
__global__ __launch_bounds__(256) void k_Ptile(const float* __restrict__ l2,
                                               const float* __restrict__ r2,
                                               const float* __restrict__ bsin,
                                               unsigned short* __restrict__ Pt)
{
    __shared__ float l2s[64][13];
    __shared__ float r2s[12][64];
    __shared__ float bsS[64][65];
    int k0 = blockIdx.x * 64, m0 = blockIdx.y * 64, b = blockIdx.z;
    int tid = threadIdx.x;
    for (int i = tid; i < 768; i += 256) {
        int r = i / 12, t = i - r * 12;
        l2s[r][t] = l2[((size_t)b * NN + m0 + r) * 12 + t];
    }
    for (int i = tid; i < 768; i += 256) {
        int t = i >> 6, k = i & 63;
        r2s[t][k] = r2[((size_t)b * 12 + t) * NN + k0 + k];
    }
    for (int i = tid; i < 4096; i += 256) {
        int r = i >> 6, c = i & 63;
        bsS[r][c] = bsin[(size_t)(m0 + r) * NN + k0 + c];
    }
    __syncthreads();
    int m = tid & 63, kg = tid >> 6;
    float lv[12];
#pragma unroll
    for (int t = 0; t < 12; t++) lv[t] = l2s[m][t];
#pragma unroll
    for (int s = 0; s < 16; s++) {
        int kl = kg * 16 + s;
        float p = bsS[m][kl];
#pragma unroll
        for (int t = 0; t < 12; t++) p += lv[t] * r2s[t][kl];
        float sg = 1.f / (1.f + expf(-p));
        Pt[((size_t)b * NN + k0 + kl) * NN + m0 + m] = cvt_bf(sg);
    }
}

// Vs fp32 -> bf16
__global__ __launch_bounds__(256) void k_cvt(const float* __restrict__ s,
                                             unsigned short* __restrict__ d)
{
    size_t i = ((size_t)blockIdx.x * 256 + threadIdx.x) * 4;
    float4 v = *(const float4*)(s + i);
    unsigned int p0 = (unsigned int)cvt_bf(v.x) | ((unsigned int)cvt_bf(v.y) << 16);
    unsigned int p1 = (unsigned int)cvt_bf(v.z) | ((unsigned int)cvt_bf(v.w) << 16);
    *(unsigned int*)(d + i) = p0;
    *(unsigned int*)(d + i + 2) = p1;
}

// bf16 transpose 1024x1024
__global__ __launch_bounds__(256) void k_tb16(const unsigned short* __restrict__ s,
                                              unsigned short* __restrict__ d)
{
    __shared__ unsigned short tl[64][65];
    int r0 = blockIdx.y * 64, c0 = blockIdx.x * 64;
    int tid = threadIdx.x;
    int c = tid & 63, rr = tid >> 6;
    for (int i = 0; i < 16; i++)
        tl[rr + i * 4][c] = s[(size_t)(r0 + rr + i * 4) * NN + c0 + c];
    __syncthreads();
    for (int i = 0; i < 16; i++)
        d[(size_t)(c0 + rr + i * 4) * NN + r0 + c] = tl[c][rr + i * 4];
}

// ---------------- 8-phase 256x256 S-GEMM: C[b] = exp(Vs @ Pt[b]^T) + colsum ----------------
// T2 (read swizzle + pre-swizzled gload src), T3+T4 (8-phase, counted vmcnt), T5 (setprio).
__device__ inline void stage2(const short* __restrict__ g, int grow0, int gk0,
                              short* dstbase, int tid)
{
#pragma unroll
    for (int o = 0; o < 2; o++) {
        int y = o * 8192 + tid * 16;                  // byte offset within 16KB half-tile
        int rowh = y >> 7;                            // 0..127
        int colb = (y & 127) ^ ((rowh & 7) << 4);     // inverse swizzle on source
        const short* src = g + (size_t)(grow0 + rowh) * NN + gk0 + (colb >> 1);
        gll16(src, dstbase + (y >> 1));               // linear LDS dest
    }
}

__global__ __launch_bounds__(512, 2) void sgemm8(const short* __restrict__ A,   // Vs bf16
                                                 const short* __restrict__ Bm,  // Pt
                                                 float* __restrict__ C,
                                                 float* __restrict__ colsum)
{
    int bz = blockIdx.z;
    const short* Bb = Bm + (size_t)bz * NN * NN;
    int i0 = blockIdx.y * 256, j0 = blockIdx.x * 256;
    __shared__ short sm[65536];   // 128 KiB: buf p @p*32768 shorts: A 16384, B 16384 (halves 8192)
    int tid = threadIdx.x;
    int ln = tid & 63, wv = tid >> 6;
    int wm = (wv >> 2) * 128, wn = (wv & 3) * 64;
    int fr = ln & 15, fk = ln >> 4;
    int ahalf = wv >> 2;
    int bhalf = wn >> 7;
    int bcol = wn & 64;
    int swz = (fr & 7) << 4;                          // byte swizzle for reads
    int kcol0 = ((fk * 16) ^ swz) >> 1;               // ks=0 (shorts)
    int kcol1 = ((64 + fk * 16) ^ swz) >> 1;          // ks=1

    f32x4 acc[8][4];
#pragma unroll
    for (int m = 0; m < 8; m++)
#pragma unroll
        for (int n = 0; n < 4; n++) acc[m][n] = (f32x4)(0.f);

    // prologue: B(0), A(0), B(1)
    stage2(Bb, j0 + 0,   0,  sm + 16384,        tid);
    stage2(Bb, j0 + 128, 0,  sm + 16384 + 8192, tid);
    stage2(A,  i0 + 0,   0,  sm + 0,            tid);
    stage2(A,  i0 + 128, 0,  sm + 8192,         tid);
    stage2(Bb, j0 + 0,   64, sm + 32768 + 16384,        tid);
    stage2(Bb, j0 + 128, 64, sm + 32768 + 16384 + 8192, tid);
    asm volatile("s_waitcnt vmcnt(4)" ::: "memory");
    __builtin_amdgcn_s_barrier();

    for (int i = 0; i < 8; i++) {
        bf16x8 bv[8];
#pragma unroll
        for (int ph = 0; ph < 8; ph++) {
            int t = 2 * i + (ph >> 2);
            int p = t & 1;
            int q = ph & 3;
            int abase = p * 32768 + ahalf * 8192;
            int bbase = p * 32768 + 16384 + bhalf * 8192;
            if (q == 0) {
#pragma unroll
                for (int nj = 0; nj < 4; nj++) {
                    int browh = bcol + nj * 16 + fr;
                    bv[nj * 2 + 0] = *(const bf16x8*)(sm + bbase + browh * 64 + kcol0);
                    bv[nj * 2 + 1] = *(const bf16x8*)(sm + bbase + browh * 64 + kcol1);
                }
            }
            bf16x8 av[4];
#pragma unroll
            for (int m2 = 0; m2 < 2; m2++) {
                int rowh = (2 * q + m2) * 16 + fr;
                av[m2 * 2 + 0] = *(const bf16x8*)(sm + abase + rowh * 64 + kcol0);
                av[m2 * 2 + 1] = *(const bf16x8*)(sm + abase + rowh * 64 + kcol1);
            }
            // staging schedule: ph0/1 A(2i+1), ph2/3 B(2i+2), ph4/5 A(2i+2), ph6/7 B(2i+3)
            {
                int st, smat, shalf;
                if (ph == 0)      { st = 2 * i + 1; smat = 0; shalf = 0; }
                else if (ph == 1) { st = 2 * i + 1; smat = 0; shalf = 1; }
                else if (ph == 2) { st = 2 * i + 2; smat = 1; shalf = 0; }
                else if (ph == 3) { st = 2 * i + 2; smat = 1; shalf = 1; }
                else if (ph == 4) { st = 2 * i + 2; smat = 0; shalf = 0; }
                else if (ph == 5) { st = 2 * i + 2; smat = 0; shalf = 1; }
                else if (ph == 6) { st = 2 * i + 3; smat = 1; shalf = 0; }
                else              { st = 2 * i + 3; smat = 1; shalf = 1; }
                if (st < 16) {
                    short* dst = sm + (st & 1) * 32768 + smat * 16384 + shalf * 8192;
                    const short* g = smat ? Bb : A;
                    int grow0 = (smat ? j0 : i0) + shalf * 128;
                    stage2(g, grow0, st * 64, dst, tid);
                }
            }
            __builtin_amdgcn_s_barrier();
            __builtin_amdgcn_s_setprio(1);
#pragma unroll
            for (int m2 = 0; m2 < 2; m2++)
#pragma unroll
                for (int nj = 0; nj < 4; nj++) {
                    acc[2 * q + m2][nj] = __builtin_amdgcn_mfma_f32_16x16x32_bf16(
                        av[m2 * 2 + 0], bv[nj * 2 + 0], acc[2 * q + m2][nj], 0, 0, 0);
                    acc[2 * q + m2][nj] = __builtin_amdgcn_mfma_f32_16x16x32_bf16(
                        av[m2 * 2 + 1], bv[nj * 2 + 1], acc[2 * q + m2][nj], 0, 0, 0);
                }
            __builtin_amdgcn_s_setprio(0);
            if (ph == 3 || ph == 7) {
                if (i < 7) asm volatile("s_waitcnt vmcnt(4)" ::: "memory");
                else       asm volatile("s_waitcnt vmcnt(0)" ::: "memory");
            }
            __builtin_amdgcn_s_barrier();
        }
    }
    // epilogue: exp + store + colsum atomics
    float* Cb = C + (size_t)bz * NN * NN;
#pragma unroll
    for (int nj = 0; nj < 4; nj++) {
        int col = j0 + wn + nj * 16 + fr;
        float cs = 0.f;
#pragma unroll
        for (int m = 0; m < 8; m++) {
            int row = i0 + wm + m * 16 + fk * 4;
#pragma unroll
            for (int r = 0; r < 4; r++) {
                float e = expf(acc[m][nj][r]);
                Cb[(size_t)(row + r) * NN + col] = e;
                cs += e;
            }
        }
        cs += __shfl_xor(cs, 16);
        cs += __shfl_xor(cs, 32);
        if (ln < 16) atomicAdd(&colsum[(size_t)bz * NN + col], cs);
    }
}

// ---------------- MFMA bf16 NT GEMM (MODE 3: split-K fp32 atomicAdd) ----------------
template<int MODE>
__global__ __launch_bounds__(256) void mgemm(const short* __restrict__ A,
                                             const short* __restrict__ B,
                                             void* __restrict__ Cv,
                                             int Kd, int kchunk,
                                             int ldA, int ldB, int ldC,
                                             long sA, long sB, long sC,
                                             float* __restrict__ colsum)
{
    int bz = blockIdx.z;
    const short* Ab = A + (size_t)bz * sA;
    const short* Bb = B + (size_t)bz * sB;
    int i0 = blockIdx.y * 128, j0 = blockIdx.x * 128;
    __shared__ short sm[16384];
    int tid = threadIdx.x;
    int ln = tid & 63, wv = tid >> 6;
    int wm = (wv >> 1) * 64, wn = (wv & 1) * 64;
    int fr = ln & 15, fk = ln >> 4;
    f32x4 acc[4][4];
#pragma unroll
    for (int a = 0; a < 4; a++)
#pragma unroll
        for (int b2 = 0; b2 < 4; b2++) acc[a][b2] = (f32x4)(0.f);

    int k_lo = 0, k_hi = Kd;
    if constexpr (MODE == 3) { k_lo = bz * kchunk; k_hi = k_lo + kchunk; }

    for (int k0 = k_lo; k0 < k_hi; k0 += 64) {
#pragma unroll
        for (int q = 0; q < 4; q++) {
            int e = q * 2048 + tid * 8;
            const short* src = Ab + (size_t)(i0 + (e >> 6)) * ldA + k0 + (e & 63);
            gll16(src, sm + e);
        }
#pragma unroll
        for (int q = 0; q < 4; q++) {
            int e = q * 2048 + tid * 8;
            const short* src = Bb + (size_t)(j0 + (e >> 6)) * ldB + k0 + (e & 63);
            gll16(src, sm + 8192 + e);
        }
        __syncthreads();
#pragma unroll
        for (int ks = 0; ks < 2; ks++) {
            bf16x8 av[4], bv[4];
#pragma unroll
            for (int mi = 0; mi < 4; mi++)
                av[mi] = *(const bf16x8*)(sm + (wm + mi * 16 + fr) * 64 + ks * 32 + fk * 8);
#pragma unroll
            for (int nj = 0; nj < 4; nj++)
                bv[nj] = *(const bf16x8*)(sm + 8192 + (wn + nj * 16 + fr) * 64 + ks * 32 + fk * 8);
#pragma unroll
            for (int mi = 0; mi < 4; mi++)
#pragma unroll
                for (int nj = 0; nj < 4; nj++)
                    acc[mi][nj] = __builtin_amdgcn_mfma_f32_16x16x32_bf16(av[mi], bv[nj], acc[mi][nj], 0, 0, 0);
        }
        __syncthreads();
    }
    if constexpr (MODE == 3) {
        float* Cb = (float*)Cv;
#pragma unroll
        for (int mi = 0; mi < 4; mi++)
#pragma unroll
            for (int nj = 0; nj < 4; nj++) {
                int row = i0 + wm + mi * 16 + fk * 4;
                int col = j0 + wn + nj * 16 + fr;
#pragma unroll
                for (int r = 0; r < 4; r++)
                    atomicAdd(&Cb[(size_t)(row + r) * ldC + col], acc[mi][nj][r]);
            }
    }
}

// ---------------- h-GEMM with XCD-batch swizzle ----------------
__global__ __launch_bounds__(256) void mgemm_h(const short* __restrict__ A,
                                               const short* __restrict__ B,
                                               unsigned short* __restrict__ C)
{
    int id = blockIdx.x;
    int xcd = id & 7, jj = id >> 3;
    int b = (xcd << 1) | (jj / 24);
    int r = jj % 24;
    int i0 = (r / 3) * 128, j0 = (r % 3) * 128;
    const short* Ab = A + (size_t)b * NN * NN;
    const short* Bb = B + (size_t)b * 384 * NN;
    __shared__ short sm[16384];
    int tid = threadIdx.x;
    int ln = tid & 63, wv = tid >> 6;
    int wm = (wv >> 1) * 64, wn = (wv & 1) * 64;
    int fr = ln & 15, fk = ln >> 4;
    f32x4 acc[4][4];
#pragma unroll
    for (int a = 0; a < 4; a++)
#pragma unroll
        for (int b2 = 0; b2 < 4; b2++) acc[a][b2] = (f32x4)(0.f);

    for (int k0 = 0; k0 < NN; k0 += 64) {
#pragma unroll
        for (int q = 0; q < 4; q++) {
            int e = q * 2048 + tid * 8;
            gll16(Ab + (size_t)(i0 + (e >> 6)) * NN + k0 + (e & 63), sm + e);
        }
#pragma unroll
        for (int q = 0; q < 4; q++) {
            int e = q * 2048 + tid * 8;
            gll16(Bb + (size_t)(j0 + (e >> 6)) * NN + k0 + (e & 63), sm + 8192 + e);
        }
        __syncthreads();
#pragma unroll
        for (int ks = 0; ks < 2; ks++) {
            bf16x8 av[4], bv[4];
#pragma unroll
            for (int mi = 0; mi < 4; mi++)
                av[mi] = *(const bf16x8*)(sm + (wm + mi * 16 + fr) * 64 + ks * 32 + fk * 8);
#pragma unroll
            for (int nj = 0; nj < 4; nj++)
                bv[nj] = *(const bf16x8*)(sm + 8192 + (wn + nj * 16 + fr) * 64 + ks * 32 + fk * 8);
#pragma unroll
            for (int mi = 0; mi < 4; mi++)
#pragma unroll
                for (int nj = 0; nj < 4; nj++)
                    acc[mi][nj] = __builtin_amdgcn_mfma_f32_16x16x32_bf16(av[mi], bv[nj], acc[mi][nj], 0, 0, 0);
        }
        __syncthreads();
    }
#pragma unroll
    for (int mi = 0; mi < 4; mi++)
#pragma unroll
        for (int nj = 0; nj < 4; nj++) {
            int row = i0 + wm + mi * 16 + fk * 4;
            int col = j0 + wn + nj * 16 + fr;
#pragma unroll
            for (int r2 = 0; r2 < 4; r2++)
                C[((size_t)b * NN + row + r2) * 384 + col] = cvt_bf(acc[mi][nj][r2]);
        }
}

// ---------------- normalize + threshold + At1 + At2 + sdiag ----------------
__global__ __launch_bounds__(256) void k_normprep2(float* __restrict__ spat,
                                                   const float* __restrict__ colsum,
                                                   const float* __restrict__ sup,
                                                   const float* __restrict__ supsq,
                                                   unsigned short* __restrict__ At1,
                                                   unsigned short* __restrict__ At2,
                                                   float* __restrict__ sdiag)
{
    __shared__ unsigned short t1[64][66];
    __shared__ unsigned short t2[64][66];
    int b = blockIdx.z;
    int n0 = blockIdx.y * 64, m0 = blockIdx.x * 64;
    int tid = threadIdx.x;
    int c = tid & 63, r0 = tid >> 6;
    const float thr = (1.0f / 1024.0f) / 0.6f;
    float inv = 1.f / colsum[(size_t)b * NN + m0 + c];
    float* sp = spat + (size_t)b * NN * NN;
    for (int i = 0; i < 16; i++) {
        int r = r0 + i * 4;
        size_t idx = (size_t)(n0 + r) * NN + m0 + c;
        float v = sp[idx] * inv;
        v = (v < thr) ? 0.f : v;
        sp[idx] = v;
        if (n0 + r == m0 + c) sdiag[(size_t)b * NN + n0 + r] = v;
        t1[r][c] = cvt_bf(sup[(size_t)(n0 + r) * NN + m0 + c] * v);
        float p2 = 2.f * supsq[(size_t)(n0 + r) * NN + m0 + c]
                 - (((n0 + r) == (m0 + c)) ? 1.f : 0.f);
        t2[r][c] = cvt_bf(p2 * v);
    }
    __syncthreads();
    int c2 = tid & 31, r4 = tid >> 5;
    size_t ob = ((size_t)b * NN + m0) * NN + n0;
    for (int i = 0; i < 8; i++) {
        int rr = r4 + i * 8;
        unsigned int v1 = (unsigned int)t1[2 * c2][rr] | ((unsigned int)t1[2 * c2 + 1][rr] << 16);
        unsigned int v2 = (unsigned int)t2[2 * c2][rr] | ((unsigned int)t2[2 * c2 + 1][rr] << 16);
        *(unsigned int*)(At1 + ob + (size_t)rr * NN + 2 * c2) = v1;
        *(unsigned int*)(At2 + ob + (size_t)rr * NN + 2 * c2) = v2;
    }
}

// ---------------- support graph ----------------
__global__ __launch_bounds__(256) void k_sup(const float* __restrict__ emb,
                                             float* __restrict__ sup,
                                             unsigned short* __restrict__ supB)
{
    int n = blockIdx.x, tid = threadIdx.x;
    __shared__ float en[16];
    if (tid < 16) en[tid] = emb[n * 16 + tid];
    __syncthreads();
    float v[4];
#pragma unroll
    for (int q = 0; q < 4; q++) {
        int m = q * 256 + tid;
        float d = 0.f;
#pragma unroll
        for (int dd = 0; dd < 16; dd++) d += en[dd] * emb[m * 16 + dd];
        v[q] = fmaxf(d, 0.f);
    }
    float mx = fmaxf(fmaxf(v[0], v[1]), fmaxf(v[2], v[3]));
    for (int o = 32; o > 0; o >>= 1) mx = fmaxf(mx, __shfl_xor(mx, o));
    __shared__ float red[4];
    if ((tid & 63) == 0) red[tid >> 6] = mx;
    __syncthreads();
    mx = fmaxf(fmaxf(red[0], red[1]), fmaxf(red[2], red[3]));
    float e[4];
    float s = 0.f;
#pragma unroll
    for (int q = 0; q < 4; q++) { e[q] = expf(v[q] - mx); s += e[q]; }
    for (int o = 32; o > 0; o >>= 1) s += __shfl_xor(s, o);
    __shared__ float red2[4];
    if ((tid & 63) == 0) red2[tid >> 6] = s;
    __syncthreads();
    s = red2[0] + red2[1] + red2[2] + red2[3];
    float inv = 1.f / s;
#pragma unroll
    for (int q = 0; q < 4; q++) {
        float val = e[q] * inv;
        sup[(size_t)n * NN + q * 256 + tid] = val;
        supB[(size_t)n * NN + q * 256 + tid] = cvt_bf(val);
    }
}

// ---------------- merged weight prep ----------------
__global__ __launch_bounds__(256) void k_wprep(const float* __restrict__ tcv,
                                               const float* __restrict__ tcg,
                                               const float* __restrict__ Theta,
                                               const float* __restrict__ rcw,
                                               unsigned short* __restrict__ Wr,
                                               unsigned short* __restrict__ Th,
                                               unsigned short* __restrict__ Rc)
{
    int tid = threadIdx.x;
    if (blockIdx.x < 64) {
        int o = blockIdx.x;
        float t = 0.f, p = 0.f;
        if (tid < 192) { t = tcv[o * 192 + tid]; p = t * t; }
        for (int off = 32; off > 0; off >>= 1) p += __shfl_xor(p, off);
        __shared__ float wsr[3];
        if (tid < 192 && (tid & 63) == 0) wsr[tid >> 6] = p;
        __syncthreads();
        if (tid < 192) {
            float sum = wsr[0] + wsr[1] + wsr[2];
            int c = tid / 3, dt = tid - c * 3;
            Wr[o * 192 + dt * 64 + c] = cvt_bf(t * (tcg[o] / sqrtf(sum)));
        }
    } else {
        for (int i = tid; i < 6144; i += 256) {
            int o = i / 96, rem = i - o * 96;
            int kind = rem >> 5, f = rem & 31;
            Th[i] = cvt_bf(Theta[kind * 2048 + f * 64 + o]);
        }
        for (int i = tid; i < 2048; i += 256) Rc[i] = cvt_bf(rcw[i]);
    }
}

// ---------------- MFMA fused tail ----------------
__global__ __launch_bounds__(256) void k_tail(const float* __restrict__ x,
                                              const unsigned short* __restrict__ h1,
                                              const unsigned short* __restrict__ h2,
                                              const float* __restrict__ sdiag,
                                              const unsigned short* __restrict__ Th,
                                              const unsigned short* __restrict__ Wr,
                                              const unsigned short* __restrict__ Rc,
                                              const float* __restrict__ tcb,
                                              const float* __restrict__ rcb,
                                              const float* __restrict__ lnw,
                                              const float* __restrict__ lnb,
                                              float* __restrict__ out)
{
    int b = blockIdx.y;
    int node0 = blockIdx.x * 4;
    int tid = threadIdx.x;
    int ln = tid & 63, wv = tid >> 6;
    int fr = ln & 15, fk = ln >> 4;

    __shared__ union {
        struct { unsigned short xt[1920], h1t[1920], h2t[1920], gcn[4032]; } a;
        float Y[48 * 65];
    } u;
    __shared__ float sdp[48];
    __shared__ float lnwS[64], lnbS[64], tbS[64];
    __shared__ float muS[48], rsS[48];

    size_t rowb = ((size_t)b * NN + node0) * 384;
    {
        const float2* xp = (const float2*)(x + rowb);
        const unsigned int* h1p = (const unsigned int*)(h1 + rowb);
        const unsigned int* h2p = (const unsigned int*)(h2 + rowb);
        for (int q = tid; q < 768; q += 256) {
            int j0 = q * 2;
            int node = j0 / 384, j = j0 - node * 384;
            int f = j / 12, t = j - f * 12;
            int t2 = t + 1, f2 = f;
            if (t2 == 12) { t2 = 0; f2 = f + 1; }
            int la0 = node * 480 + t * 40 + f;
            int la1 = node * 480 + t2 * 40 + f2;
            float2 xv = xp[q];
            unsigned int w1 = h1p[q], w2 = h2p[q];
            u.a.xt[la0] = cvt_bf(xv.x);  u.a.xt[la1] = cvt_bf(xv.y);
            u.a.h1t[la0] = (unsigned short)(w1 & 0xffff); u.a.h1t[la1] = (unsigned short)(w1 >> 16);
            u.a.h2t[la0] = (unsigned short)(w2 & 0xffff); u.a.h2t[la1] = (unsigned short)(w2 >> 16);
        }
    }
    for (int i = tid; i < 576; i += 256) {
        int node = i / 144, r = i - node * 144;
        int rr = (r < 72) ? 0 : 13;
        u.a.gcn[node * 1008 + rr * 72 + (r % 72)] = 0;
    }
    if (tid < 48) sdp[tid] = sdiag[(size_t)b * NN + node0 + tid / 12];
    if (tid < 64) { lnwS[tid] = lnw[tid]; lnbS[tid] = lnb[tid]; tbS[tid] = tcb[tid] + rcb[tid]; }

    int ocol = wv * 16 + fr;
    bf16x8 bTh[3], bWr[6], bRc;
#pragma unroll
    for (int kb = 0; kb < 3; kb++)
        bTh[kb] = *(const bf16x8*)((const short*)Th + (size_t)ocol * 96 + kb * 32 + fk * 8);
#pragma unroll
    for (int kb = 0; kb < 6; kb++)
        bWr[kb] = *(const bf16x8*)((const short*)Wr + (size_t)ocol * 192 + kb * 32 + fk * 8);
    bRc = *(const bf16x8*)((const short*)Rc + (size_t)ocol * 32 + fk * 8);

    int na[3], ta[3];
#pragma unroll
    for (int rb = 0; rb < 3; rb++) {
        int p = rb * 16 + fr;
        na[rb] = p / 12; ta[rb] = p - na[rb] * 12;
    }
    __syncthreads();

    f32x4 acc[3];
#pragma unroll
    for (int rb = 0; rb < 3; rb++) {
        int ax = na[rb] * 480 + ta[rb] * 40 + fk * 8;
        bf16x8 avx = *(const bf16x8*)(u.a.xt + ax);
        f32x4 z = (f32x4)(0.f);
        acc[rb] = __builtin_amdgcn_mfma_f32_16x16x32_bf16(avx, bTh[0], z, 0, 0, 0);
#pragma unroll
        for (int r = 0; r < 4; r++) acc[rb][r] *= sdp[rb * 16 + fk * 4 + r];
        bf16x8 av1 = *(const bf16x8*)(u.a.h1t + ax);
        acc[rb] = __builtin_amdgcn_mfma_f32_16x16x32_bf16(av1, bTh[1], acc[rb], 0, 0, 0);
        bf16x8 av2 = *(const bf16x8*)(u.a.h2t + ax);
        acc[rb] = __builtin_amdgcn_mfma_f32_16x16x32_bf16(av2, bTh[2], acc[rb], 0, 0, 0);
    }
#pragma unroll
    for (int rb = 0; rb < 3; rb++) {
#pragma unroll
        for (int r = 0; r < 4; r++) {
            int pc = rb * 16 + fk * 4 + r;
            int nc = pc / 12, tc2 = pc - nc * 12;
            u.a.gcn[nc * 1008 + (tc2 + 1) * 72 + wv * 16 + fr] = cvt_bf(fmaxf(acc[rb][r], 0.f));
        }
    }
    __syncthreads();
#pragma unroll
    for (int rb = 0; rb < 3; rb++) {
        f32x4 a2 = (f32x4)(0.f);
#pragma unroll
        for (int kb = 0; kb < 6; kb++) {
            int dt = kb >> 1, c0 = (kb & 1) * 32;
            bf16x8 ag = *(const bf16x8*)(u.a.gcn + na[rb] * 1008 + (ta[rb] + dt) * 72 + c0 + fk * 8);
            a2 = __builtin_amdgcn_mfma_f32_16x16x32_bf16(ag, bWr[kb], a2, 0, 0, 0);
        }
        int ax = na[rb] * 480 + ta[rb] * 40 + fk * 8;
        bf16x8 avx = *(const bf16x8*)(u.a.xt + ax);
        acc[rb] = __builtin_amdgcn_mfma_f32_16x16x32_bf16(avx, bRc, a2, 0, 0, 0);
    }
    __syncthreads();
    float tb = tbS[ocol];
#pragma unroll
    for (int rb = 0; rb < 3; rb++)
#pragma unroll
        for (int r = 0; r < 4; r++)
            u.Y[(rb * 16 + fk * 4 + r) * 65 + ocol] = acc[rb][r] + tb;
    __syncthreads();
    if (tid < 48) {
        float s = 0.f, s2 = 0.f;
        for (int o = 0; o < 64; o++) {
            float v = u.Y[tid * 65 + o];
            s += v; s2 += v * v;
        }
        float mm = s * (1.f / 64.f);
        float var = s2 * (1.f / 64.f) - mm * mm;
        muS[tid] = mm; rsS[tid] = rsqrtf(var + 1e-5f);
    }
    __syncthreads();
    float2* obv = (float2*)(out + rowb * 2);
    for (int q = tid; q < 1536; q += 256) {
        int i = q * 2;
        int node = i / 768, rr = i - node * 768;
        int o = rr / 12, t = rr - o * 12;
        int p0 = node * 12 + t;
        float v0 = (u.Y[p0 * 65 + o] - muS[p0]) * rsS[p0] * lnwS[o] + lnbS[o];
        int t1 = t + 1, o1 = o;
        if (t1 == 12) { t1 = 0; o1 = o + 1; }
        int p1 = node * 12 + t1;
        float v1 = (u.Y[p1 * 65 + o1] - muS[p1]) * rsS[p1] * lnwS[o1] + lnbS[o1];
        float2 pk; pk.x = v0; pk.y = v1;
        obv[q] = pk;
    }
}

extern "C" void kernel_launch(void* const* d_in, const int* in_sizes, int n_in,
                              void* d_out, int out_size, void* d_ws, size_t ws_size,
                              hipStream_t stream)
{
    const float* x    = (const float*)d_in[0];
    const float* emb  = (const float*)d_in[1];
    const float* W1   = (const float*)d_in[2];
    const float* W2   = (const float*)d_in[3];
    const float* W3   = (const float*)d_in[4];
    const float* bs   = (const float*)d_in[5];
    const float* Vs   = (const float*)d_in[6];
    const float* U1   = (const float*)d_in[7];
    const float* U2   = (const float*)d_in[8];
    const float* U3   = (const float*)d_in[9];
    const float* be   = (const float*)d_in[10];
    const float* Ve   = (const float*)d_in[11];
    const float* Theta= (const float*)d_in[12];
    const float* tcv  = (const float*)d_in[13];
    const float* tcg  = (const float*)d_in[14];
    const float* tcb  = (const float*)d_in[15];
    const float* rcw  = (const float*)d_in[16];
    const float* rcb  = (const float*)d_in[17];
    const float* lnw  = (const float*)d_in[18];
    const float* lnb  = (const float*)d_in[19];

    float* xres = (float*)d_out;                       // B*N*FT*T fp32 (scratch for At2 until k_tail)
    float* spat = xres + (size_t)NB * NN * NFT * NT;   // B*N*N fp32

    char* base = (char*)d_ws;
    unsigned short* Xrow = (unsigned short*)(base + 0);
    unsigned short* Pt   = (unsigned short*)(base + 0);
    unsigned short* supB = (unsigned short*)(base + 0);
    unsigned short* supT = (unsigned short*)(base + 2097152);
    unsigned short* At1  = (unsigned short*)(base + 0);
    unsigned short* At2  = (unsigned short*)xres;          // d_out scratch
    unsigned short* Xt  = (unsigned short*)(base + 33554432);
    unsigned short* h1  = (unsigned short*)(base + 46137344);
    unsigned short* h2  = (unsigned short*)(base + 58720256);
    unsigned short* Vsb = (unsigned short*)(base + 71303168);
    float* colsum  = (float*)(base + 73400320);
    float* sdiag   = (float*)(base + 73465856);
    float* sup     = (float*)(base + 77594624);
    float* supsq   = (float*)(base + 81788928);
    float* lhs_pre = (float*)(base + 85983232);
    float* lhs     = (float*)(base + 86007808);
    float* rhs     = (float*)(base + 86794240);
    float* rr3     = (float*)(base + 87580672);
    float* prod    = (float*)(base + 88367104);
    float* E       = (float*)(base + 88376320);
    float* EW1     = (float*)(base + 88385536);
    float* l2      = (float*)(base + 88386560);
    float* r2      = (float*)(base + 89172992);
    unsigned short* Wr = (unsigned short*)(base + 89959424);
    unsigned short* Th = (unsigned short*)(base + 89984000);
    unsigned short* Rc = (unsigned short*)(base + 89996288);

    hipMemsetAsync(lhs_pre, 0, 6144 * sizeof(float), stream);
    hipMemsetAsync(supsq, 0, (size_t)NN * NN * sizeof(float), stream);

    // pre-pass: x fp32 -> lhs_pre, rhs, rr3, Xrow(bf16)
    k_pre<<<dim3(16, 16), 384, 0, stream>>>(x, U1, U3, W3, lhs_pre, rhs, rr3, Xrow);
    k_lhs<<<192, 256, 0, stream>>>(lhs_pre, U2, lhs);
    k_prod<<<2304, 64, 0, stream>>>(lhs, rhs, prod);
    k_E<<<16, 192, 0, stream>>>(prod, be, Ve, W1, E, EW1);
    // spatial attention
    k_l2r2x<<<dim3(128, 16), 384, 0, stream>>>(Xrow, rr3, E, EW1, W2, l2, r2);
    k_xt<<<dim3(6, 16, 16), 256, 0, stream>>>(Xrow, Xt);       // before Pt overwrites Xrow
    k_Ptile<<<dim3(16, 16, 16), 256, 0, stream>>>(l2, r2, bs, Pt);
    k_cvt<<<1024, 256, 0, stream>>>(Vs, Vsb);
    hipMemsetAsync(colsum, 0, (size_t)NB * NN * sizeof(float), stream);
    // 8-phase 256^2 S-GEMM with exp+colsum epilogue
    sgemm8<<<dim3(4, 4, 16), 512, 0, stream>>>((const short*)Vsb, (const short*)Pt,
                                               spat, colsum);
    // graph supports
    k_sup<<<1024, 256, 0, stream>>>(emb, sup, supB);
    k_tb16<<<dim3(16, 16), 256, 0, stream>>>(supB, supT);
    mgemm<3><<<dim3(8, 8, 4), 256, 0, stream>>>((const short*)supB, (const short*)supT,
        (void*)supsq, NN, 256, NN, NN, NN, 0L, 0L, 0L, nullptr);
    // normalize + threshold + masked adjacencies + diagonal
    k_normprep2<<<dim3(16, 16, 16), 256, 0, stream>>>(spat, colsum, sup, supsq, At1, At2, sdiag);
    // h-GEMMs with XCD-batch swizzle
    mgemm_h<<<384, 256, 0, stream>>>((const short*)At1, (const short*)Xt, h1);
    mgemm_h<<<384, 256, 0, stream>>>((const short*)At2, (const short*)Xt, h2);
    // tail
    k_wprep<<<65, 256, 0, stream>>>(tcv, tcg, Theta, rcw, Wr, Th, Rc);
    k_tail<<<dim3(256, 16), 256, 0, stream>>>(x, h1, h2, sdiag, Th, Wr, Rc,
                                              tcb, rcb, lnw, lnb, xres);
}

// Round 11
// 290.423 us; speedup vs baseline: 1.3359x; 1.0890x over previous
//
#include <hip/hip_runtime.h>
#include <math.h>

#define NB 16      // B
#define NN 1024    // N
#define NF 32      // F
#define NT 12      // T
#define NFC 64
#define NFT 64

typedef __attribute__((ext_vector_type(8))) short bf16x8;
typedef __attribute__((ext_vector_type(4))) float f32x4;

__device__ inline unsigned short cvt_bf(float f) {
    unsigned int u = __float_as_uint(f);
    u += 0x7fff + ((u >> 16) & 1);
    return (unsigned short)(u >> 16);
}
__device__ inline float bf2f(unsigned short u) {
    return __uint_as_float(((unsigned int)u) << 16);
}
__device__ inline void gll16(const short* g, short* l) {
    __builtin_amdgcn_global_load_lds((const __attribute__((address_space(1))) void*)g,
                                     (__attribute__((address_space(3))) void*)l, 16, 0, 0);
}

// ---------------- fused pre-pass: lhs_pre (U1), rhs (U3), rr3 (W3), Xrow (bf16) ----------------
__global__ __launch_bounds__(384) void k_pre(const float* __restrict__ x,
                                             const float* __restrict__ U1,
                                             const float* __restrict__ U3,
                                             const float* __restrict__ W3,
                                             float* __restrict__ lhs_pre,
                                             float* __restrict__ rhs,
                                             float* __restrict__ rr3,
                                             unsigned short* __restrict__ Xrow)
{
    __shared__ float xs[8 * 384];
    int b = blockIdx.x, ch = blockIdx.y, tid = threadIdx.x;
    float acc = 0.f;
    for (int c8 = 0; c8 < 8; c8++) {
        int n0 = ch * 64 + c8 * 8;
        size_t r0 = (size_t)b * NN + n0;
        __syncthreads();
        for (int i = 0; i < 8; i++) xs[i * 384 + tid] = x[(r0 + i) * 384 + tid];
        __syncthreads();
        for (int i = 0; i < 8; i++) acc += xs[i * 384 + tid] * U1[n0 + i];
        for (int idx = tid; idx < 1536; idx += 384) {
            int row = idx / 192, jj = (idx - row * 192) * 2;
            unsigned int w = (unsigned int)cvt_bf(xs[row * 384 + jj])
                           | ((unsigned int)cvt_bf(xs[row * 384 + jj + 1]) << 16);
            *(unsigned int*)(Xrow + (r0 + row) * 384 + jj) = w;
        }
        if (tid < 192) {
            int half = tid / 96;
            int r = tid - half * 96;
            int i = r / 12, t = r - i * 12;
            const float* wv = half ? W3 : U3;
            float s = 0.f;
            for (int f = 0; f < 32; f++) s += wv[f] * xs[i * 384 + f * 12 + t];
            float* outp = half ? rr3 : rhs;
            outp[(r0 + i) * 12 + t] = s;
        }
    }
    int f = tid / 12, t = tid - f * 12;
    atomicAdd(&lhs_pre[b * 384 + t * 32 + f], acc);
}

// M2[b][f][u] = sum_n U2[f][n] * rhs[b][n][u]   (atomic over n-chunks)
__global__ __launch_bounds__(384) void k_M2(const float* __restrict__ U2,
                                            const float* __restrict__ rhs,
                                            float* __restrict__ M2)
{
    int b = blockIdx.x, ch = blockIdx.y, tid = threadIdx.x;
    int f = tid / 12, u = tid - (tid / 12) * 12;
    int n0 = ch * 32;
    float a = 0.f;
    for (int n = n0; n < n0 + 32; n++)
        a += U2[(size_t)f * NN + n] * rhs[((size_t)b * NN + n) * 12 + u];
    atomicAdd(&M2[b * 384 + f * 12 + u], a);
}

// E (softmax over t) + EW1; prod computed inline: prod[s,u] = sum_f lhs_pre[s,f]*M2[f,u]
__global__ __launch_bounds__(192) void k_E(const float* __restrict__ lhs_pre,
                                           const float* __restrict__ M2,
                                           const float* __restrict__ be,
                                           const float* __restrict__ Ve,
                                           const float* __restrict__ W1,
                                           float* __restrict__ E,
                                           float* __restrict__ EW1)
{
    int b = blockIdx.x, tid = threadIdx.x;
    __shared__ float lp2[384], m2s[384];
    __shared__ float ssig[144], sE[144], mx[12], sm[12];
    for (int i = tid; i < 384; i += 192) {
        lp2[i] = lhs_pre[b * 384 + i];
        m2s[i] = M2[b * 384 + i];
    }
    __syncthreads();
    if (tid < 144) {
        int s = tid / 12, u = tid - s * 12;
        float p = 0.f;
#pragma unroll
        for (int f = 0; f < 32; f++) p += lp2[s * 32 + f] * m2s[f * 12 + u];
        ssig[tid] = 1.f / (1.f + expf(-(p + be[tid])));
    }
    __syncthreads();
    if (tid < 144) {
        int t = tid / 12, u = tid - t * 12;
        float a = 0.f;
        for (int s2 = 0; s2 < 12; s2++) a += Ve[t * 12 + s2] * ssig[s2 * 12 + u];
        sE[tid] = a;
    }
    __syncthreads();
    if (tid < 12) {
        float m = -1e30f;
        for (int t = 0; t < 12; t++) m = fmaxf(m, sE[t * 12 + tid]);
        float s = 0.f;
        for (int t = 0; t < 12; t++) s += expf(sE[t * 12 + tid] - m);
        mx[tid] = m; sm[tid] = s;
    }
    __syncthreads();
    float val = 0.f;
    if (tid < 144) {
        int u = tid % 12;
        val = expf(sE[tid] - mx[u]) / sm[u];
        E[b * 144 + tid] = val;
    }
    __syncthreads();
    if (tid < 144) sE[tid] = val;
    __syncthreads();
    if (tid < 12) {
        float a = 0.f;
        for (int u = 0; u < 12; u++) a += sE[tid * 12 + u] * W1[u];
        EW1[b * 12 + tid] = a;
    }
}

// ---------------- l2/r2 from Xrow (bf16, packed loads) ----------------
__global__ __launch_bounds__(384) void k_l2r2x(const unsigned short* __restrict__ Xrow,
                                               const float* __restrict__ rr3,
                                               const float* __restrict__ E,
                                               const float* __restrict__ EW1,
                                               const float* __restrict__ W2,
                                               float* __restrict__ l2,
                                               float* __restrict__ r2)
{
    __shared__ float xs[8 * 384];
    __shared__ float Es[144], ew[12], rrs[96], lp[8][32];
    int b = blockIdx.y, tid = threadIdx.x;
    int n0 = blockIdx.x * 8;
    size_t r0 = (size_t)b * NN + n0;
    if (tid < 144) Es[tid] = E[b * 144 + tid];
    if (tid < 12) ew[tid] = EW1[b * 12 + tid];
    if (tid < 96) rrs[tid] = rr3[(r0 + tid / 12) * 12 + (tid % 12)];
    const unsigned int* Xr = (const unsigned int*)(Xrow + r0 * 384);
    for (int i2 = tid; i2 < 1536; i2 += 384) {
        unsigned int w = Xr[i2];
        xs[2 * i2]     = bf2f((unsigned short)(w & 0xffff));
        xs[2 * i2 + 1] = bf2f((unsigned short)(w >> 16));
    }
    __syncthreads();
    if (tid < 256) {
        int i = tid >> 5, f = tid & 31;
        float a = 0.f;
#pragma unroll
        for (int t = 0; t < 12; t++) a += xs[i * 384 + f * 12 + t] * ew[t];
        lp[i][f] = a;
    }
    __syncthreads();
    if (tid < 96) {
        int i = tid / 12, u = tid - i * 12;
        float a = 0.f;
        for (int f = 0; f < 32; f++) a += lp[i][f] * W2[f * 12 + u];
        l2[(r0 + i) * 12 + u] = a;
        float rv = 0.f;
#pragma unroll
        for (int t = 0; t < 12; t++) rv += rrs[i * 12 + t] * Es[t * 12 + u];
        r2[((size_t)b * 12 + u) * NN + n0 + i] = rv;
    }
}

// Xt[b][j][n] = Xrow[b][n][j]; flat blocks < 1024 also convert Vs row -> bf16
__global__ __launch_bounds__(256) void k_xt(const unsigned short* __restrict__ Xrow,
                                            unsigned short* __restrict__ Xt,
                                            const float* __restrict__ Vs,
                                            unsigned short* __restrict__ Vsb)
{
    int tid = threadIdx.x;
    int fid = blockIdx.x + 6 * (blockIdx.y + 16 * blockIdx.z);
    if (fid < 1024) {
        size_t i = (size_t)fid * 1024 + tid * 4;
        float4 v = *(const float4*)(Vs + i);
        unsigned int p0 = (unsigned int)cvt_bf(v.x) | ((unsigned int)cvt_bf(v.y) << 16);
        unsigned int p1 = (unsigned int)cvt_bf(v.z) | ((unsigned int)cvt_bf(v.w) << 16);
        *(unsigned int*)(Vsb + i) = p0;
        *(unsigned int*)(Vsb + i + 2) = p1;
    }
    __shared__ unsigned short tl[64][66];
    int b = blockIdx.z;
    int n0 = blockIdx.y * 64, j0 = blockIdx.x * 64;
    int c = tid & 63, r0 = tid >> 6;
    for (int i = 0; i < 16; i++) {
        int r = r0 + i * 4;
        tl[r][c] = Xrow[((size_t)b * NN + n0 + r) * 384 + j0 + c];
    }
    __syncthreads();
    int c2 = tid & 31, r4 = tid >> 5;
    unsigned short* ob = Xt + ((size_t)b * 384 + j0) * NN + n0;
    for (int i = 0; i < 8; i++) {
        int jr = r4 + i * 8;
        unsigned int v0 = (unsigned int)tl[2 * c2][jr] | ((unsigned int)tl[2 * c2 + 1][jr] << 16);
        *(unsigned int*)(ob + (size_t)jr * NN + 2 * c2) = v0;
    }
}

// ---------------- tiled P ----------------
__global__ __launch_bounds__(256) void k_Ptile(const float* __restrict__ l2,
                                               const float* __restrict__ r2,
                                               const float* __restrict__ bsin,
                                               unsigned short* __restrict__ Pt)
{
    __shared__ float l2s[64][13];
    __shared__ float r2s[12][64];
    __shared__ float bsS[64][65];
    int k0 = blockIdx.x * 64, m0 = blockIdx.y * 64, b = blockIdx.z;
    int tid = threadIdx.x;
    for (int i = tid; i < 768; i += 256) {
        int r = i / 12, t = i - r * 12;
        l2s[r][t] = l2[((size_t)b * NN + m0 + r) * 12 + t];
    }
    for (int i = tid; i < 768; i += 256) {
        int t = i >> 6, k = i & 63;
        r2s[t][k] = r2[((size_t)b * 12 + t) * NN + k0 + k];
    }
    for (int i = tid; i < 4096; i += 256) {
        int r = i >> 6, c = i & 63;
        bsS[r][c] = bsin[(size_t)(m0 + r) * NN + k0 + c];
    }
    __syncthreads();
    int m = tid & 63, kg = tid >> 6;
    float lv[12];
#pragma unroll
    for (int t = 0; t < 12; t++) lv[t] = l2s[m][t];
#pragma unroll
    for (int s = 0; s < 16; s++) {
        int kl = kg * 16 + s;
        float p = bsS[m][kl];
#pragma unroll
        for (int t = 0; t < 12; t++) p += lv[t] * r2s[t][kl];
        float sg = 1.f / (1.f + expf(-p));
        Pt[((size_t)b * NN + k0 + kl) * NN + m0 + m] = cvt_bf(sg);
    }
}

// bf16 transpose 1024x1024
__global__ __launch_bounds__(256) void k_tb16(const unsigned short* __restrict__ s,
                                              unsigned short* __restrict__ d)
{
    __shared__ unsigned short tl[64][65];
    int r0 = blockIdx.y * 64, c0 = blockIdx.x * 64;
    int tid = threadIdx.x;
    int c = tid & 63, rr = tid >> 6;
    for (int i = 0; i < 16; i++)
        tl[rr + i * 4][c] = s[(size_t)(r0 + rr + i * 4) * NN + c0 + c];
    __syncthreads();
    for (int i = 0; i < 16; i++)
        d[(size_t)(c0 + rr + i * 4) * NN + r0 + c] = tl[c][rr + i * 4];
}

// ---------------- 8-phase 256x256 S-GEMM: C[b] = exp(Vs @ Pt[b]^T) + colsum ----------------
__device__ inline void stage2(const short* __restrict__ g, int grow0, int gk0,
                              short* dstbase, int tid)
{
#pragma unroll
    for (int o = 0; o < 2; o++) {
        int y = o * 8192 + tid * 16;
        int rowh = y >> 7;
        int colb = (y & 127) ^ ((rowh & 7) << 4);
        const short* src = g + (size_t)(grow0 + rowh) * NN + gk0 + (colb >> 1);
        gll16(src, dstbase + (y >> 1));
    }
}

__global__ __launch_bounds__(512, 2) void sgemm8(const short* __restrict__ A,
                                                 const short* __restrict__ Bm,
                                                 float* __restrict__ C,
                                                 float* __restrict__ colsum)
{
    int bz = blockIdx.z;
    const short* Bb = Bm + (size_t)bz * NN * NN;
    int i0 = blockIdx.y * 256, j0 = blockIdx.x * 256;
    __shared__ short sm[65536];
    int tid = threadIdx.x;
    int ln = tid & 63, wv = tid >> 6;
    int wm = (wv >> 2) * 128, wn = (wv & 3) * 64;
    int fr = ln & 15, fk = ln >> 4;
    int ahalf = wv >> 2;
    int bhalf = wn >> 7;
    int bcol = wn & 64;
    int swz = (fr & 7) << 4;
    int kcol0 = ((fk * 16) ^ swz) >> 1;
    int kcol1 = ((64 + fk * 16) ^ swz) >> 1;

    f32x4 acc[8][4];
#pragma unroll
    for (int m = 0; m < 8; m++)
#pragma unroll
        for (int n = 0; n < 4; n++) acc[m][n] = (f32x4)(0.f);

    stage2(Bb, j0 + 0,   0,  sm + 16384,        tid);
    stage2(Bb, j0 + 128, 0,  sm + 16384 + 8192, tid);
    stage2(A,  i0 + 0,   0,  sm + 0,            tid);
    stage2(A,  i0 + 128, 0,  sm + 8192,         tid);
    stage2(Bb, j0 + 0,   64, sm + 32768 + 16384,        tid);
    stage2(Bb, j0 + 128, 64, sm + 32768 + 16384 + 8192, tid);
    asm volatile("s_waitcnt vmcnt(4)" ::: "memory");
    __builtin_amdgcn_s_barrier();

    for (int i = 0; i < 8; i++) {
        bf16x8 bv[8];
#pragma unroll
        for (int ph = 0; ph < 8; ph++) {
            int t = 2 * i + (ph >> 2);
            int p = t & 1;
            int q = ph & 3;
            int abase = p * 32768 + ahalf * 8192;
            int bbase = p * 32768 + 16384 + bhalf * 8192;
            if (q == 0) {
#pragma unroll
                for (int nj = 0; nj < 4; nj++) {
                    int browh = bcol + nj * 16 + fr;
                    bv[nj * 2 + 0] = *(const bf16x8*)(sm + bbase + browh * 64 + kcol0);
                    bv[nj * 2 + 1] = *(const bf16x8*)(sm + bbase + browh * 64 + kcol1);
                }
            }
            bf16x8 av[4];
#pragma unroll
            for (int m2 = 0; m2 < 2; m2++) {
                int rowh = (2 * q + m2) * 16 + fr;
                av[m2 * 2 + 0] = *(const bf16x8*)(sm + abase + rowh * 64 + kcol0);
                av[m2 * 2 + 1] = *(const bf16x8*)(sm + abase + rowh * 64 + kcol1);
            }
            {
                int st, smat, shalf;
                if (ph == 0)      { st = 2 * i + 1; smat = 0; shalf = 0; }
                else if (ph == 1) { st = 2 * i + 1; smat = 0; shalf = 1; }
                else if (ph == 2) { st = 2 * i + 2; smat = 1; shalf = 0; }
                else if (ph == 3) { st = 2 * i + 2; smat = 1; shalf = 1; }
                else if (ph == 4) { st = 2 * i + 2; smat = 0; shalf = 0; }
                else if (ph == 5) { st = 2 * i + 2; smat = 0; shalf = 1; }
                else if (ph == 6) { st = 2 * i + 3; smat = 1; shalf = 0; }
                else              { st = 2 * i + 3; smat = 1; shalf = 1; }
                if (st < 16) {
                    short* dst = sm + (st & 1) * 32768 + smat * 16384 + shalf * 8192;
                    const short* g = smat ? Bb : A;
                    int grow0 = (smat ? j0 : i0) + shalf * 128;
                    stage2(g, grow0, st * 64, dst, tid);
                }
            }
            __builtin_amdgcn_s_barrier();
            __builtin_amdgcn_s_setprio(1);
#pragma unroll
            for (int m2 = 0; m2 < 2; m2++)
#pragma unroll
                for (int nj = 0; nj < 4; nj++) {
                    acc[2 * q + m2][nj] = __builtin_amdgcn_mfma_f32_16x16x32_bf16(
                        av[m2 * 2 + 0], bv[nj * 2 + 0], acc[2 * q + m2][nj], 0, 0, 0);
                    acc[2 * q + m2][nj] = __builtin_amdgcn_mfma_f32_16x16x32_bf16(
                        av[m2 * 2 + 1], bv[nj * 2 + 1], acc[2 * q + m2][nj], 0, 0, 0);
                }
            __builtin_amdgcn_s_setprio(0);
            if (ph == 3 || ph == 7) {
                if (i < 7) asm volatile("s_waitcnt vmcnt(4)" ::: "memory");
                else       asm volatile("s_waitcnt vmcnt(0)" ::: "memory");
            }
            __builtin_amdgcn_s_barrier();
        }
    }
    float* Cb = C + (size_t)bz * NN * NN;
#pragma unroll
    for (int nj = 0; nj < 4; nj++) {
        int col = j0 + wn + nj * 16 + fr;
        float cs = 0.f;
#pragma unroll
        for (int m = 0; m < 8; m++) {
            int row = i0 + wm + m * 16 + fk * 4;
#pragma unroll
            for (int r = 0; r < 4; r++) {
                float e = expf(acc[m][nj][r]);
                Cb[(size_t)(row + r) * NN + col] = e;
                cs += e;
            }
        }
        cs += __shfl_xor(cs, 16);
        cs += __shfl_xor(cs, 32);
        if (ln < 16) atomicAdd(&colsum[(size_t)bz * NN + col], cs);
    }
}

// ---------------- MFMA bf16 NT GEMM (MODE 3: split-K fp32 atomicAdd) ----------------
template<int MODE>
__global__ __launch_bounds__(256) void mgemm(const short* __restrict__ A,
                                             const short* __restrict__ B,
                                             void* __restrict__ Cv,
                                             int Kd, int kchunk,
                                             int ldA, int ldB, int ldC,
                                             long sA, long sB, long sC,
                                             float* __restrict__ colsum)
{
    int bz = blockIdx.z;
    const short* Ab = A + (size_t)bz * sA;
    const short* Bb = B + (size_t)bz * sB;
    int i0 = blockIdx.y * 128, j0 = blockIdx.x * 128;
    __shared__ short sm[16384];
    int tid = threadIdx.x;
    int ln = tid & 63, wv = tid >> 6;
    int wm = (wv >> 1) * 64, wn = (wv & 1) * 64;
    int fr = ln & 15, fk = ln >> 4;
    f32x4 acc[4][4];
#pragma unroll
    for (int a = 0; a < 4; a++)
#pragma unroll
        for (int b2 = 0; b2 < 4; b2++) acc[a][b2] = (f32x4)(0.f);

    int k_lo = 0, k_hi = Kd;
    if constexpr (MODE == 3) { k_lo = bz * kchunk; k_hi = k_lo + kchunk; }

    for (int k0 = k_lo; k0 < k_hi; k0 += 64) {
#pragma unroll
        for (int q = 0; q < 4; q++) {
            int e = q * 2048 + tid * 8;
            const short* src = Ab + (size_t)(i0 + (e >> 6)) * ldA + k0 + (e & 63);
            gll16(src, sm + e);
        }
#pragma unroll
        for (int q = 0; q < 4; q++) {
            int e = q * 2048 + tid * 8;
            const short* src = Bb + (size_t)(j0 + (e >> 6)) * ldB + k0 + (e & 63);
            gll16(src, sm + 8192 + e);
        }
        __syncthreads();
#pragma unroll
        for (int ks = 0; ks < 2; ks++) {
            bf16x8 av[4], bv[4];
#pragma unroll
            for (int mi = 0; mi < 4; mi++)
                av[mi] = *(const bf16x8*)(sm + (wm + mi * 16 + fr) * 64 + ks * 32 + fk * 8);
#pragma unroll
            for (int nj = 0; nj < 4; nj++)
                bv[nj] = *(const bf16x8*)(sm + 8192 + (wn + nj * 16 + fr) * 64 + ks * 32 + fk * 8);
#pragma unroll
            for (int mi = 0; mi < 4; mi++)
#pragma unroll
                for (int nj = 0; nj < 4; nj++)
                    acc[mi][nj] = __builtin_amdgcn_mfma_f32_16x16x32_bf16(av[mi], bv[nj], acc[mi][nj], 0, 0, 0);
        }
        __syncthreads();
    }
    if constexpr (MODE == 3) {
        float* Cb = (float*)Cv;
#pragma unroll
        for (int mi = 0; mi < 4; mi++)
#pragma unroll
            for (int nj = 0; nj < 4; nj++) {
                int row = i0 + wm + mi * 16 + fk * 4;
                int col = j0 + wn + nj * 16 + fr;
#pragma unroll
                for (int r = 0; r < 4; r++)
                    atomicAdd(&Cb[(size_t)(row + r) * ldC + col], acc[mi][nj][r]);
            }
    }
}

// ---------------- merged h-GEMMs: 768 blocks, first 384 At1->h1, next 384 At2->h2 ----------------
__global__ __launch_bounds__(256) void mgemm_hh(const short* __restrict__ A1,
                                                const short* __restrict__ A2,
                                                const short* __restrict__ B,
                                                unsigned short* __restrict__ C1,
                                                unsigned short* __restrict__ C2)
{
    int id = blockIdx.x;
    int half = id / 384;
    int sid = id - half * 384;
    int xcd = sid & 7, jj = sid >> 3;
    int b = (xcd << 1) | (jj / 24);
    int r = jj % 24;
    int i0 = (r / 3) * 128, j0 = (r % 3) * 128;
    const short* Ab = (half ? A2 : A1) + (size_t)b * NN * NN;
    const short* Bb = B + (size_t)b * 384 * NN;
    unsigned short* C = half ? C2 : C1;
    __shared__ short sm[16384];
    int tid = threadIdx.x;
    int ln = tid & 63, wv = tid >> 6;
    int wm = (wv >> 1) * 64, wn = (wv & 1) * 64;
    int fr = ln & 15, fk = ln >> 4;
    f32x4 acc[4][4];
#pragma unroll
    for (int a = 0; a < 4; a++)
#pragma unroll
        for (int b2 = 0; b2 < 4; b2++) acc[a][b2] = (f32x4)(0.f);

    for (int k0 = 0; k0 < NN; k0 += 64) {
#pragma unroll
        for (int q = 0; q < 4; q++) {
            int e = q * 2048 + tid * 8;
            gll16(Ab + (size_t)(i0 + (e >> 6)) * NN + k0 + (e & 63), sm + e);
        }
#pragma unroll
        for (int q = 0; q < 4; q++) {
            int e = q * 2048 + tid * 8;
            gll16(Bb + (size_t)(j0 + (e >> 6)) * NN + k0 + (e & 63), sm + 8192 + e);
        }
        __syncthreads();
#pragma unroll
        for (int ks = 0; ks < 2; ks++) {
            bf16x8 av[4], bv[4];
#pragma unroll
            for (int mi = 0; mi < 4; mi++)
                av[mi] = *(const bf16x8*)(sm + (wm + mi * 16 + fr) * 64 + ks * 32 + fk * 8);
#pragma unroll
            for (int nj = 0; nj < 4; nj++)
                bv[nj] = *(const bf16x8*)(sm + 8192 + (wn + nj * 16 + fr) * 64 + ks * 32 + fk * 8);
#pragma unroll
            for (int mi = 0; mi < 4; mi++)
#pragma unroll
                for (int nj = 0; nj < 4; nj++)
                    acc[mi][nj] = __builtin_amdgcn_mfma_f32_16x16x32_bf16(av[mi], bv[nj], acc[mi][nj], 0, 0, 0);
        }
        __syncthreads();
    }
#pragma unroll
    for (int mi = 0; mi < 4; mi++)
#pragma unroll
        for (int nj = 0; nj < 4; nj++) {
            int row = i0 + wm + mi * 16 + fk * 4;
            int col = j0 + wn + nj * 16 + fr;
#pragma unroll
            for (int r2 = 0; r2 < 4; r2++)
                C[((size_t)b * NN + row + r2) * 384 + col] = cvt_bf(acc[mi][nj][r2]);
        }
}

// ---------------- normalize + threshold + At1 + At2 + sdiag ----------------
__global__ __launch_bounds__(256) void k_normprep2(float* __restrict__ spat,
                                                   const float* __restrict__ colsum,
                                                   const float* __restrict__ sup,
                                                   const float* __restrict__ supsq,
                                                   unsigned short* __restrict__ At1,
                                                   unsigned short* __restrict__ At2,
                                                   float* __restrict__ sdiag)
{
    __shared__ unsigned short t1[64][66];
    __shared__ unsigned short t2[64][66];
    int b = blockIdx.z;
    int n0 = blockIdx.y * 64, m0 = blockIdx.x * 64;
    int tid = threadIdx.x;
    int c = tid & 63, r0 = tid >> 6;
    const float thr = (1.0f / 1024.0f) / 0.6f;
    float inv = 1.f / colsum[(size_t)b * NN + m0 + c];
    float* sp = spat + (size_t)b * NN * NN;
    for (int i = 0; i < 16; i++) {
        int r = r0 + i * 4;
        size_t idx = (size_t)(n0 + r) * NN + m0 + c;
        float v = sp[idx] * inv;
        v = (v < thr) ? 0.f : v;
        sp[idx] = v;
        if (n0 + r == m0 + c) sdiag[(size_t)b * NN + n0 + r] = v;
        t1[r][c] = cvt_bf(sup[(size_t)(n0 + r) * NN + m0 + c] * v);
        float p2 = 2.f * supsq[(size_t)(n0 + r) * NN + m0 + c]
                 - (((n0 + r) == (m0 + c)) ? 1.f : 0.f);
        t2[r][c] = cvt_bf(p2 * v);
    }
    __syncthreads();
    int c2 = tid & 31, r4 = tid >> 5;
    size_t ob = ((size_t)b * NN + m0) * NN + n0;
    for (int i = 0; i < 8; i++) {
        int rr = r4 + i * 8;
        unsigned int v1 = (unsigned int)t1[2 * c2][rr] | ((unsigned int)t1[2 * c2 + 1][rr] << 16);
        unsigned int v2 = (unsigned int)t2[2 * c2][rr] | ((unsigned int)t2[2 * c2 + 1][rr] << 16);
        *(unsigned int*)(At1 + ob + (size_t)rr * NN + 2 * c2) = v1;
        *(unsigned int*)(At2 + ob + (size_t)rr * NN + 2 * c2) = v2;
    }
}

// ---------------- support graph ----------------
__global__ __launch_bounds__(256) void k_sup(const float* __restrict__ emb,
                                             float* __restrict__ sup,
                                             unsigned short* __restrict__ supB)
{
    int n = blockIdx.x, tid = threadIdx.x;
    __shared__ float en[16];
    if (tid < 16) en[tid] = emb[n * 16 + tid];
    __syncthreads();
    float v[4];
#pragma unroll
    for (int q = 0; q < 4; q++) {
        int m = q * 256 + tid;
        float d = 0.f;
#pragma unroll
        for (int dd = 0; dd < 16; dd++) d += en[dd] * emb[m * 16 + dd];
        v[q] = fmaxf(d, 0.f);
    }
    float mx = fmaxf(fmaxf(v[0], v[1]), fmaxf(v[2], v[3]));
    for (int o = 32; o > 0; o >>= 1) mx = fmaxf(mx, __shfl_xor(mx, o));
    __shared__ float red[4];
    if ((tid & 63) == 0) red[tid >> 6] = mx;
    __syncthreads();
    mx = fmaxf(fmaxf(red[0], red[1]), fmaxf(red[2], red[3]));
    float e[4];
    float s = 0.f;
#pragma unroll
    for (int q = 0; q < 4; q++) { e[q] = expf(v[q] - mx); s += e[q]; }
    for (int o = 32; o > 0; o >>= 1) s += __shfl_xor(s, o);
    __shared__ float red2[4];
    if ((tid & 63) == 0) red2[tid >> 6] = s;
    __syncthreads();
    s = red2[0] + red2[1] + red2[2] + red2[3];
    float inv = 1.f / s;
#pragma unroll
    for (int q = 0; q < 4; q++) {
        float val = e[q] * inv;
        sup[(size_t)n * NN + q * 256 + tid] = val;
        supB[(size_t)n * NN + q * 256 + tid] = cvt_bf(val);
    }
}

// ---------------- merged weight prep ----------------
__global__ __launch_bounds__(256) void k_wprep(const float* __restrict__ tcv,
                                               const float* __restrict__ tcg,
                                               const float* __restrict__ Theta,
                                               const float* __restrict__ rcw,
                                               unsigned short* __restrict__ Wr,
                                               unsigned short* __restrict__ Th,
                                               unsigned short* __restrict__ Rc)
{
    int tid = threadIdx.x;
    if (blockIdx.x < 64) {
        int o = blockIdx.x;
        float t = 0.f, p = 0.f;
        if (tid < 192) { t = tcv[o * 192 + tid]; p = t * t; }
        for (int off = 32; off > 0; off >>= 1) p += __shfl_xor(p, off);
        __shared__ float wsr[3];
        if (tid < 192 && (tid & 63) == 0) wsr[tid >> 6] = p;
        __syncthreads();
        if (tid < 192) {
            float sum = wsr[0] + wsr[1] + wsr[2];
            int c = tid / 3, dt = tid - c * 3;
            Wr[o * 192 + dt * 64 + c] = cvt_bf(t * (tcg[o] / sqrtf(sum)));
        }
    } else {
        for (int i = tid; i < 6144; i += 256) {
            int o = i / 96, rem = i - o * 96;
            int kind = rem >> 5, f = rem & 31;
            Th[i] = cvt_bf(Theta[kind * 2048 + f * 64 + o]);
        }
        for (int i = tid; i < 2048; i += 256) Rc[i] = cvt_bf(rcw[i]);
    }
}

// ---------------- MFMA fused tail ----------------
__global__ __launch_bounds__(256) void k_tail(const float* __restrict__ x,
                                              const unsigned short* __restrict__ h1,
                                              const unsigned short* __restrict__ h2,
                                              const float* __restrict__ sdiag,
                                              const unsigned short* __restrict__ Th,
                                              const unsigned short* __restrict__ Wr,
                                              const unsigned short* __restrict__ Rc,
                                              const float* __restrict__ tcb,
                                              const float* __restrict__ rcb,
                                              const float* __restrict__ lnw,
                                              const float* __restrict__ lnb,
                                              float* __restrict__ out)
{
    int b = blockIdx.y;
    int node0 = blockIdx.x * 4;
    int tid = threadIdx.x;
    int ln = tid & 63, wv = tid >> 6;
    int fr = ln & 15, fk = ln >> 4;

    __shared__ union {
        struct { unsigned short xt[1920], h1t[1920], h2t[1920], gcn[4032]; } a;
        float Y[48 * 65];
    } u;
    __shared__ float sdp[48];
    __shared__ float lnwS[64], lnbS[64], tbS[64];
    __shared__ float muS[48], rsS[48];

    size_t rowb = ((size_t)b * NN + node0) * 384;
    {
        const float2* xp = (const float2*)(x + rowb);
        const unsigned int* h1p = (const unsigned int*)(h1 + rowb);
        const unsigned int* h2p = (const unsigned int*)(h2 + rowb);
        for (int q = tid; q < 768; q += 256) {
            int j0 = q * 2;
            int node = j0 / 384, j = j0 - node * 384;
            int f = j / 12, t = j - f * 12;
            int t2 = t + 1, f2 = f;
            if (t2 == 12) { t2 = 0; f2 = f + 1; }
            int la0 = node * 480 + t * 40 + f;
            int la1 = node * 480 + t2 * 40 + f2;
            float2 xv = xp[q];
            unsigned int w1 = h1p[q], w2 = h2p[q];
            u.a.xt[la0] = cvt_bf(xv.x);  u.a.xt[la1] = cvt_bf(xv.y);
            u.a.h1t[la0] = (unsigned short)(w1 & 0xffff); u.a.h1t[la1] = (unsigned short)(w1 >> 16);
            u.a.h2t[la0] = (unsigned short)(w2 & 0xffff); u.a.h2t[la1] = (unsigned short)(w2 >> 16);
        }
    }
    for (int i = tid; i < 576; i += 256) {
        int node = i / 144, r = i - node * 144;
        int rr = (r < 72) ? 0 : 13;
        u.a.gcn[node * 1008 + rr * 72 + (r % 72)] = 0;
    }
    if (tid < 48) sdp[tid] = sdiag[(size_t)b * NN + node0 + tid / 12];
    if (tid < 64) { lnwS[tid] = lnw[tid]; lnbS[tid] = lnb[tid]; tbS[tid] = tcb[tid] + rcb[tid]; }

    int ocol = wv * 16 + fr;
    bf16x8 bTh[3], bWr[6], bRc;
#pragma unroll
    for (int kb = 0; kb < 3; kb++)
        bTh[kb] = *(const bf16x8*)((const short*)Th + (size_t)ocol * 96 + kb * 32 + fk * 8);
#pragma unroll
    for (int kb = 0; kb < 6; kb++)
        bWr[kb] = *(const bf16x8*)((const short*)Wr + (size_t)ocol * 192 + kb * 32 + fk * 8);
    bRc = *(const bf16x8*)((const short*)Rc + (size_t)ocol * 32 + fk * 8);

    int na[3], ta[3];
#pragma unroll
    for (int rb = 0; rb < 3; rb++) {
        int p = rb * 16 + fr;
        na[rb] = p / 12; ta[rb] = p - na[rb] * 12;
    }
    __syncthreads();

    f32x4 acc[3];
#pragma unroll
    for (int rb = 0; rb < 3; rb++) {
        int ax = na[rb] * 480 + ta[rb] * 40 + fk * 8;
        bf16x8 avx = *(const bf16x8*)(u.a.xt + ax);
        f32x4 z = (f32x4)(0.f);
        acc[rb] = __builtin_amdgcn_mfma_f32_16x16x32_bf16(avx, bTh[0], z, 0, 0, 0);
#pragma unroll
        for (int r = 0; r < 4; r++) acc[rb][r] *= sdp[rb * 16 + fk * 4 + r];
        bf16x8 av1 = *(const bf16x8*)(u.a.h1t + ax);
        acc[rb] = __builtin_amdgcn_mfma_f32_16x16x32_bf16(av1, bTh[1], acc[rb], 0, 0, 0);
        bf16x8 av2 = *(const bf16x8*)(u.a.h2t + ax);
        acc[rb] = __builtin_amdgcn_mfma_f32_16x16x32_bf16(av2, bTh[2], acc[rb], 0, 0, 0);
    }
#pragma unroll
    for (int rb = 0; rb < 3; rb++) {
#pragma unroll
        for (int r = 0; r < 4; r++) {
            int pc = rb * 16 + fk * 4 + r;
            int nc = pc / 12, tc2 = pc - nc * 12;
            u.a.gcn[nc * 1008 + (tc2 + 1) * 72 + wv * 16 + fr] = cvt_bf(fmaxf(acc[rb][r], 0.f));
        }
    }
    __syncthreads();
#pragma unroll
    for (int rb = 0; rb < 3; rb++) {
        f32x4 a2 = (f32x4)(0.f);
#pragma unroll
        for (int kb = 0; kb < 6; kb++) {
            int dt = kb >> 1, c0 = (kb & 1) * 32;
            bf16x8 ag = *(const bf16x8*)(u.a.gcn + na[rb] * 1008 + (ta[rb] + dt) * 72 + c0 + fk * 8);
            a2 = __builtin_amdgcn_mfma_f32_16x16x32_bf16(ag, bWr[kb], a2, 0, 0, 0);
        }
        int ax = na[rb] * 480 + ta[rb] * 40 + fk * 8;
        bf16x8 avx = *(const bf16x8*)(u.a.xt + ax);
        acc[rb] = __builtin_amdgcn_mfma_f32_16x16x32_bf16(avx, bRc, a2, 0, 0, 0);
    }
    __syncthreads();
    float tb = tbS[ocol];
#pragma unroll
    for (int rb = 0; rb < 3; rb++)
#pragma unroll
        for (int r = 0; r < 4; r++)
            u.Y[(rb * 16 + fk * 4 + r) * 65 + ocol] = acc[rb][r] + tb;
    __syncthreads();
    if (tid < 48) {
        float s = 0.f, s2 = 0.f;
        for (int o = 0; o < 64; o++) {
            float v = u.Y[tid * 65 + o];
            s += v; s2 += v * v;
        }
        float mm = s * (1.f / 64.f);
        float var = s2 * (1.f / 64.f) - mm * mm;
        muS[tid] = mm; rsS[tid] = rsqrtf(var + 1e-5f);
    }
    __syncthreads();
    float2* obv = (float2*)(out + rowb * 2);
    for (int q = tid; q < 1536; q += 256) {
        int i = q * 2;
        int node = i / 768, rr = i - node * 768;
        int o = rr / 12, t = rr - o * 12;
        int p0 = node * 12 + t;
        float v0 = (u.Y[p0 * 65 + o] - muS[p0]) * rsS[p0] * lnwS[o] + lnbS[o];
        int t1 = t + 1, o1 = o;
        if (t1 == 12) { t1 = 0; o1 = o + 1; }
        int p1 = node * 12 + t1;
        float v1 = (u.Y[p1 * 65 + o1] - muS[p1]) * rsS[p1] * lnwS[o1] + lnbS[o1];
        float2 pk; pk.x = v0; pk.y = v1;
        obv[q] = pk;
    }
}

extern "C" void kernel_launch(void* const* d_in, const int* in_sizes, int n_in,
                              void* d_out, int out_size, void* d_ws, size_t ws_size,
                              hipStream_t stream)
{
    const float* x    = (const float*)d_in[0];
    const float* emb  = (const float*)d_in[1];
    const float* W1   = (const float*)d_in[2];
    const float* W2   = (const float*)d_in[3];
    const float* W3   = (const float*)d_in[4];
    const float* bs   = (const float*)d_in[5];
    const float* Vs   = (const float*)d_in[6];
    const float* U1   = (const float*)d_in[7];
    const float* U2   = (const float*)d_in[8];
    const float* U3   = (const float*)d_in[9];
    const float* be   = (const float*)d_in[10];
    const float* Ve   = (const float*)d_in[11];
    const float* Theta= (const float*)d_in[12];
    const float* tcv  = (const float*)d_in[13];
    const float* tcg  = (const float*)d_in[14];
    const float* tcb  = (const float*)d_in[15];
    const float* rcw  = (const float*)d_in[16];
    const float* rcb  = (const float*)d_in[17];
    const float* lnw  = (const float*)d_in[18];
    const float* lnb  = (const float*)d_in[19];

    float* xres = (float*)d_out;                       // B*N*FT*T fp32 (scratch for At2 until k_tail)
    float* spat = xres + (size_t)NB * NN * NFT * NT;   // B*N*N fp32

    char* base = (char*)d_ws;
    unsigned short* Xrow = (unsigned short*)(base + 0);
    unsigned short* Pt   = (unsigned short*)(base + 0);
    unsigned short* supB = (unsigned short*)(base + 0);
    unsigned short* supT = (unsigned short*)(base + 2097152);
    unsigned short* At1  = (unsigned short*)(base + 0);
    unsigned short* At2  = (unsigned short*)xres;          // d_out scratch
    unsigned short* Xt  = (unsigned short*)(base + 33554432);
    unsigned short* h1  = (unsigned short*)(base + 46137344);
    unsigned short* h2  = (unsigned short*)(base + 58720256);
    unsigned short* Vsb = (unsigned short*)(base + 71303168);
    float* colsum  = (float*)(base + 73400320);
    float* sdiag   = (float*)(base + 73465856);
    float* sup     = (float*)(base + 77594624);
    float* supsq   = (float*)(base + 81788928);
    float* lhs_pre = (float*)(base + 85983232);
    float* M2      = (float*)(base + 86007808);
    float* rhs     = (float*)(base + 86794240);
    float* rr3     = (float*)(base + 87580672);
    float* E       = (float*)(base + 88376320);
    float* EW1     = (float*)(base + 88385536);
    float* l2      = (float*)(base + 88386560);
    float* r2      = (float*)(base + 89172992);
    unsigned short* Wr = (unsigned short*)(base + 89959424);
    unsigned short* Th = (unsigned short*)(base + 89984000);
    unsigned short* Rc = (unsigned short*)(base + 89996288);

    hipMemsetAsync(lhs_pre, 0, 49152, stream);             // lhs_pre + M2 (contiguous)
    hipMemsetAsync(supsq, 0, (size_t)NN * NN * sizeof(float), stream);

    // pre-pass: x fp32 -> lhs_pre, rhs, rr3, Xrow(bf16)
    k_pre<<<dim3(16, 16), 384, 0, stream>>>(x, U1, U3, W3, lhs_pre, rhs, rr3, Xrow);
    k_M2<<<dim3(16, 32), 384, 0, stream>>>(U2, rhs, M2);
    k_E<<<16, 192, 0, stream>>>(lhs_pre, M2, be, Ve, W1, E, EW1);
    // spatial attention
    k_l2r2x<<<dim3(128, 16), 384, 0, stream>>>(Xrow, rr3, E, EW1, W2, l2, r2);
    k_xt<<<dim3(6, 16, 16), 256, 0, stream>>>(Xrow, Xt, Vs, Vsb);  // before Pt overwrites Xrow
    k_Ptile<<<dim3(16, 16, 16), 256, 0, stream>>>(l2, r2, bs, Pt);
    hipMemsetAsync(colsum, 0, (size_t)NB * NN * sizeof(float), stream);
    // 8-phase 256^2 S-GEMM with exp+colsum epilogue
    sgemm8<<<dim3(4, 4, 16), 512, 0, stream>>>((const short*)Vsb, (const short*)Pt,
                                               spat, colsum);
    // graph supports
    k_sup<<<1024, 256, 0, stream>>>(emb, sup, supB);
    k_tb16<<<dim3(16, 16), 256, 0, stream>>>(supB, supT);
    mgemm<3><<<dim3(8, 8, 4), 256, 0, stream>>>((const short*)supB, (const short*)supT,
        (void*)supsq, NN, 256, NN, NN, NN, 0L, 0L, 0L, nullptr);
    // normalize + threshold + masked adjacencies + diagonal
    k_normprep2<<<dim3(16, 16, 16), 256, 0, stream>>>(spat, colsum, sup, supsq, At1, At2, sdiag);
    // merged h-GEMMs (768 blocks, XCD swizzle per half)
    mgemm_hh<<<768, 256, 0, stream>>>((const short*)At1, (const short*)At2,
                                      (const short*)Xt, h1, h2);
    // tail
    k_wprep<<<65, 256, 0, stream>>>(tcv, tcg, Theta, rcw, Wr, Th, Rc);
    k_tail<<<dim3(256, 16), 256, 0, stream>>>(x, h1, h2, sdiag, Th, Wr, Rc,
                                              tcb, rcb, lnw, lnb, xres);
}